// Round 3
// baseline (2377.587 us; speedup 1.0000x reference)
//
#include <hip/hip_runtime.h>

#define NG 50000
#define NR 12000
#define EPS_N 50000
#define ELR_N 5000
#define E1_N 150000
#define E2_N 150000
#define GN_EPS_F 1e-5f
#define SCAN_CHUNK 4096

typedef __attribute__((ext_vector_type(8))) __bf16 bf16x8;
typedef __attribute__((ext_vector_type(4))) float f32x4;

__device__ __forceinline__ bf16x8 cvt8(const float* __restrict__ p) {
    float4 x0 = *reinterpret_cast<const float4*>(p);
    float4 x1 = *reinterpret_cast<const float4*>(p + 4);
    bf16x8 a;
    a[0] = (__bf16)x0.x; a[1] = (__bf16)x0.y; a[2] = (__bf16)x0.z; a[3] = (__bf16)x0.w;
    a[4] = (__bf16)x1.x; a[5] = (__bf16)x1.y; a[6] = (__bf16)x1.z; a[7] = (__bf16)x1.w;
    return a;
}

// ============================ CSR construction =============================
__global__ void hist14_k(const int* __restrict__ ps_u, const int* __restrict__ lr_u,
                         int* __restrict__ cnt)
{
    int t = blockIdx.x * 256 + threadIdx.x;
    const int total = 12 * EPS_N + 2 * ELR_N;
    if (t >= total) return;
    int k, u;
    if (t < 12 * EPS_N) { k = t / EPS_N; u = ps_u[t]; }
    else { int r = t - 12 * EPS_N; k = 12 + r / ELR_N; u = lr_u[r]; }
    atomicAdd(&cnt[k * NG + u], 1);
}

__global__ void fill14_k(const int* __restrict__ ps_u, const int* __restrict__ ps_v,
                         const int* __restrict__ lr_u, const int* __restrict__ lr_v,
                         int* __restrict__ head, int* __restrict__ col)
{
    int t = blockIdx.x * 256 + threadIdx.x;
    const int total = 12 * EPS_N + 2 * ELR_N;
    if (t >= total) return;
    int k, u, v;
    if (t < 12 * EPS_N) { k = t / EPS_N; u = ps_u[t]; v = ps_v[t]; }
    else { int r = t - 12 * EPS_N; k = 12 + r / ELR_N; u = lr_u[r]; v = lr_v[r]; }
    int pos = atomicAdd(&head[k * NG + u], 1);
    col[pos] = v;
}

__global__ void histE_k(const int* __restrict__ wi, int n, int* __restrict__ cnt)
{
    int t = blockIdx.x * 256 + threadIdx.x;
    if (t >= n) return;
    atomicAdd(&cnt[wi[t]], 1);
}

__global__ void fillE_k(const int* __restrict__ wi, int n,
                        int* __restrict__ head, int* __restrict__ col)
{
    int t = blockIdx.x * 256 + threadIdx.x;
    if (t >= n) return;
    int pos = atomicAdd(&head[wi[t]], 1);
    col[pos] = t;   // payload = edge id
}

__global__ void scan1_k(const int* __restrict__ in, int n, int* __restrict__ bsum)
{
    __shared__ int sm[4];
    int base = blockIdx.x * SCAN_CHUNK;
    int s = 0;
    for (int i = threadIdx.x; i < SCAN_CHUNK; i += 256) {
        int idx = base + i;
        s += (idx < n) ? in[idx] : 0;
    }
    #pragma unroll
    for (int off = 1; off < 64; off <<= 1) s += __shfl_xor(s, off);
    if ((threadIdx.x & 63) == 0) sm[threadIdx.x >> 6] = s;
    __syncthreads();
    if (threadIdx.x == 0) bsum[blockIdx.x] = sm[0] + sm[1] + sm[2] + sm[3];
}

__global__ void scan2_k(int* __restrict__ bsum, int nb)
{
    if (threadIdx.x == 0) {
        int acc = 0;
        for (int i = 0; i < nb; ++i) { int t = bsum[i]; bsum[i] = acc; acc += t; }
    }
}

__global__ void scan3_k(const int* __restrict__ in, int n,
                        const int* __restrict__ bsum, int* __restrict__ outp)
{
    __shared__ int sm[256];
    int base = blockIdx.x * SCAN_CHUNK;
    int loc[16]; int s = 0;
    #pragma unroll
    for (int i = 0; i < 16; ++i) {
        int idx = base + threadIdx.x * 16 + i;
        loc[i] = (idx < n) ? in[idx] : 0; s += loc[i];
    }
    sm[threadIdx.x] = s; __syncthreads();
    for (int off = 1; off < 256; off <<= 1) {
        int v = (threadIdx.x >= off) ? sm[threadIdx.x - off] : 0;
        __syncthreads();
        sm[threadIdx.x] += v;
        __syncthreads();
    }
    int tp = (threadIdx.x ? sm[threadIdx.x - 1] : 0) + bsum[blockIdx.x];
    #pragma unroll
    for (int i = 0; i < 16; ++i) {
        int idx = base + threadIdx.x * 16 + i;
        if (idx < n) outp[idx] = tp;
        tp += loc[i];
        if (idx == n - 1) outp[n] = tp;
    }
}

// ============================ dense 128x128 GEMM ===========================
__launch_bounds__(256)
__global__ void gemm128_k(const float* __restrict__ A,
                          const float* __restrict__ Wb, int wrs,
                          float* __restrict__ Cout, int M)
{
    const int tid = threadIdx.x;
    const int lane = tid & 63;
    const int wave = tid >> 6;
    const int waveM = wave >> 1, waveN = wave & 1;
    const int r16 = lane & 15, kq = lane >> 4;
    const int mbase = blockIdx.x * 64 + waveM * 32;

    bf16x8 b[4][4];
    #pragma unroll
    for (int ni = 0; ni < 4; ++ni) {
        const int col = waveN * 64 + ni * 16 + r16;
        #pragma unroll
        for (int ks = 0; ks < 4; ++ks)
            b[ni][ks] = cvt8(Wb + (size_t)col * wrs + ks * 32 + kq * 8);
    }
    int asrc[2];
    #pragma unroll
    for (int mi = 0; mi < 2; ++mi) {
        int r = mbase + mi * 16 + r16;
        asrc[mi] = r < M ? r : M - 1;
    }
    f32x4 acc[2][4];
    #pragma unroll
    for (int mi = 0; mi < 2; ++mi)
        #pragma unroll
        for (int ni = 0; ni < 4; ++ni)
            acc[mi][ni] = (f32x4){0.f, 0.f, 0.f, 0.f};

    #pragma unroll
    for (int ks = 0; ks < 4; ++ks) {
        bf16x8 a[2];
        #pragma unroll
        for (int mi = 0; mi < 2; ++mi)
            a[mi] = cvt8(A + (size_t)asrc[mi] * 128 + ks * 32 + kq * 8);
        #pragma unroll
        for (int mi = 0; mi < 2; ++mi)
            #pragma unroll
            for (int ni = 0; ni < 4; ++ni)
                acc[mi][ni] = __builtin_amdgcn_mfma_f32_16x16x32_bf16(
                    a[mi], b[ni][ks], acc[mi][ni], 0, 0, 0);
    }
    #pragma unroll
    for (int mi = 0; mi < 2; ++mi) {
        const int rb = mbase + mi * 16 + kq * 4;
        #pragma unroll
        for (int reg = 0; reg < 4; ++reg) {
            const int crow = rb + reg;
            if (crow >= M) continue;
            float* dst = Cout + (size_t)crow * 128 + waveN * 64 + r16;
            #pragma unroll
            for (int ni = 0; ni < 4; ++ni) dst[ni * 16] = acc[mi][ni][reg];
        }
    }
}

// ================= fused CSR-gather + multi-scale GEMM =====================
// out[u] = Σ_k ( Σ_{j in CSR row (k,u)} src[colv[j]] ) @ W_k.T
//          (+ selfA[u] @ Wself.T)  (+ addtr[u])
// A-fragments of the gathered sum are accumulated directly in registers in
// MFMA layout: lane (r16,kq) owns rows mbase+{0,16}+r16, cols ks*32+kq*8+0..7.
template<bool SELF, bool ADDT, bool SRCBF16>
__launch_bounds__(256)
__global__ void gather_gemm_k(const void* __restrict__ srcv,
                              const float* __restrict__ selfA,
                              const float* __restrict__ Wps,
                              const float* __restrict__ Wl,
                              const float* __restrict__ Wr,
                              const float* __restrict__ Wself,
                              const int* __restrict__ row_ptr,
                              const int* __restrict__ colv,
                              const float* __restrict__ addtr,
                              float* __restrict__ outp,
                              int Mout, int NS)
{
    const int tid = threadIdx.x;
    const int lane = tid & 63;
    const int wave = tid >> 6;
    const int waveM = wave >> 1, waveN = wave & 1;
    const int r16 = lane & 15, kq = lane >> 4;
    const int mbase = blockIdx.x * 64 + waveM * 32;

    f32x4 acc[2][4];
    #pragma unroll
    for (int mi = 0; mi < 2; ++mi)
        #pragma unroll
        for (int ni = 0; ni < 4; ++ni)
            acc[mi][ni] = (f32x4){0.f, 0.f, 0.f, 0.f};

    const int nk = NS + (SELF ? 1 : 0);
    for (int k = 0; k < nk; ++k) {
        float ss[2][32];
        #pragma unroll
        for (int mi = 0; mi < 2; ++mi)
            #pragma unroll
            for (int p = 0; p < 32; ++p) ss[mi][p] = 0.f;

        if (SELF && k == NS) {
            #pragma unroll
            for (int mi = 0; mi < 2; ++mi) {
                const int u = mbase + mi * 16 + r16;
                if (u < Mout) {
                    const float* sp = selfA + (size_t)u * 128;
                    #pragma unroll
                    for (int ks = 0; ks < 4; ++ks) {
                        float4 x0 = *(const float4*)(sp + ks * 32 + kq * 8);
                        float4 x1 = *(const float4*)(sp + ks * 32 + kq * 8 + 4);
                        ss[mi][ks*8+0] += x0.x; ss[mi][ks*8+1] += x0.y;
                        ss[mi][ks*8+2] += x0.z; ss[mi][ks*8+3] += x0.w;
                        ss[mi][ks*8+4] += x1.x; ss[mi][ks*8+5] += x1.y;
                        ss[mi][ks*8+6] += x1.z; ss[mi][ks*8+7] += x1.w;
                    }
                }
            }
        } else {
            #pragma unroll
            for (int mi = 0; mi < 2; ++mi) {
                const int u = mbase + mi * 16 + r16;
                if (u < Mout) {
                    const int beg = row_ptr[k * Mout + u];
                    const int end = row_ptr[k * Mout + u + 1];
                    for (int j = beg; j < end; ++j) {
                        const int v = colv[j];
                        if (SRCBF16) {
                            const __bf16* sp = (const __bf16*)srcv + (size_t)v * 128;
                            #pragma unroll
                            for (int ks = 0; ks < 4; ++ks) {
                                bf16x8 h = *(const bf16x8*)(sp + ks * 32 + kq * 8);
                                #pragma unroll
                                for (int i = 0; i < 8; ++i)
                                    ss[mi][ks*8+i] += (float)h[i];
                            }
                        } else {
                            const float* sp = (const float*)srcv + (size_t)v * 128;
                            #pragma unroll
                            for (int ks = 0; ks < 4; ++ks) {
                                float4 x0 = *(const float4*)(sp + ks * 32 + kq * 8);
                                float4 x1 = *(const float4*)(sp + ks * 32 + kq * 8 + 4);
                                ss[mi][ks*8+0] += x0.x; ss[mi][ks*8+1] += x0.y;
                                ss[mi][ks*8+2] += x0.z; ss[mi][ks*8+3] += x0.w;
                                ss[mi][ks*8+4] += x1.x; ss[mi][ks*8+5] += x1.y;
                                ss[mi][ks*8+6] += x1.z; ss[mi][ks*8+7] += x1.w;
                            }
                        }
                    }
                }
            }
        }

        const float* Wk = (SELF && k == NS) ? Wself
                        : (k < 12 ? Wps + (size_t)k * 16384 : (k == 12 ? Wl : Wr));

        bf16x8 a[2][4];
        #pragma unroll
        for (int mi = 0; mi < 2; ++mi)
            #pragma unroll
            for (int ks = 0; ks < 4; ++ks)
                #pragma unroll
                for (int i = 0; i < 8; ++i)
                    a[mi][ks][i] = (__bf16)ss[mi][ks * 8 + i];

        #pragma unroll
        for (int ks = 0; ks < 4; ++ks) {
            bf16x8 bb[4];
            #pragma unroll
            for (int ni = 0; ni < 4; ++ni) {
                const int col = waveN * 64 + ni * 16 + r16;
                bb[ni] = cvt8(Wk + (size_t)col * 128 + ks * 32 + kq * 8);
            }
            #pragma unroll
            for (int mi = 0; mi < 2; ++mi)
                #pragma unroll
                for (int ni = 0; ni < 4; ++ni)
                    acc[mi][ni] = __builtin_amdgcn_mfma_f32_16x16x32_bf16(
                        a[mi][ks], bb[ni], acc[mi][ni], 0, 0, 0);
        }
    }

    #pragma unroll
    for (int mi = 0; mi < 2; ++mi) {
        const int rb = mbase + mi * 16 + kq * 4;
        #pragma unroll
        for (int reg = 0; reg < 4; ++reg) {
            const int crow = rb + reg;
            if (crow >= Mout) continue;
            float* dst = outp + (size_t)crow * 128 + waveN * 64 + r16;
            const float* ap = ADDT ? addtr + (size_t)crow * 128 + waveN * 64 + r16
                                   : nullptr;
            #pragma unroll
            for (int ni = 0; ni < 4; ++ni) {
                float v = acc[mi][ni][reg];
                if (ADDT) v += ap[ni * 16];
                dst[ni * 16] = v;
            }
        }
    }
}

// ========== gemmdist2: on-the-fly dist GEMM + prectx add + GN + relu =======
// h[e] = relu(gn(dist(e) @ c1B.T + prectx[hi[e]], sb))  stored bf16
__launch_bounds__(256)
__global__ void gemmdist2_k(const int* __restrict__ hi_idx, const int* __restrict__ wi_idx,
                            const float* __restrict__ cpose, const float* __restrict__ tpose,
                            const float* __restrict__ rpw, const float* __restrict__ rpb,
                            const float* __restrict__ Wb,      // c1B (offset +128), stride 256
                            const float* __restrict__ prectx,
                            const float* __restrict__ sb,
                            __bf16* __restrict__ hout, int M)
{
    __shared__ float rw[128 * 4 + 128];
    __shared__ float smS[2][64], smQ[2][64];
    const int tid = threadIdx.x;
    for (int i = tid; i < 640; i += 256)
        rw[i] = (i < 512) ? rpw[i] : rpb[i - 512];
    __syncthreads();

    const int lane = tid & 63;
    const int wave = tid >> 6;
    const int waveM = wave >> 1, waveN = wave & 1;
    const int r16 = lane & 15, kq = lane >> 4;
    const int mbase = blockIdx.x * 64 + waveM * 32;

    bf16x8 b[4][4];
    #pragma unroll
    for (int ni = 0; ni < 4; ++ni) {
        const int col = waveN * 64 + ni * 16 + r16;
        #pragma unroll
        for (int ks = 0; ks < 4; ++ks)
            b[ni][ks] = cvt8(Wb + (size_t)col * 256 + ks * 32 + kq * 8);
    }

    float dl[2][4];
    #pragma unroll
    for (int mi = 0; mi < 2; ++mi) {
        int r = mbase + mi * 16 + r16;
        int e = r < M ? r : M - 1;
        int hi = hi_idx[e], wi = wi_idx[e];
        float4 cp = *reinterpret_cast<const float4*>(cpose + (size_t)hi * 4);
        float4 tp = *reinterpret_cast<const float4*>(tpose + (size_t)wi * 4);
        dl[mi][0] = cp.x - tp.x; dl[mi][1] = cp.y - tp.y;
        dl[mi][2] = cp.z - tp.z; dl[mi][3] = cp.w - tp.w;
    }

    f32x4 acc[2][4];
    #pragma unroll
    for (int mi = 0; mi < 2; ++mi)
        #pragma unroll
        for (int ni = 0; ni < 4; ++ni)
            acc[mi][ni] = (f32x4){0.f, 0.f, 0.f, 0.f};

    #pragma unroll
    for (int ks = 0; ks < 4; ++ks) {
        bf16x8 a[2];
        #pragma unroll
        for (int mi = 0; mi < 2; ++mi) {
            #pragma unroll
            for (int i = 0; i < 8; ++i) {
                const int k = ks * 32 + kq * 8 + i;
                float4 w4 = *reinterpret_cast<const float4*>(&rw[k * 4]);
                float d = fmaf(dl[mi][0], w4.x, fmaf(dl[mi][1], w4.y,
                          fmaf(dl[mi][2], w4.z, fmaf(dl[mi][3], w4.w, rw[512 + k]))));
                a[mi][i] = (__bf16)fmaxf(d, 0.f);
            }
        }
        #pragma unroll
        for (int mi = 0; mi < 2; ++mi)
            #pragma unroll
            for (int ni = 0; ni < 4; ++ni)
                acc[mi][ni] = __builtin_amdgcn_mfma_f32_16x16x32_bf16(
                    a[mi], b[ni][ks], acc[mi][ni], 0, 0, 0);
    }

    // add prectx[hi[crow]]
    #pragma unroll
    for (int mi = 0; mi < 2; ++mi) {
        const int rb = mbase + mi * 16 + kq * 4;
        #pragma unroll
        for (int reg = 0; reg < 4; ++reg) {
            const int crow = rb + reg;
            const int e = crow < M ? crow : M - 1;
            const int hrow = hi_idx[e];
            const float* pp = prectx + (size_t)hrow * 128 + waveN * 64 + r16;
            #pragma unroll
            for (int ni = 0; ni < 4; ++ni)
                acc[mi][ni][reg] += pp[ni * 16];
        }
    }

    // GroupNorm over each output row (128 cols spread over 16 r16-lanes x 2 waveN)
    #pragma unroll
    for (int mi = 0; mi < 2; ++mi) {
        #pragma unroll
        for (int reg = 0; reg < 4; ++reg) {
            float s = acc[mi][0][reg] + acc[mi][1][reg] + acc[mi][2][reg] + acc[mi][3][reg];
            float q = acc[mi][0][reg]*acc[mi][0][reg] + acc[mi][1][reg]*acc[mi][1][reg]
                    + acc[mi][2][reg]*acc[mi][2][reg] + acc[mi][3][reg]*acc[mi][3][reg];
            #pragma unroll
            for (int off = 1; off < 16; off <<= 1) {
                s += __shfl_xor(s, off);
                q += __shfl_xor(q, off);
            }
            if (r16 == 0) {
                int lr = waveM * 32 + mi * 16 + kq * 4 + reg;
                smS[waveN][lr] = s; smQ[waveN][lr] = q;
            }
        }
    }
    __syncthreads();

    #pragma unroll
    for (int mi = 0; mi < 2; ++mi) {
        #pragma unroll
        for (int reg = 0; reg < 4; ++reg) {
            const int lr = waveM * 32 + mi * 16 + kq * 4 + reg;
            const float S = smS[0][lr] + smS[1][lr];
            const float Q = smQ[0][lr] + smQ[1][lr];
            const float m = S * (1.f / 128.f);
            const float inv = rsqrtf(fmaxf(Q * (1.f / 128.f) - m * m, 0.f) + GN_EPS_F);
            const int crow = mbase + mi * 16 + kq * 4 + reg;
            if (crow < M) {
                __bf16* dp = hout + (size_t)crow * 128 + waveN * 64 + r16;
                #pragma unroll
                for (int ni = 0; ni < 4; ++ni) {
                    const int col = waveN * 64 + ni * 16 + r16;
                    float y = (acc[mi][ni][reg] - m) * inv * sb[col] + sb[128 + col];
                    dp[ni * 16] = (__bf16)fmaxf(y, 0.f);
                }
            }
        }
    }
}

// ======================= row GroupNorm + relu ==============================
// MODE 0: out = relu(gn(x));  MODE 2: out = relu(gn(x) + add)
template<int MODE>
__launch_bounds__(256)
__global__ void rowop_k(const float* __restrict__ in,
                        const float* __restrict__ sb,
                        const float* __restrict__ addp,
                        float* __restrict__ outp, int M)
{
    const int t = threadIdx.x;
    const int row = blockIdx.x * 64 + (t >> 2);
    if (row >= M) return;
    const int q = t & 3;
    const float* __restrict__ x = in + (size_t)row * 128 + q * 32;
    float v[32];
    #pragma unroll
    for (int i = 0; i < 8; ++i) {
        float4 p = *reinterpret_cast<const float4*>(x + i * 4);
        v[i*4+0] = p.x; v[i*4+1] = p.y; v[i*4+2] = p.z; v[i*4+3] = p.w;
    }
    float s = 0.f;
    #pragma unroll
    for (int i = 0; i < 32; ++i) s += v[i];
    s += __shfl_xor(s, 1); s += __shfl_xor(s, 2);
    const float m = s * (1.f / 128.f);
    float s2 = 0.f;
    #pragma unroll
    for (int i = 0; i < 32; ++i) { float d = v[i] - m; s2 = fmaf(d, d, s2); }
    s2 += __shfl_xor(s2, 1); s2 += __shfl_xor(s2, 2);
    const float inv = rsqrtf(s2 * (1.f / 128.f) + GN_EPS_F);

    float* __restrict__ dst = outp + (size_t)row * 128 + q * 32;
    const float* __restrict__ ad = (MODE == 2) ? addp + (size_t)row * 128 + q * 32 : nullptr;
    #pragma unroll
    for (int i = 0; i < 8; ++i) {
        float4 o;
        #pragma unroll
        for (int jj = 0; jj < 4; ++jj) {
            const int c = q * 32 + i * 4 + jj;
            float y = (v[i*4+jj] - m) * inv * sb[c] + sb[128 + c];
            if (MODE == 2) y += ad[i*4+jj];
            (&o.x)[jj] = fmaxf(y, 0.f);
        }
        *reinterpret_cast<float4*>(dst + i * 4) = o;
    }
}

// ===========================================================================
extern "C" void kernel_launch(void* const* d_in, const int* in_sizes, int n_in,
                              void* d_out, int out_size, void* d_ws, size_t ws_size,
                              hipStream_t stream)
{
    const float* roi_feat   = (const float*)d_in[0];
    const float* graph_pose = (const float*)d_in[1];
    const float* roi_pose   = (const float*)d_in[2];
    const float* lp_input_w = (const float*)d_in[3];
    const float* lp_rpw     = (const float*)d_in[4];
    const float* lp_rpb     = (const float*)d_in[5];
    const float* lp_c1w     = (const float*)d_in[6];
    const float* lp_c1gn    = (const float*)d_in[7];
    const float* lp_c2w     = (const float*)d_in[8];
    const float* lp_m1w     = (const float*)d_in[9];
    const float* lp_m1gn    = (const float*)d_in[10];
    const float* lp_m2w     = (const float*)d_in[11];
    const float* lp_m2gn    = (const float*)d_in[12];
    const float* lp_ngn     = (const float*)d_in[13];
    const float* f_ctrw     = (const float*)d_in[14];
    const float* f_psw      = (const float*)d_in[15];
    const float* f_lw       = (const float*)d_in[16];
    const float* f_rw       = (const float*)d_in[17];
    const float* f_ngn      = (const float*)d_in[18];
    const float* f_c2w      = (const float*)d_in[19];
    const float* f_c2gn     = (const float*)d_in[20];
    const int* e1_hi = (const int*)d_in[21];
    const int* e1_wi = (const int*)d_in[22];
    const int* e2_hi = (const int*)d_in[23];
    const int* e2_wi = (const int*)d_in[24];
    const int* ps_u  = (const int*)d_in[25];
    const int* ps_v  = (const int*)d_in[26];
    const int* lr_u  = (const int*)d_in[27];
    const int* lr_v  = (const int*)d_in[28];
    float* out = (float*)d_out;

    // ---- workspace layout ----
    float* gfeat = (float*)d_ws;                       // NG*128
    float* tmpG  = gfeat + (size_t)NG * 128;           // NG*128
    float* midG  = tmpG  + (size_t)NG * 128;           // NG*128
    float* preN  = midG  + (size_t)NG * 128;           // NR*128
    float* preN2 = preN  + (size_t)NR * 128;           // NR*128
    __bf16* hbuf = (__bf16*)(preN2 + (size_t)NR * 128); // E1_N*128 bf16
    int* ip      = (int*)(hbuf + (size_t)E1_N * 128);
    int* cnt14   = ip;             ip += 14 * NG;       // also reused as head
    int* rp14    = ip;             ip += 14 * NG + 1;
    int* col14   = ip;             ip += 12 * EPS_N + 2 * ELR_N;
    int* cntE1   = ip;             ip += NG;
    int* rpE1    = ip;             ip += NG + 1;
    int* colE1   = ip;             ip += E1_N;
    int* cntE2   = ip;             ip += NR;
    int* rpE2    = ip;             ip += NR + 1;
    int* colE2   = ip;             ip += E2_N;
    int* bsum    = ip;             ip += 256;

    dim3 blk(256);
    const dim3 gNG64((NG + 63) / 64), gNR64((NR + 63) / 64), gE64((E1_N + 63) / 64);
    const int NE14 = 12 * EPS_N + 2 * ELR_N;    // 610000
    const dim3 gH14((NE14 + 255) / 256);

    // ======================== CSR builds (once/call) ========================
    // 14-scale fusion CSR (key = k*NG + u, payload = source node v)
    hipMemsetAsync(cnt14, 0, (size_t)14 * NG * 4, stream);
    hist14_k<<<gH14, blk, 0, stream>>>(ps_u, lr_u, cnt14);
    {
        int n = 14 * NG, nb = (n + SCAN_CHUNK - 1) / SCAN_CHUNK;
        scan1_k<<<nb, blk, 0, stream>>>(cnt14, n, bsum);
        scan2_k<<<1, blk, 0, stream>>>(bsum, nb);
        scan3_k<<<nb, blk, 0, stream>>>(cnt14, n, bsum, rp14);
    }
    hipMemcpyAsync(cnt14, rp14, (size_t)14 * NG * 4, hipMemcpyDeviceToDevice, stream);
    fill14_k<<<gH14, blk, 0, stream>>>(ps_u, ps_v, lr_u, lr_v, cnt14, col14);
    // e1_wi CSR (NG rows, payload = edge id)
    hipMemsetAsync(cntE1, 0, (size_t)NG * 4, stream);
    histE_k<<<(E1_N + 255) / 256, blk, 0, stream>>>(e1_wi, E1_N, cntE1);
    {
        int n = NG, nb = (n + SCAN_CHUNK - 1) / SCAN_CHUNK;
        scan1_k<<<nb, blk, 0, stream>>>(cntE1, n, bsum);
        scan2_k<<<1, blk, 0, stream>>>(bsum, nb);
        scan3_k<<<nb, blk, 0, stream>>>(cntE1, n, bsum, rpE1);
    }
    hipMemcpyAsync(cntE1, rpE1, (size_t)NG * 4, hipMemcpyDeviceToDevice, stream);
    fillE_k<<<(E1_N + 255) / 256, blk, 0, stream>>>(e1_wi, E1_N, cntE1, colE1);
    // e2_wi CSR (NR rows)
    hipMemsetAsync(cntE2, 0, (size_t)NR * 4, stream);
    histE_k<<<(E2_N + 255) / 256, blk, 0, stream>>>(e2_wi, E2_N, cntE2);
    {
        int n = NR, nb = (n + SCAN_CHUNK - 1) / SCAN_CHUNK;
        scan1_k<<<nb, blk, 0, stream>>>(cntE2, n, bsum);
        scan2_k<<<1, blk, 0, stream>>>(bsum, nb);
        scan3_k<<<nb, blk, 0, stream>>>(cntE2, n, bsum, rpE2);
    }
    hipMemcpyAsync(cntE2, rpE2, (size_t)NR * 4, hipMemcpyDeviceToDevice, stream);
    fillE_k<<<(E2_N + 255) / 256, blk, 0, stream>>>(e2_wi, E2_N, cntE2, colE2);

    // ============== lane_pooling #1 (roi -> graph), tgt_feat = 0 ============
    gemm128_k<<<gNR64, blk, 0, stream>>>(roi_feat, lp_c1w, 256, preN, NR);  // prectx1
    gemmdist2_k<<<gE64, blk, 0, stream>>>(
        e1_hi, e1_wi, roi_pose, graph_pose, lp_rpw, lp_rpb,
        lp_c1w + 128, preN, lp_c1gn, hbuf, E1_N);
    gather_gemm_k<false,false,true><<<gNG64, blk, 0, stream>>>(
        hbuf, nullptr, lp_c2w, nullptr, nullptr, nullptr,
        rpE1, colE1, nullptr, tmpG, NG, 1);
    rowop_k<0><<<gNG64, blk, 0, stream>>>(tmpG, lp_ngn, nullptr, midG, NG);
    gemm128_k<<<gNG64, blk, 0, stream>>>(midG, lp_m1w, 128, tmpG, NG);
    rowop_k<0><<<gNG64, blk, 0, stream>>>(tmpG, lp_m1gn, nullptr, midG, NG);
    gemm128_k<<<gNG64, blk, 0, stream>>>(midG, lp_m2w, 128, tmpG, NG);
    rowop_k<0><<<gNG64, blk, 0, stream>>>(tmpG, lp_m2gn, nullptr, gfeat, NG);

    // ============================ global_graph ==============================
    for (int i = 0; i < 4; ++i) {
        gather_gemm_k<true,false,false><<<gNG64, blk, 0, stream>>>(
            gfeat, gfeat,
            f_psw + (size_t)i * 12 * 16384, f_lw + (size_t)i * 16384,
            f_rw + (size_t)i * 16384, f_ctrw + (size_t)i * 16384,
            rp14, col14, nullptr, tmpG, NG, 14);
        rowop_k<0><<<gNG64, blk, 0, stream>>>(
            tmpG, f_ngn + (size_t)i * 256, nullptr, midG, NG);
        gemm128_k<<<gNG64, blk, 0, stream>>>(
            midG, f_c2w + (size_t)i * 16384, 128, tmpG, NG);
        rowop_k<2><<<gNG64, blk, 0, stream>>>(
            tmpG, f_c2gn + (size_t)i * 256, gfeat, gfeat, NG);
    }

    // ============ lane_pooling #2 (graph -> roi), identity = roi_feat =======
    gemm128_k<<<gNG64, blk, 0, stream>>>(gfeat, lp_c1w + 32768, 256, tmpG, NG); // prectxG
    gemm128_k<<<gNR64, blk, 0, stream>>>(roi_feat, lp_input_w + 16384, 128, preN, NR); // tR
    gemmdist2_k<<<gE64, blk, 0, stream>>>(
        e2_hi, e2_wi, graph_pose, roi_pose, lp_rpw + 512, lp_rpb + 128,
        lp_c1w + 32768 + 128, tmpG, lp_c1gn + 256, hbuf, E2_N);
    gather_gemm_k<false,true,true><<<gNR64, blk, 0, stream>>>(
        hbuf, nullptr, lp_c2w + 16384, nullptr, nullptr, nullptr,
        rpE2, colE2, preN, preN2, NR, 1);
    rowop_k<0><<<gNR64, blk, 0, stream>>>(preN2, lp_ngn + 256, nullptr, preN, NR);
    gemm128_k<<<gNR64, blk, 0, stream>>>(preN, lp_m1w + 16384, 128, preN2, NR);
    rowop_k<0><<<gNR64, blk, 0, stream>>>(preN2, lp_m1gn + 256, nullptr, preN, NR);
    gemm128_k<<<gNR64, blk, 0, stream>>>(preN, lp_m2w + 16384, 128, preN2, NR);
    rowop_k<2><<<gNR64, blk, 0, stream>>>(preN2, lp_m2gn + 256, roi_feat, out, NR);
}

// Round 4
// 2179.841 us; speedup vs baseline: 1.0907x; 1.0907x over previous
//
#include <hip/hip_runtime.h>

#define NG 50000
#define NR 12000
#define EPS_N 50000
#define ELR_N 5000
#define E1_N 150000
#define E2_N 150000
#define GN_EPS_F 1e-5f
#define SCAN_CHUNK 4096

typedef __attribute__((ext_vector_type(8))) __bf16 bf16x8;
typedef __attribute__((ext_vector_type(4))) float f32x4;

__device__ __forceinline__ bf16x8 cvt8(const float* __restrict__ p) {
    float4 x0 = *reinterpret_cast<const float4*>(p);
    float4 x1 = *reinterpret_cast<const float4*>(p + 4);
    bf16x8 a;
    a[0] = (__bf16)x0.x; a[1] = (__bf16)x0.y; a[2] = (__bf16)x0.z; a[3] = (__bf16)x0.w;
    a[4] = (__bf16)x1.x; a[5] = (__bf16)x1.y; a[6] = (__bf16)x1.z; a[7] = (__bf16)x1.w;
    return a;
}

__device__ __forceinline__ bf16x8 ldA(const float* __restrict__ p) { return cvt8(p); }
__device__ __forceinline__ bf16x8 ldA(const __bf16* __restrict__ p) {
    return *reinterpret_cast<const bf16x8*>(p);
}

// ============================ CSR construction =============================
__global__ void hist14_k(const int* __restrict__ ps_u, const int* __restrict__ lr_u,
                         int* __restrict__ cnt)
{
    int t = blockIdx.x * 256 + threadIdx.x;
    const int total = 12 * EPS_N + 2 * ELR_N;
    if (t >= total) return;
    int k, u;
    if (t < 12 * EPS_N) { k = t / EPS_N; u = ps_u[t]; }
    else { int r = t - 12 * EPS_N; k = 12 + r / ELR_N; u = lr_u[r]; }
    atomicAdd(&cnt[k * NG + u], 1);
}

__global__ void fill14_k(const int* __restrict__ ps_u, const int* __restrict__ ps_v,
                         const int* __restrict__ lr_u, const int* __restrict__ lr_v,
                         int* __restrict__ head, int* __restrict__ col)
{
    int t = blockIdx.x * 256 + threadIdx.x;
    const int total = 12 * EPS_N + 2 * ELR_N;
    if (t >= total) return;
    int k, u, v;
    if (t < 12 * EPS_N) { k = t / EPS_N; u = ps_u[t]; v = ps_v[t]; }
    else { int r = t - 12 * EPS_N; k = 12 + r / ELR_N; u = lr_u[r]; v = lr_v[r]; }
    int pos = atomicAdd(&head[k * NG + u], 1);
    col[pos] = v;
}

__global__ void histE_k(const int* __restrict__ wi, int n, int* __restrict__ cnt)
{
    int t = blockIdx.x * 256 + threadIdx.x;
    if (t >= n) return;
    atomicAdd(&cnt[wi[t]], 1);
}

__global__ void fillE_k(const int* __restrict__ wi, int n,
                        int* __restrict__ head, int* __restrict__ col)
{
    int t = blockIdx.x * 256 + threadIdx.x;
    if (t >= n) return;
    int pos = atomicAdd(&head[wi[t]], 1);
    col[pos] = t;   // payload = edge id
}

__global__ void scan1_k(const int* __restrict__ in, int n, int* __restrict__ bsum)
{
    __shared__ int sm[4];
    int base = blockIdx.x * SCAN_CHUNK;
    int s = 0;
    for (int i = threadIdx.x; i < SCAN_CHUNK; i += 256) {
        int idx = base + i;
        s += (idx < n) ? in[idx] : 0;
    }
    #pragma unroll
    for (int off = 1; off < 64; off <<= 1) s += __shfl_xor(s, off);
    if ((threadIdx.x & 63) == 0) sm[threadIdx.x >> 6] = s;
    __syncthreads();
    if (threadIdx.x == 0) bsum[blockIdx.x] = sm[0] + sm[1] + sm[2] + sm[3];
}

__global__ void scan2_k(int* __restrict__ bsum, int nb)
{
    if (threadIdx.x == 0) {
        int acc = 0;
        for (int i = 0; i < nb; ++i) { int t = bsum[i]; bsum[i] = acc; acc += t; }
    }
}

__global__ void scan3_k(const int* __restrict__ in, int n,
                        const int* __restrict__ bsum, int* __restrict__ outp)
{
    __shared__ int sm[256];
    int base = blockIdx.x * SCAN_CHUNK;
    int loc[16]; int s = 0;
    #pragma unroll
    for (int i = 0; i < 16; ++i) {
        int idx = base + threadIdx.x * 16 + i;
        loc[i] = (idx < n) ? in[idx] : 0; s += loc[i];
    }
    sm[threadIdx.x] = s; __syncthreads();
    for (int off = 1; off < 256; off <<= 1) {
        int v = (threadIdx.x >= off) ? sm[threadIdx.x - off] : 0;
        __syncthreads();
        sm[threadIdx.x] += v;
        __syncthreads();
    }
    int tp = (threadIdx.x ? sm[threadIdx.x - 1] : 0) + bsum[blockIdx.x];
    #pragma unroll
    for (int i = 0; i < 16; ++i) {
        int idx = base + threadIdx.x * 16 + i;
        if (idx < n) outp[idx] = tp;
        tp += loc[i];
        if (idx == n - 1) outp[n] = tp;
    }
}

// ====================== segment sums (no atomics) ==========================
// segsum14_k: Sbuf[j][u][:] = sum_{v in CSR row (kb0+j, u)} feat[v][:]  (bf16)
//             block 14 (self) = feat[u] copy. One thread = 32-col slice.
__launch_bounds__(256)
__global__ void segsum14_k(const float* __restrict__ feat,
                           const int* __restrict__ rp, const int* __restrict__ col,
                           int kb0, __bf16* __restrict__ Sbuf, int M)
{
    const int t = threadIdx.x;
    const int u = blockIdx.x * 64 + (t >> 2);
    if (u >= M) return;
    const int q = t & 3;
    const int k = kb0 + blockIdx.y;
    float ss[32];
    #pragma unroll
    for (int i = 0; i < 32; ++i) ss[i] = 0.f;

    if (k == 14) {
        const float* sp = feat + (size_t)u * 128 + q * 32;
        #pragma unroll
        for (int i = 0; i < 8; ++i) {
            float4 x = *reinterpret_cast<const float4*>(sp + i * 4);
            ss[i*4+0] = x.x; ss[i*4+1] = x.y; ss[i*4+2] = x.z; ss[i*4+3] = x.w;
        }
    } else {
        const int beg = rp[k * M + u], end = rp[k * M + u + 1];
        for (int j = beg; j < end; ++j) {
            const float* sp = feat + (size_t)col[j] * 128 + q * 32;
            #pragma unroll
            for (int i = 0; i < 8; ++i) {
                float4 x = *reinterpret_cast<const float4*>(sp + i * 4);
                ss[i*4+0] += x.x; ss[i*4+1] += x.y; ss[i*4+2] += x.z; ss[i*4+3] += x.w;
            }
        }
    }
    __bf16* dp = Sbuf + (size_t)blockIdx.y * M * 128 + (size_t)u * 128 + q * 32;
    #pragma unroll
    for (int i = 0; i < 4; ++i) {
        bf16x8 o;
        #pragma unroll
        for (int e = 0; e < 8; ++e) o[e] = (__bf16)ss[i * 8 + e];
        *reinterpret_cast<bf16x8*>(dp + i * 8) = o;
    }
}

// segsumE_k: Ebuf[u][:] = sum_{edge j in CSR row u} hsrc[col[j]][:]   (bf16)
// LPR lanes per row (each owns 128/LPR cols).
template<int LPR>
__launch_bounds__(256)
__global__ void segsumE_k(const __bf16* __restrict__ hsrc,
                          const int* __restrict__ rp, const int* __restrict__ col,
                          __bf16* __restrict__ Ebuf, int M)
{
    const int t = threadIdx.x;
    const int u = blockIdx.x * (256 / LPR) + t / LPR;
    if (u >= M) return;
    const int q = t % LPR;
    constexpr int NC = 128 / LPR;          // cols per lane
    float ss[NC];
    #pragma unroll
    for (int i = 0; i < NC; ++i) ss[i] = 0.f;

    const int beg = rp[u], end = rp[u + 1];
    for (int j = beg; j < end; ++j) {
        const __bf16* sp = hsrc + (size_t)col[j] * 128 + q * NC;
        #pragma unroll
        for (int i = 0; i < NC / 8; ++i) {
            bf16x8 h = *reinterpret_cast<const bf16x8*>(sp + i * 8);
            #pragma unroll
            for (int e = 0; e < 8; ++e) ss[i * 8 + e] += (float)h[e];
        }
    }
    __bf16* dp = Ebuf + (size_t)u * 128 + q * NC;
    #pragma unroll
    for (int i = 0; i < NC / 8; ++i) {
        bf16x8 o;
        #pragma unroll
        for (int e = 0; e < 8; ++e) o[e] = (__bf16)ss[i * 8 + e];
        *reinterpret_cast<bf16x8*>(dp + i * 8) = o;
    }
}

// ==================== dense GEMM + fused epilogues =========================
// C[M,128] = A[M,128] @ W[128,128]^T, 4 waves 2x2, BM=64, BN=128.
// EPI: 0 raw store; 1 relu(gn(x,sb)); 2 relu(gn(x + addp[row], sb));
//      3 relu(gn(x,sb) + addp[row])
template<typename AT, int EPI>
__launch_bounds__(256)
__global__ void gemm128e_k(const AT* __restrict__ A,
                           const float* __restrict__ W, int wrs,
                           const float* __restrict__ sb,
                           const float* __restrict__ addp,
                           float* __restrict__ outp, int M)
{
    __shared__ float smS[2][64], smQ[2][64];
    const int tid = threadIdx.x;
    const int lane = tid & 63;
    const int wave = tid >> 6;
    const int waveM = wave >> 1, waveN = wave & 1;
    const int r16 = lane & 15, kq = lane >> 4;
    const int mbase = blockIdx.x * 64 + waveM * 32;

    bf16x8 b[4][4];
    #pragma unroll
    for (int ni = 0; ni < 4; ++ni) {
        const int colc = waveN * 64 + ni * 16 + r16;
        #pragma unroll
        for (int ks = 0; ks < 4; ++ks)
            b[ni][ks] = cvt8(W + (size_t)colc * wrs + ks * 32 + kq * 8);
    }
    int asrc[2];
    #pragma unroll
    for (int mi = 0; mi < 2; ++mi) {
        int r = mbase + mi * 16 + r16;
        asrc[mi] = r < M ? r : M - 1;
    }
    f32x4 acc[2][4];
    #pragma unroll
    for (int mi = 0; mi < 2; ++mi)
        #pragma unroll
        for (int ni = 0; ni < 4; ++ni)
            acc[mi][ni] = (f32x4){0.f, 0.f, 0.f, 0.f};

    #pragma unroll
    for (int ks = 0; ks < 4; ++ks) {
        bf16x8 a[2];
        #pragma unroll
        for (int mi = 0; mi < 2; ++mi)
            a[mi] = ldA(A + (size_t)asrc[mi] * 128 + ks * 32 + kq * 8);
        #pragma unroll
        for (int mi = 0; mi < 2; ++mi)
            #pragma unroll
            for (int ni = 0; ni < 4; ++ni)
                acc[mi][ni] = __builtin_amdgcn_mfma_f32_16x16x32_bf16(
                    a[mi], b[ni][ks], acc[mi][ni], 0, 0, 0);
    }

    if (EPI == 0) {
        #pragma unroll
        for (int mi = 0; mi < 2; ++mi) {
            const int rb = mbase + mi * 16 + kq * 4;
            #pragma unroll
            for (int reg = 0; reg < 4; ++reg) {
                const int crow = rb + reg;
                if (crow >= M) continue;
                float* dst = outp + (size_t)crow * 128 + waveN * 64 + r16;
                #pragma unroll
                for (int ni = 0; ni < 4; ++ni) dst[ni * 16] = acc[mi][ni][reg];
            }
        }
        return;
    }

    if (EPI == 2) {   // pre-GN add
        #pragma unroll
        for (int mi = 0; mi < 2; ++mi) {
            const int rb = mbase + mi * 16 + kq * 4;
            #pragma unroll
            for (int reg = 0; reg < 4; ++reg) {
                const int crow = rb + reg;
                const int cr = crow < M ? crow : M - 1;
                const float* ap = addp + (size_t)cr * 128 + waveN * 64 + r16;
                #pragma unroll
                for (int ni = 0; ni < 4; ++ni)
                    acc[mi][ni][reg] += ap[ni * 16];
            }
        }
    }

    // cross-wave GroupNorm stats
    #pragma unroll
    for (int mi = 0; mi < 2; ++mi) {
        #pragma unroll
        for (int reg = 0; reg < 4; ++reg) {
            float s = acc[mi][0][reg] + acc[mi][1][reg] + acc[mi][2][reg] + acc[mi][3][reg];
            float q = acc[mi][0][reg]*acc[mi][0][reg] + acc[mi][1][reg]*acc[mi][1][reg]
                    + acc[mi][2][reg]*acc[mi][2][reg] + acc[mi][3][reg]*acc[mi][3][reg];
            #pragma unroll
            for (int off = 1; off < 16; off <<= 1) {
                s += __shfl_xor(s, off);
                q += __shfl_xor(q, off);
            }
            if (r16 == 0) {
                int lr = waveM * 32 + mi * 16 + kq * 4 + reg;
                smS[waveN][lr] = s; smQ[waveN][lr] = q;
            }
        }
    }
    __syncthreads();

    #pragma unroll
    for (int mi = 0; mi < 2; ++mi) {
        #pragma unroll
        for (int reg = 0; reg < 4; ++reg) {
            const int lr = waveM * 32 + mi * 16 + kq * 4 + reg;
            const float S = smS[0][lr] + smS[1][lr];
            const float Q = smQ[0][lr] + smQ[1][lr];
            const float m = S * (1.f / 128.f);
            const float inv = rsqrtf(fmaxf(Q * (1.f / 128.f) - m * m, 0.f) + GN_EPS_F);
            const int crow = mbase + mi * 16 + kq * 4 + reg;
            if (crow < M) {
                float* dst = outp + (size_t)crow * 128 + waveN * 64 + r16;
                const float* ap = (EPI == 3)
                    ? addp + (size_t)crow * 128 + waveN * 64 + r16 : nullptr;
                #pragma unroll
                for (int ni = 0; ni < 4; ++ni) {
                    const int colc = waveN * 64 + ni * 16 + r16;
                    float y = (acc[mi][ni][reg] - m) * inv * sb[colc] + sb[128 + colc];
                    if (EPI == 3) y += ap[ni * 16];
                    dst[ni * 16] = fmaxf(y, 0.f);
                }
            }
        }
    }
}

// gemmcat_k: acc += Sbuf[j] @ W_{kb0+j}^T for j=0..4  (A bf16, K=640/pass)
// ACC: add previous passes from temp. GN: final pass -> relu(gn(...,sb)) to outp,
// else raw store to temp.
template<bool ACC, bool GN>
__launch_bounds__(256)
__global__ void gemmcat_k(const __bf16* __restrict__ Sbuf,
                          const float* __restrict__ Wps,
                          const float* __restrict__ Wl,
                          const float* __restrict__ Wr,
                          const float* __restrict__ Wself,
                          int kb0,
                          const float* __restrict__ sb,
                          float* __restrict__ temp,
                          float* __restrict__ outp, int M)
{
    __shared__ float smS[2][64], smQ[2][64];
    const int tid = threadIdx.x;
    const int lane = tid & 63;
    const int wave = tid >> 6;
    const int waveM = wave >> 1, waveN = wave & 1;
    const int r16 = lane & 15, kq = lane >> 4;
    const int mbase = blockIdx.x * 64 + waveM * 32;

    int asrc[2];
    #pragma unroll
    for (int mi = 0; mi < 2; ++mi) {
        int r = mbase + mi * 16 + r16;
        asrc[mi] = r < M ? r : M - 1;
    }
    f32x4 acc[2][4];
    #pragma unroll
    for (int mi = 0; mi < 2; ++mi)
        #pragma unroll
        for (int ni = 0; ni < 4; ++ni)
            acc[mi][ni] = (f32x4){0.f, 0.f, 0.f, 0.f};

    #pragma unroll 1
    for (int j = 0; j < 5; ++j) {
        const int kk = kb0 + j;
        const float* Wk = (kk < 12) ? Wps + (size_t)kk * 16384
                         : (kk == 12 ? Wl : (kk == 13 ? Wr : Wself));
        const __bf16* Ab = Sbuf + (size_t)j * M * 128;

        bf16x8 b[4][4];
        #pragma unroll
        for (int ni = 0; ni < 4; ++ni) {
            const int colc = waveN * 64 + ni * 16 + r16;
            #pragma unroll
            for (int ks = 0; ks < 4; ++ks)
                b[ni][ks] = cvt8(Wk + (size_t)colc * 128 + ks * 32 + kq * 8);
        }
        #pragma unroll
        for (int ks = 0; ks < 4; ++ks) {
            bf16x8 a[2];
            #pragma unroll
            for (int mi = 0; mi < 2; ++mi)
                a[mi] = *reinterpret_cast<const bf16x8*>(
                    Ab + (size_t)asrc[mi] * 128 + ks * 32 + kq * 8);
            #pragma unroll
            for (int mi = 0; mi < 2; ++mi)
                #pragma unroll
                for (int ni = 0; ni < 4; ++ni)
                    acc[mi][ni] = __builtin_amdgcn_mfma_f32_16x16x32_bf16(
                        a[mi], b[ni][ks], acc[mi][ni], 0, 0, 0);
        }
    }

    if (ACC) {
        #pragma unroll
        for (int mi = 0; mi < 2; ++mi) {
            const int rb = mbase + mi * 16 + kq * 4;
            #pragma unroll
            for (int reg = 0; reg < 4; ++reg) {
                const int crow = rb + reg;
                const int cr = crow < M ? crow : M - 1;
                const float* tp = temp + (size_t)cr * 128 + waveN * 64 + r16;
                #pragma unroll
                for (int ni = 0; ni < 4; ++ni)
                    acc[mi][ni][reg] += tp[ni * 16];
            }
        }
    }

    if (!GN) {
        #pragma unroll
        for (int mi = 0; mi < 2; ++mi) {
            const int rb = mbase + mi * 16 + kq * 4;
            #pragma unroll
            for (int reg = 0; reg < 4; ++reg) {
                const int crow = rb + reg;
                if (crow >= M) continue;
                float* dst = temp + (size_t)crow * 128 + waveN * 64 + r16;
                #pragma unroll
                for (int ni = 0; ni < 4; ++ni) dst[ni * 16] = acc[mi][ni][reg];
            }
        }
        return;
    }

    #pragma unroll
    for (int mi = 0; mi < 2; ++mi) {
        #pragma unroll
        for (int reg = 0; reg < 4; ++reg) {
            float s = acc[mi][0][reg] + acc[mi][1][reg] + acc[mi][2][reg] + acc[mi][3][reg];
            float q = acc[mi][0][reg]*acc[mi][0][reg] + acc[mi][1][reg]*acc[mi][1][reg]
                    + acc[mi][2][reg]*acc[mi][2][reg] + acc[mi][3][reg]*acc[mi][3][reg];
            #pragma unroll
            for (int off = 1; off < 16; off <<= 1) {
                s += __shfl_xor(s, off);
                q += __shfl_xor(q, off);
            }
            if (r16 == 0) {
                int lr = waveM * 32 + mi * 16 + kq * 4 + reg;
                smS[waveN][lr] = s; smQ[waveN][lr] = q;
            }
        }
    }
    __syncthreads();
    #pragma unroll
    for (int mi = 0; mi < 2; ++mi) {
        #pragma unroll
        for (int reg = 0; reg < 4; ++reg) {
            const int lr = waveM * 32 + mi * 16 + kq * 4 + reg;
            const float S = smS[0][lr] + smS[1][lr];
            const float Q = smQ[0][lr] + smQ[1][lr];
            const float m = S * (1.f / 128.f);
            const float inv = rsqrtf(fmaxf(Q * (1.f / 128.f) - m * m, 0.f) + GN_EPS_F);
            const int crow = mbase + mi * 16 + kq * 4 + reg;
            if (crow < M) {
                float* dst = outp + (size_t)crow * 128 + waveN * 64 + r16;
                #pragma unroll
                for (int ni = 0; ni < 4; ++ni) {
                    const int colc = waveN * 64 + ni * 16 + r16;
                    float y = (acc[mi][ni][reg] - m) * inv * sb[colc] + sb[128 + colc];
                    dst[ni * 16] = fmaxf(y, 0.f);
                }
            }
        }
    }
}

// ========== gemmdist2: on-the-fly dist GEMM + prectx add + GN + relu =======
__launch_bounds__(256)
__global__ void gemmdist2_k(const int* __restrict__ hi_idx, const int* __restrict__ wi_idx,
                            const float* __restrict__ cpose, const float* __restrict__ tpose,
                            const float* __restrict__ rpw, const float* __restrict__ rpb,
                            const float* __restrict__ Wb,      // c1B, stride 256
                            const float* __restrict__ prectx,
                            const float* __restrict__ sb,
                            __bf16* __restrict__ hout, int M)
{
    __shared__ float rw[128 * 4 + 128];
    __shared__ float smS[2][64], smQ[2][64];
    const int tid = threadIdx.x;
    for (int i = tid; i < 640; i += 256)
        rw[i] = (i < 512) ? rpw[i] : rpb[i - 512];
    __syncthreads();

    const int lane = tid & 63;
    const int wave = tid >> 6;
    const int waveM = wave >> 1, waveN = wave & 1;
    const int r16 = lane & 15, kq = lane >> 4;
    const int mbase = blockIdx.x * 64 + waveM * 32;

    bf16x8 b[4][4];
    #pragma unroll
    for (int ni = 0; ni < 4; ++ni) {
        const int colc = waveN * 64 + ni * 16 + r16;
        #pragma unroll
        for (int ks = 0; ks < 4; ++ks)
            b[ni][ks] = cvt8(Wb + (size_t)colc * 256 + ks * 32 + kq * 8);
    }

    float dl[2][4];
    #pragma unroll
    for (int mi = 0; mi < 2; ++mi) {
        int r = mbase + mi * 16 + r16;
        int e = r < M ? r : M - 1;
        int hi = hi_idx[e], wi = wi_idx[e];
        float4 cp = *reinterpret_cast<const float4*>(cpose + (size_t)hi * 4);
        float4 tp = *reinterpret_cast<const float4*>(tpose + (size_t)wi * 4);
        dl[mi][0] = cp.x - tp.x; dl[mi][1] = cp.y - tp.y;
        dl[mi][2] = cp.z - tp.z; dl[mi][3] = cp.w - tp.w;
    }

    f32x4 acc[2][4];
    #pragma unroll
    for (int mi = 0; mi < 2; ++mi)
        #pragma unroll
        for (int ni = 0; ni < 4; ++ni)
            acc[mi][ni] = (f32x4){0.f, 0.f, 0.f, 0.f};

    #pragma unroll
    for (int ks = 0; ks < 4; ++ks) {
        bf16x8 a[2];
        #pragma unroll
        for (int mi = 0; mi < 2; ++mi) {
            #pragma unroll
            for (int i = 0; i < 8; ++i) {
                const int k = ks * 32 + kq * 8 + i;
                float4 w4 = *reinterpret_cast<const float4*>(&rw[k * 4]);
                float d = fmaf(dl[mi][0], w4.x, fmaf(dl[mi][1], w4.y,
                          fmaf(dl[mi][2], w4.z, fmaf(dl[mi][3], w4.w, rw[512 + k]))));
                a[mi][i] = (__bf16)fmaxf(d, 0.f);
            }
        }
        #pragma unroll
        for (int mi = 0; mi < 2; ++mi)
            #pragma unroll
            for (int ni = 0; ni < 4; ++ni)
                acc[mi][ni] = __builtin_amdgcn_mfma_f32_16x16x32_bf16(
                    a[mi], b[ni][ks], acc[mi][ni], 0, 0, 0);
    }

    // add prectx[hi[crow]]
    #pragma unroll
    for (int mi = 0; mi < 2; ++mi) {
        const int rb = mbase + mi * 16 + kq * 4;
        #pragma unroll
        for (int reg = 0; reg < 4; ++reg) {
            const int crow = rb + reg;
            const int e = crow < M ? crow : M - 1;
            const int hrow = hi_idx[e];
            const float* pp = prectx + (size_t)hrow * 128 + waveN * 64 + r16;
            #pragma unroll
            for (int ni = 0; ni < 4; ++ni)
                acc[mi][ni][reg] += pp[ni * 16];
        }
    }

    #pragma unroll
    for (int mi = 0; mi < 2; ++mi) {
        #pragma unroll
        for (int reg = 0; reg < 4; ++reg) {
            float s = acc[mi][0][reg] + acc[mi][1][reg] + acc[mi][2][reg] + acc[mi][3][reg];
            float q = acc[mi][0][reg]*acc[mi][0][reg] + acc[mi][1][reg]*acc[mi][1][reg]
                    + acc[mi][2][reg]*acc[mi][2][reg] + acc[mi][3][reg]*acc[mi][3][reg];
            #pragma unroll
            for (int off = 1; off < 16; off <<= 1) {
                s += __shfl_xor(s, off);
                q += __shfl_xor(q, off);
            }
            if (r16 == 0) {
                int lr = waveM * 32 + mi * 16 + kq * 4 + reg;
                smS[waveN][lr] = s; smQ[waveN][lr] = q;
            }
        }
    }
    __syncthreads();

    #pragma unroll
    for (int mi = 0; mi < 2; ++mi) {
        #pragma unroll
        for (int reg = 0; reg < 4; ++reg) {
            const int lr = waveM * 32 + mi * 16 + kq * 4 + reg;
            const float S = smS[0][lr] + smS[1][lr];
            const float Q = smQ[0][lr] + smQ[1][lr];
            const float m = S * (1.f / 128.f);
            const float inv = rsqrtf(fmaxf(Q * (1.f / 128.f) - m * m, 0.f) + GN_EPS_F);
            const int crow = mbase + mi * 16 + kq * 4 + reg;
            if (crow < M) {
                __bf16* dp = hout + (size_t)crow * 128 + waveN * 64 + r16;
                #pragma unroll
                for (int ni = 0; ni < 4; ++ni) {
                    const int colc = waveN * 64 + ni * 16 + r16;
                    float y = (acc[mi][ni][reg] - m) * inv * sb[colc] + sb[128 + colc];
                    dp[ni * 16] = (__bf16)fmaxf(y, 0.f);
                }
            }
        }
    }
}

// ===========================================================================
extern "C" void kernel_launch(void* const* d_in, const int* in_sizes, int n_in,
                              void* d_out, int out_size, void* d_ws, size_t ws_size,
                              hipStream_t stream)
{
    const float* roi_feat   = (const float*)d_in[0];
    const float* graph_pose = (const float*)d_in[1];
    const float* roi_pose   = (const float*)d_in[2];
    const float* lp_input_w = (const float*)d_in[3];
    const float* lp_rpw     = (const float*)d_in[4];
    const float* lp_rpb     = (const float*)d_in[5];
    const float* lp_c1w     = (const float*)d_in[6];
    const float* lp_c1gn    = (const float*)d_in[7];
    const float* lp_c2w     = (const float*)d_in[8];
    const float* lp_m1w     = (const float*)d_in[9];
    const float* lp_m1gn    = (const float*)d_in[10];
    const float* lp_m2w     = (const float*)d_in[11];
    const float* lp_m2gn    = (const float*)d_in[12];
    const float* lp_ngn     = (const float*)d_in[13];
    const float* f_ctrw     = (const float*)d_in[14];
    const float* f_psw      = (const float*)d_in[15];
    const float* f_lw       = (const float*)d_in[16];
    const float* f_rw       = (const float*)d_in[17];
    const float* f_ngn      = (const float*)d_in[18];
    const float* f_c2w      = (const float*)d_in[19];
    const float* f_c2gn     = (const float*)d_in[20];
    const int* e1_hi = (const int*)d_in[21];
    const int* e1_wi = (const int*)d_in[22];
    const int* e2_hi = (const int*)d_in[23];
    const int* e2_wi = (const int*)d_in[24];
    const int* ps_u  = (const int*)d_in[25];
    const int* ps_v  = (const int*)d_in[26];
    const int* lr_u  = (const int*)d_in[27];
    const int* lr_v  = (const int*)d_in[28];
    float* out = (float*)d_out;

    // ---- workspace layout (~163 MB) ----
    float* gfeat = (float*)d_ws;                        // NG*128 f32
    float* tmpG  = gfeat + (size_t)NG * 128;            // NG*128 f32
    float* midG  = tmpG  + (size_t)NG * 128;            // NG*128 f32
    float* preN  = midG  + (size_t)NG * 128;            // NR*128 f32
    float* preN2 = preN  + (size_t)NR * 128;            // NR*128 f32
    __bf16* ubuf = (__bf16*)(preN2 + (size_t)NR * 128); // union: 5*NG*128 bf16 (64MB)
    __bf16* hbuf = ubuf;                                // E_N*128 bf16 (38.4MB)
    __bf16* Sbuf = ubuf;                                // fusion S chunks (64MB)
    __bf16* Ebuf = ubuf + (size_t)E1_N * 128;           // NG*128 bf16 (12.8MB)
    int* ip      = (int*)(ubuf + (size_t)5 * NG * 128);
    int* cnt14   = ip;             ip += 14 * NG;
    int* rp14    = ip;             ip += 14 * NG + 1;
    int* col14   = ip;             ip += 12 * EPS_N + 2 * ELR_N;
    int* cntE1   = ip;             ip += NG;
    int* rpE1    = ip;             ip += NG + 1;
    int* colE1   = ip;             ip += E1_N;
    int* cntE2   = ip;             ip += NR;
    int* rpE2    = ip;             ip += NR + 1;
    int* colE2   = ip;             ip += E2_N;
    int* bsum    = ip;             ip += 256;

    dim3 blk(256);
    const dim3 gNG64((NG + 63) / 64), gNR64((NR + 63) / 64), gE64((E1_N + 63) / 64);
    const dim3 gS14((NG + 63) / 64, 5);
    const int NE14 = 12 * EPS_N + 2 * ELR_N;
    const dim3 gH14((NE14 + 255) / 256);

    // ======================== CSR builds (once/call) ========================
    hipMemsetAsync(cnt14, 0, (size_t)14 * NG * 4, stream);
    hist14_k<<<gH14, blk, 0, stream>>>(ps_u, lr_u, cnt14);
    {
        int n = 14 * NG, nb = (n + SCAN_CHUNK - 1) / SCAN_CHUNK;
        scan1_k<<<nb, blk, 0, stream>>>(cnt14, n, bsum);
        scan2_k<<<1, blk, 0, stream>>>(bsum, nb);
        scan3_k<<<nb, blk, 0, stream>>>(cnt14, n, bsum, rp14);
    }
    hipMemcpyAsync(cnt14, rp14, (size_t)14 * NG * 4, hipMemcpyDeviceToDevice, stream);
    fill14_k<<<gH14, blk, 0, stream>>>(ps_u, ps_v, lr_u, lr_v, cnt14, col14);

    hipMemsetAsync(cntE1, 0, (size_t)NG * 4, stream);
    histE_k<<<(E1_N + 255) / 256, blk, 0, stream>>>(e1_wi, E1_N, cntE1);
    {
        int n = NG, nb = (n + SCAN_CHUNK - 1) / SCAN_CHUNK;
        scan1_k<<<nb, blk, 0, stream>>>(cntE1, n, bsum);
        scan2_k<<<1, blk, 0, stream>>>(bsum, nb);
        scan3_k<<<nb, blk, 0, stream>>>(cntE1, n, bsum, rpE1);
    }
    hipMemcpyAsync(cntE1, rpE1, (size_t)NG * 4, hipMemcpyDeviceToDevice, stream);
    fillE_k<<<(E1_N + 255) / 256, blk, 0, stream>>>(e1_wi, E1_N, cntE1, colE1);

    hipMemsetAsync(cntE2, 0, (size_t)NR * 4, stream);
    histE_k<<<(E2_N + 255) / 256, blk, 0, stream>>>(e2_wi, E2_N, cntE2);
    {
        int n = NR, nb = (n + SCAN_CHUNK - 1) / SCAN_CHUNK;
        scan1_k<<<nb, blk, 0, stream>>>(cntE2, n, bsum);
        scan2_k<<<1, blk, 0, stream>>>(bsum, nb);
        scan3_k<<<nb, blk, 0, stream>>>(cntE2, n, bsum, rpE2);
    }
    hipMemcpyAsync(cntE2, rpE2, (size_t)NR * 4, hipMemcpyDeviceToDevice, stream);
    fillE_k<<<(E2_N + 255) / 256, blk, 0, stream>>>(e2_wi, E2_N, cntE2, colE2);

    // ============== lane_pooling #1 (roi -> graph), tgt_feat = 0 ============
    gemm128e_k<float,0><<<gNR64, blk, 0, stream>>>(
        roi_feat, lp_c1w, 256, nullptr, nullptr, preN, NR);          // prectx1
    gemmdist2_k<<<gE64, blk, 0, stream>>>(
        e1_hi, e1_wi, roi_pose, graph_pose, lp_rpw, lp_rpb,
        lp_c1w + 128, preN, lp_c1gn, hbuf, E1_N);
    segsumE_k<4><<<gNG64, blk, 0, stream>>>(hbuf, rpE1, colE1, Ebuf, NG);
    gemm128e_k<__bf16,1><<<gNG64, blk, 0, stream>>>(
        Ebuf, lp_c2w, 128, lp_ngn, nullptr, midG, NG);
    gemm128e_k<float,1><<<gNG64, blk, 0, stream>>>(
        midG, lp_m1w, 128, lp_m1gn, nullptr, tmpG, NG);
    gemm128e_k<float,1><<<gNG64, blk, 0, stream>>>(
        tmpG, lp_m2w, 128, lp_m2gn, nullptr, gfeat, NG);

    // ============================ global_graph ==============================
    for (int i = 0; i < 4; ++i) {
        const float* Wps = f_psw + (size_t)i * 12 * 16384;
        const float* Wl  = f_lw  + (size_t)i * 16384;
        const float* Wr  = f_rw  + (size_t)i * 16384;
        const float* Wc  = f_ctrw + (size_t)i * 16384;
        for (int p = 0; p < 3; ++p) {
            const int kb0 = 5 * p;
            segsum14_k<<<gS14, blk, 0, stream>>>(gfeat, rp14, col14, kb0, Sbuf, NG);
            if (p == 0)
                gemmcat_k<false,false><<<gNG64, blk, 0, stream>>>(
                    Sbuf, Wps, Wl, Wr, Wc, kb0, nullptr, tmpG, nullptr, NG);
            else if (p == 1)
                gemmcat_k<true,false><<<gNG64, blk, 0, stream>>>(
                    Sbuf, Wps, Wl, Wr, Wc, kb0, nullptr, tmpG, nullptr, NG);
            else
                gemmcat_k<true,true><<<gNG64, blk, 0, stream>>>(
                    Sbuf, Wps, Wl, Wr, Wc, kb0, f_ngn + (size_t)i * 256,
                    tmpG, midG, NG);
        }
        gemm128e_k<float,3><<<gNG64, blk, 0, stream>>>(
            midG, f_c2w + (size_t)i * 16384, 128, f_c2gn + (size_t)i * 256,
            gfeat, gfeat, NG);
    }

    // ============ lane_pooling #2 (graph -> roi), identity = roi_feat =======
    gemm128e_k<float,0><<<gNG64, blk, 0, stream>>>(
        gfeat, lp_c1w + 32768, 256, nullptr, nullptr, tmpG, NG);     // prectxG
    gemm128e_k<float,0><<<gNR64, blk, 0, stream>>>(
        roi_feat, lp_input_w + 16384, 128, nullptr, nullptr, preN, NR); // tR
    gemmdist2_k<<<gE64, blk, 0, stream>>>(
        e2_hi, e2_wi, graph_pose, roi_pose, lp_rpw + 512, lp_rpb + 128,
        lp_c1w + 32768 + 128, tmpG, lp_c1gn + 256, hbuf, E2_N);
    segsumE_k<8><<<dim3((NR + 31) / 32), blk, 0, stream>>>(hbuf, rpE2, colE2, Ebuf, NR);
    gemm128e_k<__bf16,2><<<gNR64, blk, 0, stream>>>(
        Ebuf, lp_c2w + 16384, 128, lp_ngn + 256, preN, preN2, NR);
    gemm128e_k<float,1><<<gNR64, blk, 0, stream>>>(
        preN2, lp_m1w + 16384, 128, lp_m1gn + 256, nullptr, tmpG, NR);
    gemm128e_k<float,3><<<gNR64, blk, 0, stream>>>(
        tmpG, lp_m2w + 16384, 128, lp_m2gn + 256, roi_feat, out, NR);
}

// Round 5
// 1113.890 us; speedup vs baseline: 2.1345x; 1.9570x over previous
//
#include <hip/hip_runtime.h>

#define NG 50000
#define NR 12000
#define EPS_N 50000
#define ELR_N 5000
#define E1_N 150000
#define E2_N 150000
#define GN_EPS_F 1e-5f
#define SCAN_CHUNK 4096

typedef __attribute__((ext_vector_type(8))) __bf16 bf16x8;
typedef __attribute__((ext_vector_type(4))) float f32x4;

__device__ __forceinline__ bf16x8 cvt8(const float* __restrict__ p) {
    float4 x0 = *reinterpret_cast<const float4*>(p);
    float4 x1 = *reinterpret_cast<const float4*>(p + 4);
    bf16x8 a;
    a[0] = (__bf16)x0.x; a[1] = (__bf16)x0.y; a[2] = (__bf16)x0.z; a[3] = (__bf16)x0.w;
    a[4] = (__bf16)x1.x; a[5] = (__bf16)x1.y; a[6] = (__bf16)x1.z; a[7] = (__bf16)x1.w;
    return a;
}
__device__ __forceinline__ bf16x8 ldA(const float* __restrict__ p) { return cvt8(p); }
__device__ __forceinline__ bf16x8 ldA(const __bf16* __restrict__ p) {
    return *reinterpret_cast<const bf16x8*>(p);
}
__device__ __forceinline__ float ldf(const float* p) { return *p; }
__device__ __forceinline__ float ldf(const __bf16* p) { return (float)*p; }

// ================= weight prep: f32 -> swizzled bf16 LDS image ==============
// image byte layout (per 128x128 matrix, 32 KB): row c (out-col) stride 256 B,
// 16B slot s at byte c*256 + (s ^ (c&7))*16 holds W[c][s*8 .. s*8+7] as bf16.
struct PrepTab { const float* src[80]; int stride[80]; int n; };

__global__ void prepw_k(PrepTab tab, __bf16* __restrict__ wbuf)
{
    int t = blockIdx.x * 256 + threadIdx.x;
    int w = t >> 11;                      // 2048 slots per matrix
    if (w >= tab.n) return;
    int rr = t & 2047, c = rr >> 4, slot = rr & 15;
    const float* s = tab.src[w] + (size_t)c * tab.stride[w] + slot * 8;
    bf16x8 o;
    #pragma unroll
    for (int e = 0; e < 8; ++e) o[e] = (__bf16)s[e];
    *reinterpret_cast<bf16x8*>(wbuf + (size_t)w * 16384 + c * 128 +
                               ((slot ^ (c & 7)) * 8)) = o;
}

// ============================ CSR construction =============================
__global__ void hist14_k(const int* __restrict__ ps_u, const int* __restrict__ lr_u,
                         int* __restrict__ cnt)
{
    int t = blockIdx.x * 256 + threadIdx.x;
    const int total = 12 * EPS_N + 2 * ELR_N;
    if (t >= total) return;
    int k, u;
    if (t < 12 * EPS_N) { k = t / EPS_N; u = ps_u[t]; }
    else { int r = t - 12 * EPS_N; k = 12 + r / ELR_N; u = lr_u[r]; }
    atomicAdd(&cnt[k * NG + u], 1);
}

__global__ void fill14_k(const int* __restrict__ ps_u, const int* __restrict__ ps_v,
                         const int* __restrict__ lr_u, const int* __restrict__ lr_v,
                         int* __restrict__ head, int* __restrict__ col)
{
    int t = blockIdx.x * 256 + threadIdx.x;
    const int total = 12 * EPS_N + 2 * ELR_N;
    if (t >= total) return;
    int k, u, v;
    if (t < 12 * EPS_N) { k = t / EPS_N; u = ps_u[t]; v = ps_v[t]; }
    else { int r = t - 12 * EPS_N; k = 12 + r / ELR_N; u = lr_u[r]; v = lr_v[r]; }
    int pos = atomicAdd(&head[k * NG + u], 1);
    col[pos] = v;
}

__global__ void histE_k(const int* __restrict__ wi, int n, int* __restrict__ cnt)
{
    int t = blockIdx.x * 256 + threadIdx.x;
    if (t >= n) return;
    atomicAdd(&cnt[wi[t]], 1);
}

__global__ void fillE_k(const int* __restrict__ wi, int n,
                        int* __restrict__ head, int* __restrict__ col)
{
    int t = blockIdx.x * 256 + threadIdx.x;
    if (t >= n) return;
    int pos = atomicAdd(&head[wi[t]], 1);
    col[pos] = t;
}

__global__ void scan1_k(const int* __restrict__ in, int n, int* __restrict__ bsum)
{
    __shared__ int sm[4];
    int base = blockIdx.x * SCAN_CHUNK;
    int s = 0;
    for (int i = threadIdx.x; i < SCAN_CHUNK; i += 256) {
        int idx = base + i;
        s += (idx < n) ? in[idx] : 0;
    }
    #pragma unroll
    for (int off = 1; off < 64; off <<= 1) s += __shfl_xor(s, off);
    if ((threadIdx.x & 63) == 0) sm[threadIdx.x >> 6] = s;
    __syncthreads();
    if (threadIdx.x == 0) bsum[blockIdx.x] = sm[0] + sm[1] + sm[2] + sm[3];
}

__global__ void scan2_k(int* __restrict__ bsum, int nb)
{
    if (threadIdx.x == 0) {
        int acc = 0;
        for (int i = 0; i < nb; ++i) { int t = bsum[i]; bsum[i] = acc; acc += t; }
    }
}

__global__ void scan3_k(const int* __restrict__ in, int n,
                        const int* __restrict__ bsum, int* __restrict__ outp)
{
    __shared__ int sm[256];
    int base = blockIdx.x * SCAN_CHUNK;
    int loc[16]; int s = 0;
    #pragma unroll
    for (int i = 0; i < 16; ++i) {
        int idx = base + threadIdx.x * 16 + i;
        loc[i] = (idx < n) ? in[idx] : 0; s += loc[i];
    }
    sm[threadIdx.x] = s; __syncthreads();
    for (int off = 1; off < 256; off <<= 1) {
        int v = (threadIdx.x >= off) ? sm[threadIdx.x - off] : 0;
        __syncthreads();
        sm[threadIdx.x] += v;
        __syncthreads();
    }
    int tp = (threadIdx.x ? sm[threadIdx.x - 1] : 0) + bsum[blockIdx.x];
    #pragma unroll
    for (int i = 0; i < 16; ++i) {
        int idx = base + threadIdx.x * 16 + i;
        if (idx < n) outp[idx] = tp;
        tp += loc[i];
        if (idx == n - 1) outp[n] = tp;
    }
}

// ====================== segment sums (no atomics) ==========================
__launch_bounds__(256)
__global__ void segsum14_k(const __bf16* __restrict__ feat,
                           const int* __restrict__ rp, const int* __restrict__ col,
                           int kb0, __bf16* __restrict__ Sbuf, int M)
{
    const int t = threadIdx.x;
    const int u = blockIdx.x * 64 + (t >> 2);
    if (u >= M) return;
    const int q = t & 3;
    const int k = kb0 + blockIdx.y;
    float ss[32];
    #pragma unroll
    for (int i = 0; i < 32; ++i) ss[i] = 0.f;

    const int beg = rp[k * M + u], end = rp[k * M + u + 1];
    for (int j = beg; j < end; ++j) {
        const __bf16* sp = feat + (size_t)col[j] * 128 + q * 32;
        #pragma unroll
        for (int i = 0; i < 4; ++i) {
            bf16x8 h = *reinterpret_cast<const bf16x8*>(sp + i * 8);
            #pragma unroll
            for (int e = 0; e < 8; ++e) ss[i * 8 + e] += (float)h[e];
        }
    }
    __bf16* dp = Sbuf + (size_t)blockIdx.y * M * 128 + (size_t)u * 128 + q * 32;
    #pragma unroll
    for (int i = 0; i < 4; ++i) {
        bf16x8 o;
        #pragma unroll
        for (int e = 0; e < 8; ++e) o[e] = (__bf16)ss[i * 8 + e];
        *reinterpret_cast<bf16x8*>(dp + i * 8) = o;
    }
}

template<int LPR>
__launch_bounds__(256)
__global__ void segsumE_k(const __bf16* __restrict__ hsrc,
                          const int* __restrict__ rp, const int* __restrict__ col,
                          __bf16* __restrict__ Ebuf, int M)
{
    const int t = threadIdx.x;
    const int u = blockIdx.x * (256 / LPR) + t / LPR;
    if (u >= M) return;
    const int q = t % LPR;
    constexpr int NC = 128 / LPR;
    float ss[NC];
    #pragma unroll
    for (int i = 0; i < NC; ++i) ss[i] = 0.f;

    const int beg = rp[u], end = rp[u + 1];
    for (int j = beg; j < end; ++j) {
        const __bf16* sp = hsrc + (size_t)col[j] * 128 + q * NC;
        #pragma unroll
        for (int i = 0; i < NC / 8; ++i) {
            bf16x8 h = *reinterpret_cast<const bf16x8*>(sp + i * 8);
            #pragma unroll
            for (int e = 0; e < 8; ++e) ss[i * 8 + e] += (float)h[e];
        }
    }
    __bf16* dp = Ebuf + (size_t)u * 128 + q * NC;
    #pragma unroll
    for (int i = 0; i < NC / 8; ++i) {
        bf16x8 o;
        #pragma unroll
        for (int e = 0; e < 8; ++e) o[e] = (__bf16)ss[i * 8 + e];
        *reinterpret_cast<bf16x8*>(dp + i * 8) = o;
    }
}

// ============= unified MFMA GEMM: C = sum_j A_j @ W_j^T (+epilogues) ========
// 256 thr = 4 waves 2(M)x2(N); BM=64, BN=128; W_j from swizzled wbuf via LDS.
// EPI: 0 raw->outp; 1 relu(gn(x)); 2 relu(gn(x+addp)); 3 relu(gn(x)+addp)
// ACC: x += tempf[row] before epilogue (cross-pass accumulator).
struct MG { const __bf16* w[5]; const void* a[5]; };

template<int NJ, typename AT, typename ADT, typename OT, int EPI, bool ACC>
__launch_bounds__(256)
__global__ void mgemm_k(MG mg, const float* __restrict__ sb,
                        const ADT* __restrict__ addp,
                        const float* __restrict__ tempf,
                        OT* __restrict__ outp, int M)
{
    __shared__ __bf16 wl[16384];
    __shared__ float smS[2][64], smQ[2][64];
    const int tid = threadIdx.x, lane = tid & 63, wave = tid >> 6;
    const int waveM = wave >> 1, waveN = wave & 1;
    const int r16 = lane & 15, kq = lane >> 4;
    const int mbase = blockIdx.x * 64 + waveM * 32;

    int asrc[2];
    #pragma unroll
    for (int mi = 0; mi < 2; ++mi) {
        int r = mbase + mi * 16 + r16;
        asrc[mi] = r < M ? r : M - 1;
    }
    f32x4 acc[2][4];
    #pragma unroll
    for (int mi = 0; mi < 2; ++mi)
        #pragma unroll
        for (int ni = 0; ni < 4; ++ni)
            acc[mi][ni] = (f32x4){0.f, 0.f, 0.f, 0.f};

    for (int j = 0; j < NJ; ++j) {
        if (j) __syncthreads();
        {   // stage swizzled W image (identity copy, coalesced)
            const __bf16* wsrc = mg.w[j];
            #pragma unroll
            for (int r = 0; r < 8; ++r) {
                const int off = r * 2048 + tid * 8;
                *reinterpret_cast<bf16x8*>(wl + off) =
                    *reinterpret_cast<const bf16x8*>(wsrc + off);
            }
        }
        const AT* Aj = (const AT*)mg.a[j];
        bf16x8 a[2][4];
        #pragma unroll
        for (int mi = 0; mi < 2; ++mi)
            #pragma unroll
            for (int ks = 0; ks < 4; ++ks)
                a[mi][ks] = ldA(Aj + (size_t)asrc[mi] * 128 + ks * 32 + kq * 8);
        __syncthreads();
        #pragma unroll
        for (int ks = 0; ks < 4; ++ks) {
            bf16x8 b[4];
            #pragma unroll
            for (int ni = 0; ni < 4; ++ni) {
                const int c = waveN * 64 + ni * 16 + r16;
                b[ni] = *reinterpret_cast<const bf16x8*>(
                    wl + c * 128 + (((ks << 2) + kq) ^ (c & 7)) * 8);
            }
            #pragma unroll
            for (int mi = 0; mi < 2; ++mi)
                #pragma unroll
                for (int ni = 0; ni < 4; ++ni)
                    acc[mi][ni] = __builtin_amdgcn_mfma_f32_16x16x32_bf16(
                        a[mi][ks], b[ni], acc[mi][ni], 0, 0, 0);
        }
    }

    if (ACC) {
        #pragma unroll
        for (int mi = 0; mi < 2; ++mi) {
            const int rb = mbase + mi * 16 + kq * 4;
            #pragma unroll
            for (int reg = 0; reg < 4; ++reg) {
                const int cr = (rb + reg) < M ? (rb + reg) : M - 1;
                const float* tp = tempf + (size_t)cr * 128 + waveN * 64 + r16;
                #pragma unroll
                for (int ni = 0; ni < 4; ++ni)
                    acc[mi][ni][reg] += tp[ni * 16];
            }
        }
    }
    if (EPI == 2) {
        #pragma unroll
        for (int mi = 0; mi < 2; ++mi) {
            const int rb = mbase + mi * 16 + kq * 4;
            #pragma unroll
            for (int reg = 0; reg < 4; ++reg) {
                const int cr = (rb + reg) < M ? (rb + reg) : M - 1;
                const ADT* ap = addp + (size_t)cr * 128 + waveN * 64 + r16;
                #pragma unroll
                for (int ni = 0; ni < 4; ++ni)
                    acc[mi][ni][reg] += ldf(ap + ni * 16);
            }
        }
    }

    if (EPI == 0) {
        #pragma unroll
        for (int mi = 0; mi < 2; ++mi) {
            const int rb = mbase + mi * 16 + kq * 4;
            #pragma unroll
            for (int reg = 0; reg < 4; ++reg) {
                const int crow = rb + reg;
                if (crow >= M) continue;
                OT* dst = outp + (size_t)crow * 128 + waveN * 64 + r16;
                #pragma unroll
                for (int ni = 0; ni < 4; ++ni) dst[ni * 16] = (OT)acc[mi][ni][reg];
            }
        }
        return;
    }

    // GroupNorm stats (cross-r16 shfl + cross-waveN LDS)
    #pragma unroll
    for (int mi = 0; mi < 2; ++mi) {
        #pragma unroll
        for (int reg = 0; reg < 4; ++reg) {
            float s = acc[mi][0][reg] + acc[mi][1][reg] + acc[mi][2][reg] + acc[mi][3][reg];
            float q = acc[mi][0][reg]*acc[mi][0][reg] + acc[mi][1][reg]*acc[mi][1][reg]
                    + acc[mi][2][reg]*acc[mi][2][reg] + acc[mi][3][reg]*acc[mi][3][reg];
            #pragma unroll
            for (int off = 1; off < 16; off <<= 1) {
                s += __shfl_xor(s, off);
                q += __shfl_xor(q, off);
            }
            if (r16 == 0) {
                int lr = waveM * 32 + mi * 16 + kq * 4 + reg;
                smS[waveN][lr] = s; smQ[waveN][lr] = q;
            }
        }
    }
    __syncthreads();

    #pragma unroll
    for (int mi = 0; mi < 2; ++mi) {
        #pragma unroll
        for (int reg = 0; reg < 4; ++reg) {
            const int lr = waveM * 32 + mi * 16 + kq * 4 + reg;
            const float S = smS[0][lr] + smS[1][lr];
            const float Q = smQ[0][lr] + smQ[1][lr];
            const float m = S * (1.f / 128.f);
            const float inv = rsqrtf(fmaxf(Q * (1.f / 128.f) - m * m, 0.f) + GN_EPS_F);
            const int crow = mbase + mi * 16 + kq * 4 + reg;
            if (crow < M) {
                OT* dst = outp + (size_t)crow * 128 + waveN * 64 + r16;
                const ADT* ap = (EPI == 3)
                    ? addp + (size_t)crow * 128 + waveN * 64 + r16 : nullptr;
                #pragma unroll
                for (int ni = 0; ni < 4; ++ni) {
                    const int colc = waveN * 64 + ni * 16 + r16;
                    float y = (acc[mi][ni][reg] - m) * inv * sb[colc] + sb[128 + colc];
                    if (EPI == 3) y += ldf(ap + ni * 16);
                    dst[ni * 16] = (OT)fmaxf(y, 0.f);
                }
            }
        }
    }
}

// ========== gemmdist2: on-the-fly dist GEMM + prectx add + GN + relu =======
__launch_bounds__(256)
__global__ void gemmdist2_k(const int* __restrict__ hi_idx, const int* __restrict__ wi_idx,
                            const float* __restrict__ cpose, const float* __restrict__ tpose,
                            const float* __restrict__ rpw, const float* __restrict__ rpb,
                            const __bf16* __restrict__ wsw,     // swizzled c1B image
                            const __bf16* __restrict__ prectx,
                            const float* __restrict__ sb,
                            __bf16* __restrict__ hout, int M)
{
    __shared__ __bf16 wl[16384];
    __shared__ float rw[640];
    __shared__ float smS[2][64], smQ[2][64];
    const int tid = threadIdx.x;
    for (int i = tid; i < 640; i += 256)
        rw[i] = (i < 512) ? rpw[i] : rpb[i - 512];
    #pragma unroll
    for (int r = 0; r < 8; ++r) {
        const int off = r * 2048 + tid * 8;
        *reinterpret_cast<bf16x8*>(wl + off) =
            *reinterpret_cast<const bf16x8*>(wsw + off);
    }
    __syncthreads();

    const int lane = tid & 63, wave = tid >> 6;
    const int waveM = wave >> 1, waveN = wave & 1;
    const int r16 = lane & 15, kq = lane >> 4;
    const int mbase = blockIdx.x * 64 + waveM * 32;

    float dl[2][4];
    #pragma unroll
    for (int mi = 0; mi < 2; ++mi) {
        int r = mbase + mi * 16 + r16;
        int e = r < M ? r : M - 1;
        int hi = hi_idx[e], wi = wi_idx[e];
        float4 cp = *reinterpret_cast<const float4*>(cpose + (size_t)hi * 4);
        float4 tp = *reinterpret_cast<const float4*>(tpose + (size_t)wi * 4);
        dl[mi][0] = cp.x - tp.x; dl[mi][1] = cp.y - tp.y;
        dl[mi][2] = cp.z - tp.z; dl[mi][3] = cp.w - tp.w;
    }

    f32x4 acc[2][4];
    #pragma unroll
    for (int mi = 0; mi < 2; ++mi)
        #pragma unroll
        for (int ni = 0; ni < 4; ++ni)
            acc[mi][ni] = (f32x4){0.f, 0.f, 0.f, 0.f};

    #pragma unroll
    for (int ks = 0; ks < 4; ++ks) {
        bf16x8 a[2];
        #pragma unroll
        for (int mi = 0; mi < 2; ++mi) {
            #pragma unroll
            for (int i = 0; i < 8; ++i) {
                const int k = ks * 32 + kq * 8 + i;
                float4 w4 = *reinterpret_cast<const float4*>(&rw[k * 4]);
                float d = fmaf(dl[mi][0], w4.x, fmaf(dl[mi][1], w4.y,
                          fmaf(dl[mi][2], w4.z, fmaf(dl[mi][3], w4.w, rw[512 + k]))));
                a[mi][i] = (__bf16)fmaxf(d, 0.f);
            }
        }
        bf16x8 b[4];
        #pragma unroll
        for (int ni = 0; ni < 4; ++ni) {
            const int c = waveN * 64 + ni * 16 + r16;
            b[ni] = *reinterpret_cast<const bf16x8*>(
                wl + c * 128 + (((ks << 2) + kq) ^ (c & 7)) * 8);
        }
        #pragma unroll
        for (int mi = 0; mi < 2; ++mi)
            #pragma unroll
            for (int ni = 0; ni < 4; ++ni)
                acc[mi][ni] = __builtin_amdgcn_mfma_f32_16x16x32_bf16(
                    a[mi], b[ni], acc[mi][ni], 0, 0, 0);
    }

    // add prectx[hi[crow]] (bf16)
    #pragma unroll
    for (int mi = 0; mi < 2; ++mi) {
        const int rb = mbase + mi * 16 + kq * 4;
        #pragma unroll
        for (int reg = 0; reg < 4; ++reg) {
            const int crow = rb + reg;
            const int e = crow < M ? crow : M - 1;
            const int hrow = hi_idx[e];
            const __bf16* pp = prectx + (size_t)hrow * 128 + waveN * 64 + r16;
            #pragma unroll
            for (int ni = 0; ni < 4; ++ni)
                acc[mi][ni][reg] += (float)pp[ni * 16];
        }
    }

    #pragma unroll
    for (int mi = 0; mi < 2; ++mi) {
        #pragma unroll
        for (int reg = 0; reg < 4; ++reg) {
            float s = acc[mi][0][reg] + acc[mi][1][reg] + acc[mi][2][reg] + acc[mi][3][reg];
            float q = acc[mi][0][reg]*acc[mi][0][reg] + acc[mi][1][reg]*acc[mi][1][reg]
                    + acc[mi][2][reg]*acc[mi][2][reg] + acc[mi][3][reg]*acc[mi][3][reg];
            #pragma unroll
            for (int off = 1; off < 16; off <<= 1) {
                s += __shfl_xor(s, off);
                q += __shfl_xor(q, off);
            }
            if (r16 == 0) {
                int lr = waveM * 32 + mi * 16 + kq * 4 + reg;
                smS[waveN][lr] = s; smQ[waveN][lr] = q;
            }
        }
    }
    __syncthreads();

    #pragma unroll
    for (int mi = 0; mi < 2; ++mi) {
        #pragma unroll
        for (int reg = 0; reg < 4; ++reg) {
            const int lr = waveM * 32 + mi * 16 + kq * 4 + reg;
            const float S = smS[0][lr] + smS[1][lr];
            const float Q = smQ[0][lr] + smQ[1][lr];
            const float m = S * (1.f / 128.f);
            const float inv = rsqrtf(fmaxf(Q * (1.f / 128.f) - m * m, 0.f) + GN_EPS_F);
            const int crow = mbase + mi * 16 + kq * 4 + reg;
            if (crow < M) {
                __bf16* dp = hout + (size_t)crow * 128 + waveN * 64 + r16;
                #pragma unroll
                for (int ni = 0; ni < 4; ++ni) {
                    const int colc = waveN * 64 + ni * 16 + r16;
                    float y = (acc[mi][ni][reg] - m) * inv * sb[colc] + sb[128 + colc];
                    dp[ni * 16] = (__bf16)fmaxf(y, 0.f);
                }
            }
        }
    }
}

// ===========================================================================
extern "C" void kernel_launch(void* const* d_in, const int* in_sizes, int n_in,
                              void* d_out, int out_size, void* d_ws, size_t ws_size,
                              hipStream_t stream)
{
    const float* roi_feat   = (const float*)d_in[0];
    const float* graph_pose = (const float*)d_in[1];
    const float* roi_pose   = (const float*)d_in[2];
    const float* lp_input_w = (const float*)d_in[3];
    const float* lp_rpw     = (const float*)d_in[4];
    const float* lp_rpb     = (const float*)d_in[5];
    const float* lp_c1w     = (const float*)d_in[6];
    const float* lp_c1gn    = (const float*)d_in[7];
    const float* lp_c2w     = (const float*)d_in[8];
    const float* lp_m1w     = (const float*)d_in[9];
    const float* lp_m1gn    = (const float*)d_in[10];
    const float* lp_m2w     = (const float*)d_in[11];
    const float* lp_m2gn    = (const float*)d_in[12];
    const float* lp_ngn     = (const float*)d_in[13];
    const float* f_ctrw     = (const float*)d_in[14];
    const float* f_psw      = (const float*)d_in[15];
    const float* f_lw       = (const float*)d_in[16];
    const float* f_rw       = (const float*)d_in[17];
    const float* f_ngn      = (const float*)d_in[18];
    const float* f_c2w      = (const float*)d_in[19];
    const float* f_c2gn     = (const float*)d_in[20];
    const int* e1_hi = (const int*)d_in[21];
    const int* e1_wi = (const int*)d_in[22];
    const int* e2_hi = (const int*)d_in[23];
    const int* e2_wi = (const int*)d_in[24];
    const int* ps_u  = (const int*)d_in[25];
    const int* ps_v  = (const int*)d_in[26];
    const int* lr_u  = (const int*)d_in[27];
    const int* lr_v  = (const int*)d_in[28];
    float* out = (float*)d_out;

    // ---- workspace layout (~147 MB) ----
    float*  tempf  = (float*)d_ws;                        // NG*128 f32
    __bf16* gfeatB = (__bf16*)(tempf + (size_t)NG * 128);
    __bf16* midB   = gfeatB + (size_t)NG * 128;
    __bf16* EbufB  = midB   + (size_t)NG * 128;
    __bf16* preB1  = EbufB  + (size_t)NG * 128;
    __bf16* preB2  = preB1  + (size_t)NR * 128;
    __bf16* wbuf   = preB2  + (size_t)NR * 128;           // 80*16384 bf16
    __bf16* ubuf   = wbuf   + (size_t)80 * 16384;         // 5*NG*128 bf16 union
    __bf16* Sbuf = ubuf;
    __bf16* hbuf = ubuf;
    int* ip      = (int*)(ubuf + (size_t)5 * NG * 128);
    int* cnt14   = ip;             ip += 14 * NG;
    int* rp14    = ip;             ip += 14 * NG + 1;
    int* col14   = ip;             ip += 12 * EPS_N + 2 * ELR_N;
    int* cntE1   = ip;             ip += NG;
    int* rpE1    = ip;             ip += NG + 1;
    int* colE1   = ip;             ip += E1_N;
    int* cntE2   = ip;             ip += NR;
    int* rpE2    = ip;             ip += NR + 1;
    int* colE2   = ip;             ip += E2_N;
    int* bsum    = ip;             ip += 256;

    dim3 blk(256);
    const dim3 gNG64((NG + 63) / 64), gNR64((NR + 63) / 64), gE64((E1_N + 63) / 64);
    const int NE14 = 12 * EPS_N + 2 * ELR_N;
    const dim3 gH14((NE14 + 255) / 256);

    // ---------------- weight prep (once per call) ----------------
    PrepTab tab; int nw = 0;
    auto addw = [&](const float* p, int s) { tab.src[nw] = p; tab.stride[nw] = s; ++nw; };
    addw(lp_c1w, 256);                 // 0 c1A_0
    addw(lp_c1w + 128, 256);           // 1 c1B_0
    addw(lp_c1w + 32768, 256);         // 2 c1A_1
    addw(lp_c1w + 32768 + 128, 256);   // 3 c1B_1
    addw(lp_input_w + 16384, 128);     // 4 input_w[1]
    addw(lp_c2w, 128); addw(lp_c2w + 16384, 128);   // 5,6
    addw(lp_m1w, 128); addw(lp_m1w + 16384, 128);   // 7,8
    addw(lp_m2w, 128); addw(lp_m2w + 16384, 128);   // 9,10
    for (int i = 0; i < 4; ++i) addw(f_ctrw + (size_t)i * 16384, 128);      // 11..14
    for (int i = 0; i < 4; ++i)
        for (int k = 0; k < 12; ++k) addw(f_psw + ((size_t)i * 12 + k) * 16384, 128); // 15+i*12+k
    for (int i = 0; i < 4; ++i) addw(f_lw + (size_t)i * 16384, 128);        // 63+i
    for (int i = 0; i < 4; ++i) addw(f_rw + (size_t)i * 16384, 128);        // 67+i
    for (int i = 0; i < 4; ++i) addw(f_c2w + (size_t)i * 16384, 128);       // 71+i
    tab.n = nw;
    auto wb = [&](int idx) { return wbuf + (size_t)idx * 16384; };
    prepw_k<<<dim3((nw * 2048 + 255) / 256), blk, 0, stream>>>(tab, wbuf);

    // ======================== CSR builds (once/call) ========================
    hipMemsetAsync(cnt14, 0, (size_t)14 * NG * 4, stream);
    hist14_k<<<gH14, blk, 0, stream>>>(ps_u, lr_u, cnt14);
    {
        int n = 14 * NG, nb = (n + SCAN_CHUNK - 1) / SCAN_CHUNK;
        scan1_k<<<nb, blk, 0, stream>>>(cnt14, n, bsum);
        scan2_k<<<1, blk, 0, stream>>>(bsum, nb);
        scan3_k<<<nb, blk, 0, stream>>>(cnt14, n, bsum, rp14);
    }
    hipMemcpyAsync(cnt14, rp14, (size_t)14 * NG * 4, hipMemcpyDeviceToDevice, stream);
    fill14_k<<<gH14, blk, 0, stream>>>(ps_u, ps_v, lr_u, lr_v, cnt14, col14);

    hipMemsetAsync(cntE1, 0, (size_t)NG * 4, stream);
    histE_k<<<(E1_N + 255) / 256, blk, 0, stream>>>(e1_wi, E1_N, cntE1);
    {
        int n = NG, nb = (n + SCAN_CHUNK - 1) / SCAN_CHUNK;
        scan1_k<<<nb, blk, 0, stream>>>(cntE1, n, bsum);
        scan2_k<<<1, blk, 0, stream>>>(bsum, nb);
        scan3_k<<<nb, blk, 0, stream>>>(cntE1, n, bsum, rpE1);
    }
    hipMemcpyAsync(cntE1, rpE1, (size_t)NG * 4, hipMemcpyDeviceToDevice, stream);
    fillE_k<<<(E1_N + 255) / 256, blk, 0, stream>>>(e1_wi, E1_N, cntE1, colE1);

    hipMemsetAsync(cntE2, 0, (size_t)NR * 4, stream);
    histE_k<<<(E2_N + 255) / 256, blk, 0, stream>>>(e2_wi, E2_N, cntE2);
    {
        int n = NR, nb = (n + SCAN_CHUNK - 1) / SCAN_CHUNK;
        scan1_k<<<nb, blk, 0, stream>>>(cntE2, n, bsum);
        scan2_k<<<1, blk, 0, stream>>>(bsum, nb);
        scan3_k<<<nb, blk, 0, stream>>>(cntE2, n, bsum, rpE2);
    }
    hipMemcpyAsync(cntE2, rpE2, (size_t)NR * 4, hipMemcpyDeviceToDevice, stream);
    fillE_k<<<(E2_N + 255) / 256, blk, 0, stream>>>(e2_wi, E2_N, cntE2, colE2);

    // helper to build single-W MG
    auto mg1 = [&](int widx, const void* a) {
        MG m{}; m.w[0] = wb(widx); m.a[0] = a; return m;
    };

    // ============== lane_pooling #1 (roi -> graph), tgt_feat = 0 ============
    mgemm_k<1, float, float, __bf16, 0, false><<<gNR64, blk, 0, stream>>>(
        mg1(0, roi_feat), nullptr, (const float*)nullptr, nullptr, preB1, NR);
    gemmdist2_k<<<gE64, blk, 0, stream>>>(
        e1_hi, e1_wi, roi_pose, graph_pose, lp_rpw, lp_rpb,
        wb(1), preB1, lp_c1gn, hbuf, E1_N);
    segsumE_k<4><<<gNG64, blk, 0, stream>>>(hbuf, rpE1, colE1, EbufB, NG);
    mgemm_k<1, __bf16, float, __bf16, 1, false><<<gNG64, blk, 0, stream>>>(
        mg1(5, EbufB), lp_ngn, (const float*)nullptr, nullptr, midB, NG);
    mgemm_k<1, __bf16, float, __bf16, 1, false><<<gNG64, blk, 0, stream>>>(
        mg1(7, midB), lp_m1gn, (const float*)nullptr, nullptr, EbufB, NG);
    mgemm_k<1, __bf16, float, __bf16, 1, false><<<gNG64, blk, 0, stream>>>(
        mg1(9, EbufB), lp_m2gn, (const float*)nullptr, nullptr, gfeatB, NG);

    // ============================ global_graph ==============================
    for (int i = 0; i < 4; ++i) {
        // pass 0: scales 0..4
        segsum14_k<<<dim3(gNG64.x, 5), blk, 0, stream>>>(gfeatB, rp14, col14, 0, Sbuf, NG);
        {
            MG m{};
            for (int j = 0; j < 5; ++j) {
                m.w[j] = wb(15 + i * 12 + j);
                m.a[j] = Sbuf + (size_t)j * NG * 128;
            }
            mgemm_k<5, __bf16, float, float, 0, false><<<gNG64, blk, 0, stream>>>(
                m, nullptr, (const float*)nullptr, nullptr, tempf, NG);
        }
        // pass 1: scales 5..9
        segsum14_k<<<dim3(gNG64.x, 5), blk, 0, stream>>>(gfeatB, rp14, col14, 5, Sbuf, NG);
        {
            MG m{};
            for (int j = 0; j < 5; ++j) {
                m.w[j] = wb(15 + i * 12 + 5 + j);
                m.a[j] = Sbuf + (size_t)j * NG * 128;
            }
            mgemm_k<5, __bf16, float, float, 0, true><<<gNG64, blk, 0, stream>>>(
                m, nullptr, (const float*)nullptr, tempf, tempf, NG);
        }
        // pass 2: ps10, ps11, left, right, ctr(self) + GN
        segsum14_k<<<dim3(gNG64.x, 4), blk, 0, stream>>>(gfeatB, rp14, col14, 10, Sbuf, NG);
        {
            MG m{};
            m.w[0] = wb(15 + i * 12 + 10); m.a[0] = Sbuf;
            m.w[1] = wb(15 + i * 12 + 11); m.a[1] = Sbuf + (size_t)1 * NG * 128;
            m.w[2] = wb(63 + i);           m.a[2] = Sbuf + (size_t)2 * NG * 128;
            m.w[3] = wb(67 + i);           m.a[3] = Sbuf + (size_t)3 * NG * 128;
            m.w[4] = wb(11 + i);           m.a[4] = gfeatB;
            mgemm_k<5, __bf16, float, __bf16, 1, true><<<gNG64, blk, 0, stream>>>(
                m, f_ngn + (size_t)i * 256, (const float*)nullptr, tempf, midB, NG);
        }
        // ctr2 + residual
        mgemm_k<1, __bf16, __bf16, __bf16, 3, false><<<gNG64, blk, 0, stream>>>(
            mg1(71 + i, midB), f_c2gn + (size_t)i * 256, gfeatB, nullptr, gfeatB, NG);
    }

    // ============ lane_pooling #2 (graph -> roi), identity = roi_feat =======
    mgemm_k<1, __bf16, float, __bf16, 0, false><<<gNG64, blk, 0, stream>>>(
        mg1(2, gfeatB), nullptr, (const float*)nullptr, nullptr, midB, NG);   // prectxG
    mgemm_k<1, float, float, __bf16, 0, false><<<gNR64, blk, 0, stream>>>(
        mg1(4, roi_feat), nullptr, (const float*)nullptr, nullptr, preB2, NR); // tR
    gemmdist2_k<<<gE64, blk, 0, stream>>>(
        e2_hi, e2_wi, graph_pose, roi_pose, lp_rpw + 512, lp_rpb + 128,
        wb(3), midB, lp_c1gn + 256, hbuf, E2_N);
    segsumE_k<8><<<dim3((NR + 31) / 32), blk, 0, stream>>>(hbuf, rpE2, colE2, EbufB, NR);
    mgemm_k<1, __bf16, __bf16, __bf16, 2, false><<<gNR64, blk, 0, stream>>>(
        mg1(6, EbufB), lp_ngn + 256, preB2, nullptr, preB1, NR);
    mgemm_k<1, __bf16, float, __bf16, 1, false><<<gNR64, blk, 0, stream>>>(
        mg1(8, preB1), lp_m1gn + 256, (const float*)nullptr, nullptr, preB2, NR);
    mgemm_k<1, __bf16, float, float, 3, false><<<gNR64, blk, 0, stream>>>(
        mg1(10, preB2), lp_m2gn + 256, roi_feat, nullptr, out, NR);
}

// Round 6
// 845.996 us; speedup vs baseline: 2.8104x; 1.3167x over previous
//
#include <hip/hip_runtime.h>

#define NG 50000
#define NR 12000
#define EPS_N 50000
#define ELR_N 5000
#define E1_N 150000
#define E2_N 150000
#define GN_EPS_F 1e-5f
#define SCAN_CHUNK 4096

typedef __attribute__((ext_vector_type(8))) __bf16 bf16x8;
typedef __attribute__((ext_vector_type(4))) float f32x4;

__device__ __forceinline__ bf16x8 cvt8(const float* __restrict__ p) {
    float4 x0 = *reinterpret_cast<const float4*>(p);
    float4 x1 = *reinterpret_cast<const float4*>(p + 4);
    bf16x8 a;
    a[0] = (__bf16)x0.x; a[1] = (__bf16)x0.y; a[2] = (__bf16)x0.z; a[3] = (__bf16)x0.w;
    a[4] = (__bf16)x1.x; a[5] = (__bf16)x1.y; a[6] = (__bf16)x1.z; a[7] = (__bf16)x1.w;
    return a;
}

// swizzled tile addressing: row stride 128 elems; 16B slot s lives at slot s^(row&7)
__device__ __forceinline__ int tslot(int row, int slot) {
    return row * 128 + ((slot ^ (row & 7)) << 3);
}

// ================= weight prep: f32 -> swizzled bf16 LDS image ==============
struct PrepTab { const float* src[80]; int stride[80]; int n; };

__global__ void prepw_k(PrepTab tab, __bf16* __restrict__ wbuf)
{
    int t = blockIdx.x * 256 + threadIdx.x;
    int w = t >> 11;
    if (w >= tab.n) return;
    int rr = t & 2047, c = rr >> 4, slot = rr & 15;
    const float* s = tab.src[w] + (size_t)c * tab.stride[w] + slot * 8;
    bf16x8 o;
    #pragma unroll
    for (int e = 0; e < 8; ++e) o[e] = (__bf16)s[e];
    *reinterpret_cast<bf16x8*>(wbuf + (size_t)w * 16384 + tslot(c, slot)) = o;
}

// ============================ CSR construction =============================
__global__ void hist14_k(const int* __restrict__ ps_u, const int* __restrict__ lr_u,
                         int* __restrict__ cnt)
{
    int t = blockIdx.x * 256 + threadIdx.x;
    const int total = 12 * EPS_N + 2 * ELR_N;
    if (t >= total) return;
    int k, u;
    if (t < 12 * EPS_N) { k = t / EPS_N; u = ps_u[t]; }
    else { int r = t - 12 * EPS_N; k = 12 + r / ELR_N; u = lr_u[r]; }
    atomicAdd(&cnt[k * NG + u], 1);
}

__global__ void fill14_k(const int* __restrict__ ps_u, const int* __restrict__ ps_v,
                         const int* __restrict__ lr_u, const int* __restrict__ lr_v,
                         int* __restrict__ head, int* __restrict__ col)
{
    int t = blockIdx.x * 256 + threadIdx.x;
    const int total = 12 * EPS_N + 2 * ELR_N;
    if (t >= total) return;
    int k, u, v;
    if (t < 12 * EPS_N) { k = t / EPS_N; u = ps_u[t]; v = ps_v[t]; }
    else { int r = t - 12 * EPS_N; k = 12 + r / ELR_N; u = lr_u[r]; v = lr_v[r]; }
    int pos = atomicAdd(&head[k * NG + u], 1);
    col[pos] = v;
}

__global__ void histE_k(const int* __restrict__ wi, int n, int* __restrict__ cnt)
{
    int t = blockIdx.x * 256 + threadIdx.x;
    if (t >= n) return;
    atomicAdd(&cnt[wi[t]], 1);
}

__global__ void fillE_k(const int* __restrict__ wi, int n,
                        int* __restrict__ head, int* __restrict__ col)
{
    int t = blockIdx.x * 256 + threadIdx.x;
    if (t >= n) return;
    int pos = atomicAdd(&head[wi[t]], 1);
    col[pos] = t;
}

__global__ void scan1_k(const int* __restrict__ in, int n, int* __restrict__ bsum)
{
    __shared__ int sm[4];
    int base = blockIdx.x * SCAN_CHUNK;
    int s = 0;
    for (int i = threadIdx.x; i < SCAN_CHUNK; i += 256) {
        int idx = base + i;
        s += (idx < n) ? in[idx] : 0;
    }
    #pragma unroll
    for (int off = 1; off < 64; off <<= 1) s += __shfl_xor(s, off);
    if ((threadIdx.x & 63) == 0) sm[threadIdx.x >> 6] = s;
    __syncthreads();
    if (threadIdx.x == 0) bsum[blockIdx.x] = sm[0] + sm[1] + sm[2] + sm[3];
}

__global__ void scan2_k(int* __restrict__ bsum, int nb)
{
    if (threadIdx.x == 0) {
        int acc = 0;
        for (int i = 0; i < nb; ++i) { int t = bsum[i]; bsum[i] = acc; acc += t; }
    }
}

__global__ void scan3_k(const int* __restrict__ in, int n,
                        const int* __restrict__ bsum, int* __restrict__ outp)
{
    __shared__ int sm[256];
    int base = blockIdx.x * SCAN_CHUNK;
    int loc[16]; int s = 0;
    #pragma unroll
    for (int i = 0; i < 16; ++i) {
        int idx = base + threadIdx.x * 16 + i;
        loc[i] = (idx < n) ? in[idx] : 0; s += loc[i];
    }
    sm[threadIdx.x] = s; __syncthreads();
    for (int off = 1; off < 256; off <<= 1) {
        int v = (threadIdx.x >= off) ? sm[threadIdx.x - off] : 0;
        __syncthreads();
        sm[threadIdx.x] += v;
        __syncthreads();
    }
    int tp = (threadIdx.x ? sm[threadIdx.x - 1] : 0) + bsum[blockIdx.x];
    #pragma unroll
    for (int i = 0; i < 16; ++i) {
        int idx = base + threadIdx.x * 16 + i;
        if (idx < n) outp[idx] = tp;
        tp += loc[i];
        if (idx == n - 1) outp[n] = tp;
    }
}

// ======================= shared device helpers =============================
// stage one 128x128 swizzled W image into wl (identity copy)
__device__ __forceinline__ void stage_w(__bf16* wl, const __bf16* __restrict__ wsrc,
                                        int tid)
{
    #pragma unroll
    for (int r = 0; r < 8; ++r) {
        const int off = r * 2048 + tid * 8;
        *reinterpret_cast<bf16x8*>(wl + off) =
            *reinterpret_cast<const bf16x8*>(wsrc + off);
    }
}

// one K=128 MFMA sweep: acc += atile-rows @ wl^T
__device__ __forceinline__ void mfma_tile(f32x4 (&acc)[2][4], const __bf16* atile,
                                          const __bf16* wl, int waveM, int waveN,
                                          int r16, int kq)
{
    #pragma unroll
    for (int ks = 0; ks < 4; ++ks) {
        bf16x8 a[2], b[4];
        #pragma unroll
        for (int mi = 0; mi < 2; ++mi) {
            const int lr = waveM * 32 + mi * 16 + r16;
            a[mi] = *reinterpret_cast<const bf16x8*>(atile + tslot(lr, (ks << 2) + kq));
        }
        #pragma unroll
        for (int ni = 0; ni < 4; ++ni) {
            const int c = waveN * 64 + ni * 16 + r16;
            b[ni] = *reinterpret_cast<const bf16x8*>(wl + tslot(c, (ks << 2) + kq));
        }
        #pragma unroll
        for (int mi = 0; mi < 2; ++mi)
            #pragma unroll
            for (int ni = 0; ni < 4; ++ni)
                acc[mi][ni] = __builtin_amdgcn_mfma_f32_16x16x32_bf16(
                    a[mi], b[ni], acc[mi][ni], 0, 0, 0);
    }
}

__device__ __forceinline__ void gn_stats(const f32x4 (&acc)[2][4],
                                         float (*smS)[64], float (*smQ)[64],
                                         int waveM, int waveN, int r16, int kq)
{
    #pragma unroll
    for (int mi = 0; mi < 2; ++mi) {
        #pragma unroll
        for (int reg = 0; reg < 4; ++reg) {
            float s = acc[mi][0][reg] + acc[mi][1][reg] + acc[mi][2][reg] + acc[mi][3][reg];
            float q = acc[mi][0][reg]*acc[mi][0][reg] + acc[mi][1][reg]*acc[mi][1][reg]
                    + acc[mi][2][reg]*acc[mi][2][reg] + acc[mi][3][reg]*acc[mi][3][reg];
            #pragma unroll
            for (int off = 1; off < 16; off <<= 1) {
                s += __shfl_xor(s, off);
                q += __shfl_xor(q, off);
            }
            if (r16 == 0) {
                int lr = waveM * 32 + mi * 16 + kq * 4 + reg;
                smS[waveN][lr] = s; smQ[waveN][lr] = q;
            }
        }
    }
}

// ============ edgefull: h[e] = relu(gn(ctx[hi]@c1A + dist@c1B, sb)) =========
template<typename CT>
__launch_bounds__(256)
__global__ void edgefull_k(const int* __restrict__ hi_idx, const int* __restrict__ wi_idx,
                           const CT* __restrict__ ctxfeat,
                           const float* __restrict__ cpose, const float* __restrict__ tpose,
                           const float* __restrict__ rpw, const float* __restrict__ rpb,
                           const __bf16* __restrict__ wc1A, const __bf16* __restrict__ wc1B,
                           const float* __restrict__ sb,
                           __bf16* __restrict__ hout, int M)
{
    __shared__ __bf16 wl[16384];
    __shared__ __bf16 atile[8192];
    __shared__ float rw[640];
    __shared__ float smS[2][64], smQ[2][64];
    const int tid = threadIdx.x, lane = tid & 63, wave = tid >> 6;
    const int waveM = wave >> 1, waveN = wave & 1;
    const int r16 = lane & 15, kq = lane >> 4;
    const int ublk = blockIdx.x * 64;
    const int mbase = ublk + waveM * 32;

    for (int i = tid; i < 640; i += 256)
        rw[i] = (i < 512) ? rpw[i] : rpb[i - 512];

    // pose diffs (lane role) — issue early
    float dl[2][4];
    #pragma unroll
    for (int mi = 0; mi < 2; ++mi) {
        int r = mbase + mi * 16 + r16;
        int e = r < M ? r : M - 1;
        int hi = hi_idx[e], wi = wi_idx[e];
        float4 cp = *reinterpret_cast<const float4*>(cpose + (size_t)hi * 4);
        float4 tp = *reinterpret_cast<const float4*>(tpose + (size_t)wi * 4);
        dl[mi][0] = cp.x - tp.x; dl[mi][1] = cp.y - tp.y;
        dl[mi][2] = cp.z - tp.z; dl[mi][3] = cp.w - tp.w;
    }

    // gather ctx rows (thread role): row lr=tid>>2, cols q*32..
    {
        const int lr = tid >> 2, q = tid & 3;
        const int e = (ublk + lr) < M ? (ublk + lr) : M - 1;
        const int cr = hi_idx[e];
        const CT* sp = ctxfeat + (size_t)cr * 128 + q * 32;
        #pragma unroll
        for (int i = 0; i < 4; ++i) {
            bf16x8 h;
            if constexpr (sizeof(CT) == 4) h = cvt8((const float*)sp + i * 8);
            else h = *reinterpret_cast<const bf16x8*>((const __bf16*)sp + i * 8);
            *reinterpret_cast<bf16x8*>(atile + tslot(lr, q * 4 + i)) = h;
        }
    }
    stage_w(wl, wc1A, tid);
    __syncthreads();

    f32x4 acc[2][4];
    #pragma unroll
    for (int mi = 0; mi < 2; ++mi)
        #pragma unroll
        for (int ni = 0; ni < 4; ++ni)
            acc[mi][ni] = (f32x4){0.f, 0.f, 0.f, 0.f};

    mfma_tile(acc, atile, wl, waveM, waveN, r16, kq);
    __syncthreads();                 // wl reads done everywhere
    stage_w(wl, wc1B, tid);
    __syncthreads();

    // dist matmul (A built in-register)
    #pragma unroll
    for (int ks = 0; ks < 4; ++ks) {
        bf16x8 a[2], b[4];
        #pragma unroll
        for (int mi = 0; mi < 2; ++mi) {
            #pragma unroll
            for (int i = 0; i < 8; ++i) {
                const int k = ks * 32 + kq * 8 + i;
                float4 w4 = *reinterpret_cast<const float4*>(&rw[k * 4]);
                float d = fmaf(dl[mi][0], w4.x, fmaf(dl[mi][1], w4.y,
                          fmaf(dl[mi][2], w4.z, fmaf(dl[mi][3], w4.w, rw[512 + k]))));
                a[mi][i] = (__bf16)fmaxf(d, 0.f);
            }
        }
        #pragma unroll
        for (int ni = 0; ni < 4; ++ni) {
            const int c = waveN * 64 + ni * 16 + r16;
            b[ni] = *reinterpret_cast<const bf16x8*>(wl + tslot(c, (ks << 2) + kq));
        }
        #pragma unroll
        for (int mi = 0; mi < 2; ++mi)
            #pragma unroll
            for (int ni = 0; ni < 4; ++ni)
                acc[mi][ni] = __builtin_amdgcn_mfma_f32_16x16x32_bf16(
                    a[mi], b[ni], acc[mi][ni], 0, 0, 0);
    }

    gn_stats(acc, smS, smQ, waveM, waveN, r16, kq);
    __syncthreads();

    #pragma unroll
    for (int mi = 0; mi < 2; ++mi) {
        #pragma unroll
        for (int reg = 0; reg < 4; ++reg) {
            const int lr = waveM * 32 + mi * 16 + kq * 4 + reg;
            const float S = smS[0][lr] + smS[1][lr];
            const float Q = smQ[0][lr] + smQ[1][lr];
            const float m = S * (1.f / 128.f);
            const float inv = rsqrtf(fmaxf(Q * (1.f / 128.f) - m * m, 0.f) + GN_EPS_F);
            const int crow = mbase + mi * 16 + kq * 4 + reg;
            if (crow < M) {
                __bf16* dp = hout + (size_t)crow * 128 + waveN * 64 + r16;
                #pragma unroll
                for (int ni = 0; ni < 4; ++ni) {
                    const int colc = waveN * 64 + ni * 16 + r16;
                    float y = (acc[mi][ni][reg] - m) * inv * sb[colc] + sb[128 + colc];
                    dp[ni * 16] = (__bf16)fmaxf(y, 0.f);
                }
            }
        }
    }
}

// ======= fusedlayer: one global_graph fusion layer in a single kernel =======
// temp = Σ_{j<14} S_j@W_j^T + feat@ctr^T; mid = relu(gn(temp, gn1));
// out = relu(gn(mid@ctr2^T, gn2) + feat)
struct FW { const __bf16* w[16]; };   // 0..11 ps, 12 left, 13 right, 14 ctr, 15 ctr2

__launch_bounds__(256)
__global__ void fusedlayer_k(const __bf16* __restrict__ feat,
                             const int* __restrict__ rp, const int* __restrict__ col,
                             FW fw, const float* __restrict__ gn1,
                             const float* __restrict__ gn2,
                             __bf16* __restrict__ outp, int M)
{
    __shared__ __bf16 wl[16384];
    __shared__ __bf16 atile[8192];
    __shared__ float smS[2][64], smQ[2][64];
    const int tid = threadIdx.x, lane = tid & 63, wave = tid >> 6;
    const int waveM = wave >> 1, waveN = wave & 1;
    const int r16 = lane & 15, kq = lane >> 4;
    const int ublk = blockIdx.x * 64;
    const int mbase = ublk + waveM * 32;
    const int glr = tid >> 2, q = tid & 3;
    const int grow = ublk + glr;
    const bool gv = grow < M;

    // prefetch all CSR row extents (static-indexed; loop fully unrolled)
    int begs[14], degs[14];
    #pragma unroll
    for (int j = 0; j < 14; ++j) {
        int b = 0, e = 0;
        if (gv) { b = rp[j * M + grow]; e = rp[j * M + grow + 1]; }
        begs[j] = b; degs[j] = e - b;
    }

    f32x4 acc[2][4];
    #pragma unroll
    for (int mi = 0; mi < 2; ++mi)
        #pragma unroll
        for (int ni = 0; ni < 4; ++ni)
            acc[mi][ni] = (f32x4){0.f, 0.f, 0.f, 0.f};

    #pragma unroll
    for (int j = 0; j < 15; ++j) {
        __syncthreads();             // prior atile/wl reads complete
        if (j < 14) {
            float ss[32];
            #pragma unroll
            for (int i = 0; i < 32; ++i) ss[i] = 0.f;
            const int b = begs[j], d = degs[j];
            for (int t2 = 0; t2 < d; ++t2) {
                const __bf16* sp = feat + (size_t)col[b + t2] * 128 + q * 32;
                #pragma unroll
                for (int i = 0; i < 4; ++i) {
                    bf16x8 h = *reinterpret_cast<const bf16x8*>(sp + i * 8);
                    #pragma unroll
                    for (int e = 0; e < 8; ++e) ss[i * 8 + e] += (float)h[e];
                }
            }
            #pragma unroll
            for (int i = 0; i < 4; ++i) {
                bf16x8 o;
                #pragma unroll
                for (int e = 0; e < 8; ++e) o[e] = (__bf16)ss[i * 8 + e];
                *reinterpret_cast<bf16x8*>(atile + tslot(glr, q * 4 + i)) = o;
            }
        } else {   // self term: copy feat row
            const __bf16* sp = feat + (size_t)(gv ? grow : 0) * 128 + q * 32;
            #pragma unroll
            for (int i = 0; i < 4; ++i)
                *reinterpret_cast<bf16x8*>(atile + tslot(glr, q * 4 + i)) =
                    *reinterpret_cast<const bf16x8*>(sp + i * 8);
        }
        stage_w(wl, fw.w[j], tid);
        __syncthreads();
        mfma_tile(acc, atile, wl, waveM, waveN, r16, kq);
    }

    // GN1 + relu -> atile (bf16), stage ctr2, mfma2
    gn_stats(acc, smS, smQ, waveM, waveN, r16, kq);
    __syncthreads();                 // also guarantees last mfma atile reads done
    #pragma unroll
    for (int mi = 0; mi < 2; ++mi) {
        #pragma unroll
        for (int reg = 0; reg < 4; ++reg) {
            const int lr = waveM * 32 + mi * 16 + kq * 4 + reg;
            const float S = smS[0][lr] + smS[1][lr];
            const float Q = smQ[0][lr] + smQ[1][lr];
            const float m = S * (1.f / 128.f);
            const float inv = rsqrtf(fmaxf(Q * (1.f / 128.f) - m * m, 0.f) + GN_EPS_F);
            #pragma unroll
            for (int ni = 0; ni < 4; ++ni) {
                const int colc = waveN * 64 + ni * 16 + r16;
                float y = (acc[mi][ni][reg] - m) * inv * gn1[colc] + gn1[128 + colc];
                atile[lr * 128 + (((colc >> 3) ^ (lr & 7)) << 3) + (colc & 7)] =
                    (__bf16)fmaxf(y, 0.f);
            }
        }
    }
    stage_w(wl, fw.w[15], tid);
    __syncthreads();

    f32x4 acc2[2][4];
    #pragma unroll
    for (int mi = 0; mi < 2; ++mi)
        #pragma unroll
        for (int ni = 0; ni < 4; ++ni)
            acc2[mi][ni] = (f32x4){0.f, 0.f, 0.f, 0.f};
    mfma_tile(acc2, atile, wl, waveM, waveN, r16, kq);

    // GN2 + residual + relu -> outp
    gn_stats(acc2, smS, smQ, waveM, waveN, r16, kq);
    __syncthreads();
    #pragma unroll
    for (int mi = 0; mi < 2; ++mi) {
        #pragma unroll
        for (int reg = 0; reg < 4; ++reg) {
            const int lr = waveM * 32 + mi * 16 + kq * 4 + reg;
            const float S = smS[0][lr] + smS[1][lr];
            const float Q = smQ[0][lr] + smQ[1][lr];
            const float m = S * (1.f / 128.f);
            const float inv = rsqrtf(fmaxf(Q * (1.f / 128.f) - m * m, 0.f) + GN_EPS_F);
            const int crow = mbase + mi * 16 + kq * 4 + reg;
            if (crow < M) {
                __bf16* dp = outp + (size_t)crow * 128 + waveN * 64 + r16;
                const __bf16* rs = feat + (size_t)crow * 128 + waveN * 64 + r16;
                #pragma unroll
                for (int ni = 0; ni < 4; ++ni) {
                    const int colc = waveN * 64 + ni * 16 + r16;
                    float y = (acc2[mi][ni][reg] - m) * inv * gn2[colc] + gn2[128 + colc];
                    y += (float)rs[ni * 16];
                    dp[ni * 16] = (__bf16)fmaxf(y, 0.f);
                }
            }
        }
    }
}

// ============= lptail: lane_pooling tail (3-4 chained GEMMs + GNs) ==========
// LP1: out(bf16) = relu(gn(relu(gn(relu(gn(Σh@c2,ngn))@m1,m1gn))@m2,m2gn))
// LP2: x0 = Σh@c2 + roi@inW; ... final: relu(gn(...@m2,m2gn) + roi) -> f32
template<bool LP2>
__launch_bounds__(256)
__global__ void lptail_k(const __bf16* __restrict__ hsrc,
                         const int* __restrict__ rp, const int* __restrict__ col,
                         const float* __restrict__ roi,
                         const __bf16* __restrict__ wc2, const __bf16* __restrict__ winW,
                         const __bf16* __restrict__ wm1, const __bf16* __restrict__ wm2,
                         const float* __restrict__ ngn, const float* __restrict__ m1gn,
                         const float* __restrict__ m2gn,
                         void* __restrict__ outp, int M)
{
    __shared__ __bf16 wl[16384];
    __shared__ __bf16 atile[8192];
    __shared__ float smS[2][64], smQ[2][64];
    const int tid = threadIdx.x, lane = tid & 63, wave = tid >> 6;
    const int waveM = wave >> 1, waveN = wave & 1;
    const int r16 = lane & 15, kq = lane >> 4;
    const int ublk = blockIdx.x * 64;
    const int mbase = ublk + waveM * 32;
    const int glr = tid >> 2, q = tid & 3;
    const int grow = ublk + glr;
    const bool gv = grow < M;

    // phase A: gather Σ h rows -> atile ; stage c2 ; mfma
    {
        float ss[32];
        #pragma unroll
        for (int i = 0; i < 32; ++i) ss[i] = 0.f;
        if (gv) {
            const int b = rp[grow], e = rp[grow + 1];
            for (int jj = b; jj < e; ++jj) {
                const __bf16* sp = hsrc + (size_t)col[jj] * 128 + q * 32;
                #pragma unroll
                for (int i = 0; i < 4; ++i) {
                    bf16x8 h = *reinterpret_cast<const bf16x8*>(sp + i * 8);
                    #pragma unroll
                    for (int e2 = 0; e2 < 8; ++e2) ss[i * 8 + e2] += (float)h[e2];
                }
            }
        }
        #pragma unroll
        for (int i = 0; i < 4; ++i) {
            bf16x8 o;
            #pragma unroll
            for (int e2 = 0; e2 < 8; ++e2) o[e2] = (__bf16)ss[i * 8 + e2];
            *reinterpret_cast<bf16x8*>(atile + tslot(glr, q * 4 + i)) = o;
        }
    }
    stage_w(wl, wc2, tid);
    __syncthreads();

    f32x4 acc[2][4];
    #pragma unroll
    for (int mi = 0; mi < 2; ++mi)
        #pragma unroll
        for (int ni = 0; ni < 4; ++ni)
            acc[mi][ni] = (f32x4){0.f, 0.f, 0.f, 0.f};
    mfma_tile(acc, atile, wl, waveM, waveN, r16, kq);

    if (LP2) {   // + roi @ input_w
        __syncthreads();
        {
            const float* sp = roi + (size_t)(gv ? grow : 0) * 128 + q * 32;
            #pragma unroll
            for (int i = 0; i < 4; ++i)
                *reinterpret_cast<bf16x8*>(atile + tslot(glr, q * 4 + i)) =
                    cvt8(sp + i * 8);
        }
        stage_w(wl, winW, tid);
        __syncthreads();
        mfma_tile(acc, atile, wl, waveM, waveN, r16, kq);
    }

    // chain helper macro: GN(acc, sbp) + relu -> atile; stage w; mfma fresh acc
    #define CHAIN_STEP(SBP, WNEXT)                                               \
    {                                                                            \
        gn_stats(acc, smS, smQ, waveM, waveN, r16, kq);                          \
        __syncthreads();                                                         \
        _Pragma("unroll")                                                        \
        for (int mi = 0; mi < 2; ++mi) {                                         \
            _Pragma("unroll")                                                    \
            for (int reg = 0; reg < 4; ++reg) {                                  \
                const int lr = waveM * 32 + mi * 16 + kq * 4 + reg;              \
                const float S = smS[0][lr] + smS[1][lr];                         \
                const float Q = smQ[0][lr] + smQ[1][lr];                         \
                const float m = S * (1.f / 128.f);                               \
                const float inv = rsqrtf(fmaxf(Q * (1.f / 128.f) - m * m, 0.f)   \
                                         + GN_EPS_F);                            \
                _Pragma("unroll")                                                \
                for (int ni = 0; ni < 4; ++ni) {                                 \
                    const int colc = waveN * 64 + ni * 16 + r16;                 \
                    float y = (acc[mi][ni][reg] - m) * inv * (SBP)[colc]         \
                              + (SBP)[128 + colc];                               \
                    atile[lr * 128 + (((colc >> 3) ^ (lr & 7)) << 3)             \
                          + (colc & 7)] = (__bf16)fmaxf(y, 0.f);                 \
                }                                                                \
            }                                                                    \
        }                                                                        \
        stage_w(wl, WNEXT, tid);                                                 \
        __syncthreads();                                                         \
        _Pragma("unroll")                                                        \
        for (int mi = 0; mi < 2; ++mi)                                           \
            _Pragma("unroll")                                                    \
            for (int ni = 0; ni < 4; ++ni)                                       \
                acc[mi][ni] = (f32x4){0.f, 0.f, 0.f, 0.f};                       \
        mfma_tile(acc, atile, wl, waveM, waveN, r16, kq);                        \
    }

    CHAIN_STEP(ngn, wm1)
    CHAIN_STEP(m1gn, wm2)
    #undef CHAIN_STEP

    // final GN(m2gn) [+ roi residual if LP2] + relu -> store
    gn_stats(acc, smS, smQ, waveM, waveN, r16, kq);
    __syncthreads();
    #pragma unroll
    for (int mi = 0; mi < 2; ++mi) {
        #pragma unroll
        for (int reg = 0; reg < 4; ++reg) {
            const int lr = waveM * 32 + mi * 16 + kq * 4 + reg;
            const float S = smS[0][lr] + smS[1][lr];
            const float Q = smQ[0][lr] + smQ[1][lr];
            const float m = S * (1.f / 128.f);
            const float inv = rsqrtf(fmaxf(Q * (1.f / 128.f) - m * m, 0.f) + GN_EPS_F);
            const int crow = mbase + mi * 16 + kq * 4 + reg;
            if (crow < M) {
                #pragma unroll
                for (int ni = 0; ni < 4; ++ni) {
                    const int colc = waveN * 64 + ni * 16 + r16;
                    float y = (acc[mi][ni][reg] - m) * inv * m2gn[colc] + m2gn[128 + colc];
                    if (LP2) {
                        y += roi[(size_t)crow * 128 + colc];
                        ((float*)outp)[(size_t)crow * 128 + colc] = fmaxf(y, 0.f);
                    } else {
                        ((__bf16*)outp)[(size_t)crow * 128 + colc] = (__bf16)fmaxf(y, 0.f);
                    }
                }
            }
        }
    }
}

// ===========================================================================
extern "C" void kernel_launch(void* const* d_in, const int* in_sizes, int n_in,
                              void* d_out, int out_size, void* d_ws, size_t ws_size,
                              hipStream_t stream)
{
    const float* roi_feat   = (const float*)d_in[0];
    const float* graph_pose = (const float*)d_in[1];
    const float* roi_pose   = (const float*)d_in[2];
    const float* lp_input_w = (const float*)d_in[3];
    const float* lp_rpw     = (const float*)d_in[4];
    const float* lp_rpb     = (const float*)d_in[5];
    const float* lp_c1w     = (const float*)d_in[6];
    const float* lp_c1gn    = (const float*)d_in[7];
    const float* lp_c2w     = (const float*)d_in[8];
    const float* lp_m1w     = (const float*)d_in[9];
    const float* lp_m1gn    = (const float*)d_in[10];
    const float* lp_m2w     = (const float*)d_in[11];
    const float* lp_m2gn    = (const float*)d_in[12];
    const float* lp_ngn     = (const float*)d_in[13];
    const float* f_ctrw     = (const float*)d_in[14];
    const float* f_psw      = (const float*)d_in[15];
    const float* f_lw       = (const float*)d_in[16];
    const float* f_rw       = (const float*)d_in[17];
    const float* f_ngn      = (const float*)d_in[18];
    const float* f_c2w      = (const float*)d_in[19];
    const float* f_c2gn     = (const float*)d_in[20];
    const int* e1_hi = (const int*)d_in[21];
    const int* e1_wi = (const int*)d_in[22];
    const int* e2_hi = (const int*)d_in[23];
    const int* e2_wi = (const int*)d_in[24];
    const int* ps_u  = (const int*)d_in[25];
    const int* ps_v  = (const int*)d_in[26];
    const int* lr_u  = (const int*)d_in[27];
    const int* lr_v  = (const int*)d_in[28];
    float* out = (float*)d_out;

    // ---- workspace (~77 MB) ----
    __bf16* gA   = (__bf16*)d_ws;                       // NG*128
    __bf16* gB   = gA + (size_t)NG * 128;               // NG*128
    __bf16* hbuf = gB + (size_t)NG * 128;               // E1_N*128
    __bf16* wbuf = hbuf + (size_t)E1_N * 128;           // 80*16384
    int* ip      = (int*)(wbuf + (size_t)80 * 16384);
    int* cnt14   = ip;             ip += 14 * NG;
    int* rp14    = ip;             ip += 14 * NG + 1;
    int* col14   = ip;             ip += 12 * EPS_N + 2 * ELR_N;
    int* cntE1   = ip;             ip += NG;
    int* rpE1    = ip;             ip += NG + 1;
    int* colE1   = ip;             ip += E1_N;
    int* cntE2   = ip;             ip += NR;
    int* rpE2    = ip;             ip += NR + 1;
    int* colE2   = ip;             ip += E2_N;
    int* bsum    = ip;             ip += 256;

    dim3 blk(256);
    const dim3 gNG64((NG + 63) / 64), gNR64((NR + 63) / 64), gE64((E1_N + 63) / 64);
    const int NE14 = 12 * EPS_N + 2 * ELR_N;
    const dim3 gH14((NE14 + 255) / 256);

    // ---------------- weight prep ----------------
    PrepTab tab; int nw = 0;
    auto addw = [&](const float* p, int s) { tab.src[nw] = p; tab.stride[nw] = s; ++nw; };
    addw(lp_c1w, 256);                 // 0 c1A_0
    addw(lp_c1w + 128, 256);           // 1 c1B_0
    addw(lp_c1w + 32768, 256);         // 2 c1A_1
    addw(lp_c1w + 32768 + 128, 256);   // 3 c1B_1
    addw(lp_input_w + 16384, 128);     // 4 input_w[1]
    addw(lp_c2w, 128); addw(lp_c2w + 16384, 128);   // 5,6
    addw(lp_m1w, 128); addw(lp_m1w + 16384, 128);   // 7,8
    addw(lp_m2w, 128); addw(lp_m2w + 16384, 128);   // 9,10
    for (int i = 0; i < 4; ++i) addw(f_ctrw + (size_t)i * 16384, 128);      // 11..14
    for (int i = 0; i < 4; ++i)
        for (int k = 0; k < 12; ++k) addw(f_psw + ((size_t)i * 12 + k) * 16384, 128);
    for (int i = 0; i < 4; ++i) addw(f_lw + (size_t)i * 16384, 128);        // 63..66
    for (int i = 0; i < 4; ++i) addw(f_rw + (size_t)i * 16384, 128);        // 67..70
    for (int i = 0; i < 4; ++i) addw(f_c2w + (size_t)i * 16384, 128);       // 71..74
    tab.n = nw;
    auto wb = [&](int idx) { return (const __bf16*)(wbuf + (size_t)idx * 16384); };
    prepw_k<<<dim3((nw * 2048 + 255) / 256), blk, 0, stream>>>(tab, wbuf);

    // ---------------- CSR builds ----------------
    hipMemsetAsync(cnt14, 0, (size_t)14 * NG * 4, stream);
    hist14_k<<<gH14, blk, 0, stream>>>(ps_u, lr_u, cnt14);
    {
        int n = 14 * NG, nb = (n + SCAN_CHUNK - 1) / SCAN_CHUNK;
        scan1_k<<<nb, blk, 0, stream>>>(cnt14, n, bsum);
        scan2_k<<<1, blk, 0, stream>>>(bsum, nb);
        scan3_k<<<nb, blk, 0, stream>>>(cnt14, n, bsum, rp14);
    }
    hipMemcpyAsync(cnt14, rp14, (size_t)14 * NG * 4, hipMemcpyDeviceToDevice, stream);
    fill14_k<<<gH14, blk, 0, stream>>>(ps_u, ps_v, lr_u, lr_v, cnt14, col14);

    hipMemsetAsync(cntE1, 0, (size_t)NG * 4, stream);
    histE_k<<<(E1_N + 255) / 256, blk, 0, stream>>>(e1_wi, E1_N, cntE1);
    {
        int n = NG, nb = (n + SCAN_CHUNK - 1) / SCAN_CHUNK;
        scan1_k<<<nb, blk, 0, stream>>>(cntE1, n, bsum);
        scan2_k<<<1, blk, 0, stream>>>(bsum, nb);
        scan3_k<<<nb, blk, 0, stream>>>(cntE1, n, bsum, rpE1);
    }
    hipMemcpyAsync(cntE1, rpE1, (size_t)NG * 4, hipMemcpyDeviceToDevice, stream);
    fillE_k<<<(E1_N + 255) / 256, blk, 0, stream>>>(e1_wi, E1_N, cntE1, colE1);

    hipMemsetAsync(cntE2, 0, (size_t)NR * 4, stream);
    histE_k<<<(E2_N + 255) / 256, blk, 0, stream>>>(e2_wi, E2_N, cntE2);
    {
        int n = NR, nb = (n + SCAN_CHUNK - 1) / SCAN_CHUNK;
        scan1_k<<<nb, blk, 0, stream>>>(cntE2, n, bsum);
        scan2_k<<<1, blk, 0, stream>>>(bsum, nb);
        scan3_k<<<nb, blk, 0, stream>>>(cntE2, n, bsum, rpE2);
    }
    hipMemcpyAsync(cntE2, rpE2, (size_t)NR * 4, hipMemcpyDeviceToDevice, stream);
    fillE_k<<<(E2_N + 255) / 256, blk, 0, stream>>>(e2_wi, E2_N, cntE2, colE2);

    // ---------------- lane_pooling #1 (roi -> graph) ----------------
    edgefull_k<float><<<gE64, blk, 0, stream>>>(
        e1_hi, e1_wi, roi_feat, roi_pose, graph_pose, lp_rpw, lp_rpb,
        wb(0), wb(1), lp_c1gn, hbuf, E1_N);
    lptail_k<false><<<gNG64, blk, 0, stream>>>(
        hbuf, rpE1, colE1, nullptr, wb(5), nullptr, wb(7), wb(9),
        lp_ngn, lp_m1gn, lp_m2gn, gA, NG);

    // ---------------- global_graph: 4 fused layers ----------------
    for (int i = 0; i < 4; ++i) {
        FW fw;
        for (int k = 0; k < 12; ++k) fw.w[k] = wb(15 + i * 12 + k);
        fw.w[12] = wb(63 + i); fw.w[13] = wb(67 + i);
        fw.w[14] = wb(11 + i); fw.w[15] = wb(71 + i);
        const __bf16* src = (i & 1) ? gB : gA;
        __bf16* dst = (i & 1) ? gA : gB;
        fusedlayer_k<<<gNG64, blk, 0, stream>>>(
            src, rp14, col14, fw, f_ngn + (size_t)i * 256,
            f_c2gn + (size_t)i * 256, dst, NG);
    }
    // after i=3: result in gA

    // ---------------- lane_pooling #2 (graph -> roi) ----------------
    edgefull_k<__bf16><<<gE64, blk, 0, stream>>>(
        e2_hi, e2_wi, gA, graph_pose, roi_pose, lp_rpw + 512, lp_rpb + 128,
        wb(2), wb(3), lp_c1gn + 256, hbuf, E2_N);
    lptail_k<true><<<gNR64, blk, 0, stream>>>(
        hbuf, rpE2, colE2, roi_feat, wb(6), wb(4), wb(8), wb(10),
        lp_ngn + 256, lp_m1gn + 256, lp_m2gn + 256, out, NR);
}

// Round 7
// 829.341 us; speedup vs baseline: 2.8668x; 1.0201x over previous
//
#include <hip/hip_runtime.h>

#define NG 50000
#define NR 12000
#define EPS_N 50000
#define ELR_N 5000
#define E1_N 150000
#define E2_N 150000
#define GN_EPS_F 1e-5f
#define SCAN_CHUNK 4096
#define AST 136   // padded atile row stride (elements)

typedef __attribute__((ext_vector_type(8))) __bf16 bf16x8;
typedef __attribute__((ext_vector_type(4))) float f32x4;

__device__ __forceinline__ bf16x8 cvt8(const float* __restrict__ p) {
    float4 x0 = *reinterpret_cast<const float4*>(p);
    float4 x1 = *reinterpret_cast<const float4*>(p + 4);
    bf16x8 a;
    a[0] = (__bf16)x0.x; a[1] = (__bf16)x0.y; a[2] = (__bf16)x0.z; a[3] = (__bf16)x0.w;
    a[4] = (__bf16)x1.x; a[5] = (__bf16)x1.y; a[6] = (__bf16)x1.z; a[7] = (__bf16)x1.w;
    return a;
}

// ====== weight prep: f32 -> fragment-major bf16 (global, coalesced reads) ===
// chunk c∈[0,32): c = waveN*16 + ks*4 + ni ; within chunk lane l owns 16B:
//   W[waveN*64 + ni*16 + (l&15)][(ks*4 + (l>>4))*8 .. +8]
struct PrepTab { const float* src[80]; int stride[80]; int n; };

__global__ void prepw_k(PrepTab tab, __bf16* __restrict__ wbuf)
{
    int t = blockIdx.x * 256 + threadIdx.x;
    int w = t >> 11;
    if (w >= tab.n) return;
    int rr = t & 2047;
    int chunk = rr >> 6, l = rr & 63;
    int waveN = chunk >> 4, ks = (chunk >> 2) & 3, ni = chunk & 3;
    int c = waveN * 64 + ni * 16 + (l & 15);
    int kb = (ks * 4 + (l >> 4)) * 8;
    const float* s = tab.src[w] + (size_t)c * tab.stride[w] + kb;
    bf16x8 o;
    #pragma unroll
    for (int e = 0; e < 8; ++e) o[e] = (__bf16)s[e];
    *reinterpret_cast<bf16x8*>(wbuf + (size_t)w * 16384 + rr * 8) = o;
}

// ============================ CSR construction =============================
__global__ void hist14_k(const int* __restrict__ ps_u, const int* __restrict__ lr_u,
                         int* __restrict__ cnt)
{
    int t = blockIdx.x * 256 + threadIdx.x;
    const int total = 12 * EPS_N + 2 * ELR_N;
    if (t >= total) return;
    int k, u;
    if (t < 12 * EPS_N) { k = t / EPS_N; u = ps_u[t]; }
    else { int r = t - 12 * EPS_N; k = 12 + r / ELR_N; u = lr_u[r]; }
    atomicAdd(&cnt[k * NG + u], 1);
}

__global__ void fill14_k(const int* __restrict__ ps_u, const int* __restrict__ ps_v,
                         const int* __restrict__ lr_u, const int* __restrict__ lr_v,
                         int* __restrict__ head, int* __restrict__ col)
{
    int t = blockIdx.x * 256 + threadIdx.x;
    const int total = 12 * EPS_N + 2 * ELR_N;
    if (t >= total) return;
    int k, u, v;
    if (t < 12 * EPS_N) { k = t / EPS_N; u = ps_u[t]; v = ps_v[t]; }
    else { int r = t - 12 * EPS_N; k = 12 + r / ELR_N; u = lr_u[r]; v = lr_v[r]; }
    int pos = atomicAdd(&head[k * NG + u], 1);
    col[pos] = v;
}

__global__ void histE_k(const int* __restrict__ wi, int n, int* __restrict__ cnt)
{
    int t = blockIdx.x * 256 + threadIdx.x;
    if (t >= n) return;
    atomicAdd(&cnt[wi[t]], 1);
}

__global__ void fillE_k(const int* __restrict__ wi, int n,
                        int* __restrict__ head, int* __restrict__ col)
{
    int t = blockIdx.x * 256 + threadIdx.x;
    if (t >= n) return;
    int pos = atomicAdd(&head[wi[t]], 1);
    col[pos] = t;
}

__global__ void scan1_k(const int* __restrict__ in, int n, int* __restrict__ bsum)
{
    __shared__ int sm[4];
    int base = blockIdx.x * SCAN_CHUNK;
    int s = 0;
    for (int i = threadIdx.x; i < SCAN_CHUNK; i += 256) {
        int idx = base + i;
        s += (idx < n) ? in[idx] : 0;
    }
    #pragma unroll
    for (int off = 1; off < 64; off <<= 1) s += __shfl_xor(s, off);
    if ((threadIdx.x & 63) == 0) sm[threadIdx.x >> 6] = s;
    __syncthreads();
    if (threadIdx.x == 0) bsum[blockIdx.x] = sm[0] + sm[1] + sm[2] + sm[3];
}

__global__ void scan2_k(int* __restrict__ bsum, int nb)
{
    if (threadIdx.x == 0) {
        int acc = 0;
        for (int i = 0; i < nb; ++i) { int t = bsum[i]; bsum[i] = acc; acc += t; }
    }
}

__global__ void scan3_k(const int* __restrict__ in, int n,
                        const int* __restrict__ bsum, int* __restrict__ outp)
{
    __shared__ int sm[256];
    int base = blockIdx.x * SCAN_CHUNK;
    int loc[16]; int s = 0;
    #pragma unroll
    for (int i = 0; i < 16; ++i) {
        int idx = base + threadIdx.x * 16 + i;
        loc[i] = (idx < n) ? in[idx] : 0; s += loc[i];
    }
    sm[threadIdx.x] = s; __syncthreads();
    for (int off = 1; off < 256; off <<= 1) {
        int v = (threadIdx.x >= off) ? sm[threadIdx.x - off] : 0;
        __syncthreads();
        sm[threadIdx.x] += v;
        __syncthreads();
    }
    int tp = (threadIdx.x ? sm[threadIdx.x - 1] : 0) + bsum[blockIdx.x];
    #pragma unroll
    for (int i = 0; i < 16; ++i) {
        int idx = base + threadIdx.x * 16 + i;
        if (idx < n) outp[idx] = tp;
        tp += loc[i];
        if (idx == n - 1) outp[n] = tp;
    }
}

// ======================= shared device helpers =============================
// one K=128 MFMA sweep: acc += atile-rows @ W^T, B from frag-major GLOBAL
__device__ __forceinline__ void mfma_tile(f32x4 (&acc)[2][4], const __bf16* atile,
                                          const __bf16* __restrict__ gw,
                                          int waveM, int waveN, int r16, int kq,
                                          int lane)
{
    const __bf16* gwb = gw + ((size_t)waveN << 13) + lane * 8;   // waveN*16*512
    #pragma unroll
    for (int ks = 0; ks < 4; ++ks) {
        bf16x8 a[2], b[4];
        #pragma unroll
        for (int mi = 0; mi < 2; ++mi) {
            const int lr = waveM * 32 + mi * 16 + r16;
            a[mi] = *reinterpret_cast<const bf16x8*>(atile + lr * AST + ((ks << 2) + kq) * 8);
        }
        #pragma unroll
        for (int ni = 0; ni < 4; ++ni)
            b[ni] = *reinterpret_cast<const bf16x8*>(gwb + ((ks << 2) + ni) * 512);
        #pragma unroll
        for (int mi = 0; mi < 2; ++mi)
            #pragma unroll
            for (int ni = 0; ni < 4; ++ni)
                acc[mi][ni] = __builtin_amdgcn_mfma_f32_16x16x32_bf16(
                    a[mi], b[ni], acc[mi][ni], 0, 0, 0);
    }
}

__device__ __forceinline__ void gn_stats(const f32x4 (&acc)[2][4],
                                         float (*smS)[64], float (*smQ)[64],
                                         int waveM, int waveN, int r16, int kq)
{
    #pragma unroll
    for (int mi = 0; mi < 2; ++mi) {
        #pragma unroll
        for (int reg = 0; reg < 4; ++reg) {
            float s = acc[mi][0][reg] + acc[mi][1][reg] + acc[mi][2][reg] + acc[mi][3][reg];
            float q = acc[mi][0][reg]*acc[mi][0][reg] + acc[mi][1][reg]*acc[mi][1][reg]
                    + acc[mi][2][reg]*acc[mi][2][reg] + acc[mi][3][reg]*acc[mi][3][reg];
            #pragma unroll
            for (int off = 1; off < 16; off <<= 1) {
                s += __shfl_xor(s, off);
                q += __shfl_xor(q, off);
            }
            if (r16 == 0) {
                int lr = waveM * 32 + mi * 16 + kq * 4 + reg;
                smS[waveN][lr] = s; smQ[waveN][lr] = q;
            }
        }
    }
}

// ============ edgefull: h[e] = relu(gn(ctx[hi]@c1A + dist@c1B, sb)) =========
template<typename CT>
__launch_bounds__(256)
__global__ void edgefull_k(const int* __restrict__ hi_idx, const int* __restrict__ wi_idx,
                           const CT* __restrict__ ctxfeat,
                           const float* __restrict__ cpose, const float* __restrict__ tpose,
                           const float* __restrict__ rpw, const float* __restrict__ rpb,
                           const __bf16* __restrict__ wc1A, const __bf16* __restrict__ wc1B,
                           const float* __restrict__ sb,
                           __bf16* __restrict__ hout, int M)
{
    __shared__ __bf16 atile[64 * AST];
    __shared__ float rw[640];
    __shared__ float smS[2][64], smQ[2][64];
    const int tid = threadIdx.x, lane = tid & 63, wave = tid >> 6;
    const int waveM = wave >> 1, waveN = wave & 1;
    const int r16 = lane & 15, kq = lane >> 4;
    const int ublk = blockIdx.x * 64;
    const int mbase = ublk + waveM * 32;

    for (int i = tid; i < 640; i += 256)
        rw[i] = (i < 512) ? rpw[i] : rpb[i - 512];

    float dl[2][4];
    #pragma unroll
    for (int mi = 0; mi < 2; ++mi) {
        int r = mbase + mi * 16 + r16;
        int e = r < M ? r : M - 1;
        int hi = hi_idx[e], wi = wi_idx[e];
        float4 cp = *reinterpret_cast<const float4*>(cpose + (size_t)hi * 4);
        float4 tp = *reinterpret_cast<const float4*>(tpose + (size_t)wi * 4);
        dl[mi][0] = cp.x - tp.x; dl[mi][1] = cp.y - tp.y;
        dl[mi][2] = cp.z - tp.z; dl[mi][3] = cp.w - tp.w;
    }

    {   // gather ctx rows -> atile
        const int glr = tid >> 2, q = tid & 3;
        const int e = (ublk + glr) < M ? (ublk + glr) : M - 1;
        const int cr = hi_idx[e];
        const CT* sp = ctxfeat + (size_t)cr * 128 + q * 32;
        #pragma unroll
        for (int i = 0; i < 4; ++i) {
            bf16x8 h;
            if constexpr (sizeof(CT) == 4) h = cvt8((const float*)sp + i * 8);
            else h = *reinterpret_cast<const bf16x8*>((const __bf16*)sp + i * 8);
            *reinterpret_cast<bf16x8*>(atile + glr * AST + (q * 4 + i) * 8) = h;
        }
    }
    __syncthreads();

    f32x4 acc[2][4];
    #pragma unroll
    for (int mi = 0; mi < 2; ++mi)
        #pragma unroll
        for (int ni = 0; ni < 4; ++ni)
            acc[mi][ni] = (f32x4){0.f, 0.f, 0.f, 0.f};

    mfma_tile(acc, atile, wc1A, waveM, waveN, r16, kq, lane);

    // dist matmul (A in-register, B frag-major global)
    {
        const __bf16* gwb = wc1B + ((size_t)waveN << 13) + lane * 8;
        #pragma unroll
        for (int ks = 0; ks < 4; ++ks) {
            bf16x8 a[2], b[4];
            #pragma unroll
            for (int mi = 0; mi < 2; ++mi) {
                #pragma unroll
                for (int i = 0; i < 8; ++i) {
                    const int k = ks * 32 + kq * 8 + i;
                    float4 w4 = *reinterpret_cast<const float4*>(&rw[k * 4]);
                    float d = fmaf(dl[mi][0], w4.x, fmaf(dl[mi][1], w4.y,
                              fmaf(dl[mi][2], w4.z, fmaf(dl[mi][3], w4.w, rw[512 + k]))));
                    a[mi][i] = (__bf16)fmaxf(d, 0.f);
                }
            }
            #pragma unroll
            for (int ni = 0; ni < 4; ++ni)
                b[ni] = *reinterpret_cast<const bf16x8*>(gwb + ((ks << 2) + ni) * 512);
            #pragma unroll
            for (int mi = 0; mi < 2; ++mi)
                #pragma unroll
                for (int ni = 0; ni < 4; ++ni)
                    acc[mi][ni] = __builtin_amdgcn_mfma_f32_16x16x32_bf16(
                        a[mi], b[ni], acc[mi][ni], 0, 0, 0);
        }
    }

    gn_stats(acc, smS, smQ, waveM, waveN, r16, kq);
    __syncthreads();

    #pragma unroll
    for (int mi = 0; mi < 2; ++mi) {
        #pragma unroll
        for (int reg = 0; reg < 4; ++reg) {
            const int lr = waveM * 32 + mi * 16 + kq * 4 + reg;
            const float S = smS[0][lr] + smS[1][lr];
            const float Q = smQ[0][lr] + smQ[1][lr];
            const float m = S * (1.f / 128.f);
            const float inv = rsqrtf(fmaxf(Q * (1.f / 128.f) - m * m, 0.f) + GN_EPS_F);
            const int crow = mbase + mi * 16 + kq * 4 + reg;
            if (crow < M) {
                __bf16* dp = hout + (size_t)crow * 128 + waveN * 64 + r16;
                #pragma unroll
                for (int ni = 0; ni < 4; ++ni) {
                    const int colc = waveN * 64 + ni * 16 + r16;
                    float y = (acc[mi][ni][reg] - m) * inv * sb[colc] + sb[128 + colc];
                    dp[ni * 16] = (__bf16)fmaxf(y, 0.f);
                }
            }
        }
    }
}

// ======= fusedlayer: one global_graph fusion layer, double-buffered atile ===
struct FW { const __bf16* w[16]; };   // 0..11 ps, 12 left, 13 right, 14 ctr, 15 ctr2

__launch_bounds__(256)
__global__ void fusedlayer_k(const __bf16* __restrict__ feat,
                             const int* __restrict__ rp, const int* __restrict__ col,
                             FW fw, const float* __restrict__ gn1,
                             const float* __restrict__ gn2,
                             __bf16* __restrict__ outp, int M)
{
    __shared__ __bf16 atile[2][64 * AST];
    __shared__ float smS[2][64], smQ[2][64];
    const int tid = threadIdx.x, lane = tid & 63, wave = tid >> 6;
    const int waveM = wave >> 1, waveN = wave & 1;
    const int r16 = lane & 15, kq = lane >> 4;
    const int ublk = blockIdx.x * 64;
    const int mbase = ublk + waveM * 32;
    const int glr = tid >> 2, q = tid & 3;
    const int grow = ublk + glr;
    const bool gv = grow < M;
    const int grc = gv ? grow : 0;

    float ss[32];
    // gather for scale jj into ss (jj compile-time under unroll; 14 = self)
    auto GATHER = [&](int jj) {
        #pragma unroll
        for (int i = 0; i < 32; ++i) ss[i] = 0.f;
        if (jj == 14) {
            const __bf16* sp = feat + (size_t)grc * 128 + q * 32;
            #pragma unroll
            for (int i = 0; i < 4; ++i) {
                bf16x8 h = *reinterpret_cast<const bf16x8*>(sp + i * 8);
                #pragma unroll
                for (int e = 0; e < 8; ++e) ss[i * 8 + e] = (float)h[e];
            }
        } else if (gv) {
            const int b = rp[jj * M + grow], e = rp[jj * M + grow + 1];
            for (int t2 = b; t2 < e; ++t2) {
                const __bf16* sp = feat + (size_t)col[t2] * 128 + q * 32;
                #pragma unroll
                for (int i = 0; i < 4; ++i) {
                    bf16x8 h = *reinterpret_cast<const bf16x8*>(sp + i * 8);
                    #pragma unroll
                    for (int e2 = 0; e2 < 8; ++e2) ss[i * 8 + e2] += (float)h[e2];
                }
            }
        }
    };

    f32x4 acc[2][4];
    #pragma unroll
    for (int mi = 0; mi < 2; ++mi)
        #pragma unroll
        for (int ni = 0; ni < 4; ++ni)
            acc[mi][ni] = (f32x4){0.f, 0.f, 0.f, 0.f};

    GATHER(0);
    #pragma unroll
    for (int j = 0; j < 15; ++j) {
        // write ss -> atile[j&1]
        __bf16* at = atile[j & 1];
        #pragma unroll
        for (int i = 0; i < 4; ++i) {
            bf16x8 o;
            #pragma unroll
            for (int e = 0; e < 8; ++e) o[e] = (__bf16)ss[i * 8 + e];
            *reinterpret_cast<bf16x8*>(at + glr * AST + (q * 4 + i) * 8) = o;
        }
        __syncthreads();
        if (j < 14) GATHER(j + 1);           // loads overlap this j's MFMA
        mfma_tile(acc, at, fw.w[j], waveM, waveN, r16, kq, lane);
    }

    // GN1 + relu -> atile[1] (read last at j=13; safe after j=14's sync)
    gn_stats(acc, smS, smQ, waveM, waveN, r16, kq);
    __syncthreads();
    {
        __bf16* at = atile[1];
        #pragma unroll
        for (int mi = 0; mi < 2; ++mi) {
            #pragma unroll
            for (int reg = 0; reg < 4; ++reg) {
                const int lr = waveM * 32 + mi * 16 + kq * 4 + reg;
                const float S = smS[0][lr] + smS[1][lr];
                const float Q = smQ[0][lr] + smQ[1][lr];
                const float m = S * (1.f / 128.f);
                const float inv = rsqrtf(fmaxf(Q * (1.f / 128.f) - m * m, 0.f) + GN_EPS_F);
                #pragma unroll
                for (int ni = 0; ni < 4; ++ni) {
                    const int colc = waveN * 64 + ni * 16 + r16;
                    float y = (acc[mi][ni][reg] - m) * inv * gn1[colc] + gn1[128 + colc];
                    at[lr * AST + colc] = (__bf16)fmaxf(y, 0.f);
                }
            }
        }
    }
    __syncthreads();

    f32x4 acc2[2][4];
    #pragma unroll
    for (int mi = 0; mi < 2; ++mi)
        #pragma unroll
        for (int ni = 0; ni < 4; ++ni)
            acc2[mi][ni] = (f32x4){0.f, 0.f, 0.f, 0.f};
    mfma_tile(acc2, atile[1], fw.w[15], waveM, waveN, r16, kq, lane);

    gn_stats(acc2, smS, smQ, waveM, waveN, r16, kq);
    __syncthreads();
    #pragma unroll
    for (int mi = 0; mi < 2; ++mi) {
        #pragma unroll
        for (int reg = 0; reg < 4; ++reg) {
            const int lr = waveM * 32 + mi * 16 + kq * 4 + reg;
            const float S = smS[0][lr] + smS[1][lr];
            const float Q = smQ[0][lr] + smQ[1][lr];
            const float m = S * (1.f / 128.f);
            const float inv = rsqrtf(fmaxf(Q * (1.f / 128.f) - m * m, 0.f) + GN_EPS_F);
            const int crow = mbase + mi * 16 + kq * 4 + reg;
            if (crow < M) {
                __bf16* dp = outp + (size_t)crow * 128 + waveN * 64 + r16;
                const __bf16* rs = feat + (size_t)crow * 128 + waveN * 64 + r16;
                #pragma unroll
                for (int ni = 0; ni < 4; ++ni) {
                    const int colc = waveN * 64 + ni * 16 + r16;
                    float y = (acc2[mi][ni][reg] - m) * inv * gn2[colc] + gn2[128 + colc];
                    y += (float)rs[ni * 16];
                    dp[ni * 16] = (__bf16)fmaxf(y, 0.f);
                }
            }
        }
    }
}

// ============= lptail: lane_pooling tail (chained GEMMs + GNs) ==============
template<bool LP2>
__launch_bounds__(256)
__global__ void lptail_k(const __bf16* __restrict__ hsrc,
                         const int* __restrict__ rp, const int* __restrict__ col,
                         const float* __restrict__ roi,
                         const __bf16* __restrict__ wc2, const __bf16* __restrict__ winW,
                         const __bf16* __restrict__ wm1, const __bf16* __restrict__ wm2,
                         const float* __restrict__ ngn, const float* __restrict__ m1gn,
                         const float* __restrict__ m2gn,
                         void* __restrict__ outp, int M)
{
    __shared__ __bf16 atile[64 * AST];
    __shared__ float smS[2][64], smQ[2][64];
    const int tid = threadIdx.x, lane = tid & 63, wave = tid >> 6;
    const int waveM = wave >> 1, waveN = wave & 1;
    const int r16 = lane & 15, kq = lane >> 4;
    const int ublk = blockIdx.x * 64;
    const int mbase = ublk + waveM * 32;
    const int glr = tid >> 2, q = tid & 3;
    const int grow = ublk + glr;
    const bool gv = grow < M;

    // phase A: gather Σh -> atile; mfma c2
    {
        float ss[32];
        #pragma unroll
        for (int i = 0; i < 32; ++i) ss[i] = 0.f;
        if (gv) {
            const int b = rp[grow], e = rp[grow + 1];
            for (int jj = b; jj < e; ++jj) {
                const __bf16* sp = hsrc + (size_t)col[jj] * 128 + q * 32;
                #pragma unroll
                for (int i = 0; i < 4; ++i) {
                    bf16x8 h = *reinterpret_cast<const bf16x8*>(sp + i * 8);
                    #pragma unroll
                    for (int e2 = 0; e2 < 8; ++e2) ss[i * 8 + e2] += (float)h[e2];
                }
            }
        }
        #pragma unroll
        for (int i = 0; i < 4; ++i) {
            bf16x8 o;
            #pragma unroll
            for (int e2 = 0; e2 < 8; ++e2) o[e2] = (__bf16)ss[i * 8 + e2];
            *reinterpret_cast<bf16x8*>(atile + glr * AST + (q * 4 + i) * 8) = o;
        }
    }
    __syncthreads();

    f32x4 acc[2][4];
    #pragma unroll
    for (int mi = 0; mi < 2; ++mi)
        #pragma unroll
        for (int ni = 0; ni < 4; ++ni)
            acc[mi][ni] = (f32x4){0.f, 0.f, 0.f, 0.f};
    mfma_tile(acc, atile, wc2, waveM, waveN, r16, kq, lane);

    if (LP2) {   // + roi @ input_w
        __syncthreads();
        {
            const float* sp = roi + (size_t)(gv ? grow : 0) * 128 + q * 32;
            #pragma unroll
            for (int i = 0; i < 4; ++i)
                *reinterpret_cast<bf16x8*>(atile + glr * AST + (q * 4 + i) * 8) =
                    cvt8(sp + i * 8);
        }
        __syncthreads();
        mfma_tile(acc, atile, winW, waveM, waveN, r16, kq, lane);
    }

    // chain: GN(acc,SBP)+relu -> atile; mfma WNEXT (fresh acc)
    auto CHAIN = [&](const float* SBP, const __bf16* WNEXT) {
        gn_stats(acc, smS, smQ, waveM, waveN, r16, kq);
        __syncthreads();
        #pragma unroll
        for (int mi = 0; mi < 2; ++mi) {
            #pragma unroll
            for (int reg = 0; reg < 4; ++reg) {
                const int lr = waveM * 32 + mi * 16 + kq * 4 + reg;
                const float S = smS[0][lr] + smS[1][lr];
                const float Q = smQ[0][lr] + smQ[1][lr];
                const float m = S * (1.f / 128.f);
                const float inv = rsqrtf(fmaxf(Q * (1.f / 128.f) - m * m, 0.f) + GN_EPS_F);
                #pragma unroll
                for (int ni = 0; ni < 4; ++ni) {
                    const int colc = waveN * 64 + ni * 16 + r16;
                    float y = (acc[mi][ni][reg] - m) * inv * SBP[colc] + SBP[128 + colc];
                    atile[lr * AST + colc] = (__bf16)fmaxf(y, 0.f);
                }
            }
        }
        __syncthreads();
        #pragma unroll
        for (int mi = 0; mi < 2; ++mi)
            #pragma unroll
            for (int ni = 0; ni < 4; ++ni)
                acc[mi][ni] = (f32x4){0.f, 0.f, 0.f, 0.f};
        mfma_tile(acc, atile, WNEXT, waveM, waveN, r16, kq, lane);
    };
    CHAIN(ngn, wm1);
    CHAIN(m1gn, wm2);

    gn_stats(acc, smS, smQ, waveM, waveN, r16, kq);
    __syncthreads();
    #pragma unroll
    for (int mi = 0; mi < 2; ++mi) {
        #pragma unroll
        for (int reg = 0; reg < 4; ++reg) {
            const int lr = waveM * 32 + mi * 16 + kq * 4 + reg;
            const float S = smS[0][lr] + smS[1][lr];
            const float Q = smQ[0][lr] + smQ[1][lr];
            const float m = S * (1.f / 128.f);
            const float inv = rsqrtf(fmaxf(Q * (1.f / 128.f) - m * m, 0.f) + GN_EPS_F);
            const int crow = mbase + mi * 16 + kq * 4 + reg;
            if (crow < M) {
                #pragma unroll
                for (int ni = 0; ni < 4; ++ni) {
                    const int colc = waveN * 64 + ni * 16 + r16;
                    float y = (acc[mi][ni][reg] - m) * inv * m2gn[colc] + m2gn[128 + colc];
                    if (LP2) {
                        y += roi[(size_t)crow * 128 + colc];
                        ((float*)outp)[(size_t)crow * 128 + colc] = fmaxf(y, 0.f);
                    } else {
                        ((__bf16*)outp)[(size_t)crow * 128 + colc] = (__bf16)fmaxf(y, 0.f);
                    }
                }
            }
        }
    }
}

// ===========================================================================
extern "C" void kernel_launch(void* const* d_in, const int* in_sizes, int n_in,
                              void* d_out, int out_size, void* d_ws, size_t ws_size,
                              hipStream_t stream)
{
    const float* roi_feat   = (const float*)d_in[0];
    const float* graph_pose = (const float*)d_in[1];
    const float* roi_pose   = (const float*)d_in[2];
    const float* lp_input_w = (const float*)d_in[3];
    const float* lp_rpw     = (const float*)d_in[4];
    const float* lp_rpb     = (const float*)d_in[5];
    const float* lp_c1w     = (const float*)d_in[6];
    const float* lp_c1gn    = (const float*)d_in[7];
    const float* lp_c2w     = (const float*)d_in[8];
    const float* lp_m1w     = (const float*)d_in[9];
    const float* lp_m1gn    = (const float*)d_in[10];
    const float* lp_m2w     = (const float*)d_in[11];
    const float* lp_m2gn    = (const float*)d_in[12];
    const float* lp_ngn     = (const float*)d_in[13];
    const float* f_ctrw     = (const float*)d_in[14];
    const float* f_psw      = (const float*)d_in[15];
    const float* f_lw       = (const float*)d_in[16];
    const float* f_rw       = (const float*)d_in[17];
    const float* f_ngn      = (const float*)d_in[18];
    const float* f_c2w      = (const float*)d_in[19];
    const float* f_c2gn     = (const float*)d_in[20];
    const int* e1_hi = (const int*)d_in[21];
    const int* e1_wi = (const int*)d_in[22];
    const int* e2_hi = (const int*)d_in[23];
    const int* e2_wi = (const int*)d_in[24];
    const int* ps_u  = (const int*)d_in[25];
    const int* ps_v  = (const int*)d_in[26];
    const int* lr_u  = (const int*)d_in[27];
    const int* lr_v  = (const int*)d_in[28];
    float* out = (float*)d_out;

    // ---- workspace (~77 MB) ----
    __bf16* gA   = (__bf16*)d_ws;                       // NG*128
    __bf16* gB   = gA + (size_t)NG * 128;               // NG*128
    __bf16* hbuf = gB + (size_t)NG * 128;               // E1_N*128
    __bf16* wbuf = hbuf + (size_t)E1_N * 128;           // 80*16384
    int* ip      = (int*)(wbuf + (size_t)80 * 16384);
    int* cnt14   = ip;             ip += 14 * NG;
    int* rp14    = ip;             ip += 14 * NG + 1;
    int* col14   = ip;             ip += 12 * EPS_N + 2 * ELR_N;
    int* cntE1   = ip;             ip += NG;
    int* rpE1    = ip;             ip += NG + 1;
    int* colE1   = ip;             ip += E1_N;
    int* cntE2   = ip;             ip += NR;
    int* rpE2    = ip;             ip += NR + 1;
    int* colE2   = ip;             ip += E2_N;
    int* bsum    = ip;             ip += 256;

    dim3 blk(256);
    const dim3 gNG64((NG + 63) / 64), gNR64((NR + 63) / 64), gE64((E1_N + 63) / 64);
    const int NE14 = 12 * EPS_N + 2 * ELR_N;
    const dim3 gH14((NE14 + 255) / 256);

    // ---------------- weight prep ----------------
    PrepTab tab; int nw = 0;
    auto addw = [&](const float* p, int s) { tab.src[nw] = p; tab.stride[nw] = s; ++nw; };
    addw(lp_c1w, 256);                 // 0 c1A_0
    addw(lp_c1w + 128, 256);           // 1 c1B_0
    addw(lp_c1w + 32768, 256);         // 2 c1A_1
    addw(lp_c1w + 32768 + 128, 256);   // 3 c1B_1
    addw(lp_input_w + 16384, 128);     // 4 input_w[1]
    addw(lp_c2w, 128); addw(lp_c2w + 16384, 128);   // 5,6
    addw(lp_m1w, 128); addw(lp_m1w + 16384, 128);   // 7,8
    addw(lp_m2w, 128); addw(lp_m2w + 16384, 128);   // 9,10
    for (int i = 0; i < 4; ++i) addw(f_ctrw + (size_t)i * 16384, 128);      // 11..14
    for (int i = 0; i < 4; ++i)
        for (int k = 0; k < 12; ++k) addw(f_psw + ((size_t)i * 12 + k) * 16384, 128);
    for (int i = 0; i < 4; ++i) addw(f_lw + (size_t)i * 16384, 128);        // 63..66
    for (int i = 0; i < 4; ++i) addw(f_rw + (size_t)i * 16384, 128);        // 67..70
    for (int i = 0; i < 4; ++i) addw(f_c2w + (size_t)i * 16384, 128);       // 71..74
    tab.n = nw;
    auto wb = [&](int idx) { return (const __bf16*)(wbuf + (size_t)idx * 16384); };
    prepw_k<<<dim3((nw * 2048 + 255) / 256), blk, 0, stream>>>(tab, wbuf);

    // ---------------- CSR builds ----------------
    hipMemsetAsync(cnt14, 0, (size_t)14 * NG * 4, stream);
    hist14_k<<<gH14, blk, 0, stream>>>(ps_u, lr_u, cnt14);
    {
        int n = 14 * NG, nb = (n + SCAN_CHUNK - 1) / SCAN_CHUNK;
        scan1_k<<<nb, blk, 0, stream>>>(cnt14, n, bsum);
        scan2_k<<<1, blk, 0, stream>>>(bsum, nb);
        scan3_k<<<nb, blk, 0, stream>>>(cnt14, n, bsum, rp14);
    }
    hipMemcpyAsync(cnt14, rp14, (size_t)14 * NG * 4, hipMemcpyDeviceToDevice, stream);
    fill14_k<<<gH14, blk, 0, stream>>>(ps_u, ps_v, lr_u, lr_v, cnt14, col14);

    hipMemsetAsync(cntE1, 0, (size_t)NG * 4, stream);
    histE_k<<<(E1_N + 255) / 256, blk, 0, stream>>>(e1_wi, E1_N, cntE1);
    {
        int n = NG, nb = (n + SCAN_CHUNK - 1) / SCAN_CHUNK;
        scan1_k<<<nb, blk, 0, stream>>>(cntE1, n, bsum);
        scan2_k<<<1, blk, 0, stream>>>(bsum, nb);
        scan3_k<<<nb, blk, 0, stream>>>(cntE1, n, bsum, rpE1);
    }
    hipMemcpyAsync(cntE1, rpE1, (size_t)NG * 4, hipMemcpyDeviceToDevice, stream);
    fillE_k<<<(E1_N + 255) / 256, blk, 0, stream>>>(e1_wi, E1_N, cntE1, colE1);

    hipMemsetAsync(cntE2, 0, (size_t)NR * 4, stream);
    histE_k<<<(E2_N + 255) / 256, blk, 0, stream>>>(e2_wi, E2_N, cntE2);
    {
        int n = NR, nb = (n + SCAN_CHUNK - 1) / SCAN_CHUNK;
        scan1_k<<<nb, blk, 0, stream>>>(cntE2, n, bsum);
        scan2_k<<<1, blk, 0, stream>>>(bsum, nb);
        scan3_k<<<nb, blk, 0, stream>>>(cntE2, n, bsum, rpE2);
    }
    hipMemcpyAsync(cntE2, rpE2, (size_t)NR * 4, hipMemcpyDeviceToDevice, stream);
    fillE_k<<<(E2_N + 255) / 256, blk, 0, stream>>>(e2_wi, E2_N, cntE2, colE2);

    // ---------------- lane_pooling #1 (roi -> graph) ----------------
    edgefull_k<float><<<gE64, blk, 0, stream>>>(
        e1_hi, e1_wi, roi_feat, roi_pose, graph_pose, lp_rpw, lp_rpb,
        wb(0), wb(1), lp_c1gn, hbuf, E1_N);
    lptail_k<false><<<gNG64, blk, 0, stream>>>(
        hbuf, rpE1, colE1, nullptr, wb(5), nullptr, wb(7), wb(9),
        lp_ngn, lp_m1gn, lp_m2gn, gA, NG);

    // ---------------- global_graph: 4 fused layers ----------------
    for (int i = 0; i < 4; ++i) {
        FW fw;
        for (int k = 0; k < 12; ++k) fw.w[k] = wb(15 + i * 12 + k);
        fw.w[12] = wb(63 + i); fw.w[13] = wb(67 + i);
        fw.w[14] = wb(11 + i); fw.w[15] = wb(71 + i);
        const __bf16* src = (i & 1) ? gB : gA;
        __bf16* dst = (i & 1) ? gA : gB;
        fusedlayer_k<<<gNG64, blk, 0, stream>>>(
            src, rp14, col14, fw, f_ngn + (size_t)i * 256,
            f_c2gn + (size_t)i * 256, dst, NG);
    }
    // after i=3: result in gA

    // ---------------- lane_pooling #2 (graph -> roi) ----------------
    edgefull_k<__bf16><<<gE64, blk, 0, stream>>>(
        e2_hi, e2_wi, gA, graph_pose, roi_pose, lp_rpw + 512, lp_rpb + 128,
        wb(2), wb(3), lp_c1gn + 256, hbuf, E2_N);
    lptail_k<true><<<gNR64, blk, 0, stream>>>(
        hbuf, rpE2, colE2, roi_feat, wb(6), wb(4), wb(8), wb(10),
        lp_ngn + 256, lp_m1gn + 256, lp_m2gn + 256, out, NR);
}

// Round 8
// 765.094 us; speedup vs baseline: 3.1076x; 1.0840x over previous
//
#include <hip/hip_runtime.h>

#define NG 50000
#define NR 12000
#define EPS_N 50000
#define ELR_N 5000
#define E1_N 150000
#define E2_N 150000
#define GN_EPS_F 1e-5f
#define SCAN_CHUNK 4096
#define AST 136   // padded atile row stride (elements)

typedef __attribute__((ext_vector_type(8))) __bf16 bf16x8;
typedef __attribute__((ext_vector_type(4))) float f32x4;

__device__ __forceinline__ bf16x8 cvt8(const float* __restrict__ p) {
    float4 x0 = *reinterpret_cast<const float4*>(p);
    float4 x1 = *reinterpret_cast<const float4*>(p + 4);
    bf16x8 a;
    a[0] = (__bf16)x0.x; a[1] = (__bf16)x0.y; a[2] = (__bf16)x0.z; a[3] = (__bf16)x0.w;
    a[4] = (__bf16)x1.x; a[5] = (__bf16)x1.y; a[6] = (__bf16)x1.z; a[7] = (__bf16)x1.w;
    return a;
}

// ====== weight prep: f32 -> fragment-major bf16 (global, coalesced reads) ===
struct PrepTab { const float* src[80]; int stride[80]; int n; };

__global__ void prepw_k(PrepTab tab, __bf16* __restrict__ wbuf)
{
    int t = blockIdx.x * 256 + threadIdx.x;
    int w = t >> 11;
    if (w >= tab.n) return;
    int rr = t & 2047;
    int chunk = rr >> 6, l = rr & 63;
    int waveN = chunk >> 4, ks = (chunk >> 2) & 3, ni = chunk & 3;
    int c = waveN * 64 + ni * 16 + (l & 15);
    int kb = (ks * 4 + (l >> 4)) * 8;
    const float* s = tab.src[w] + (size_t)c * tab.stride[w] + kb;
    bf16x8 o;
    #pragma unroll
    for (int e = 0; e < 8; ++e) o[e] = (__bf16)s[e];
    *reinterpret_cast<bf16x8*>(wbuf + (size_t)w * 16384 + rr * 8) = o;
}

// ============================ CSR construction =============================
__global__ void hist14_k(const int* __restrict__ ps_u, const int* __restrict__ lr_u,
                         int* __restrict__ cnt)
{
    int t = blockIdx.x * 256 + threadIdx.x;
    const int total = 12 * EPS_N + 2 * ELR_N;
    if (t >= total) return;
    int k, u;
    if (t < 12 * EPS_N) { k = t / EPS_N; u = ps_u[t]; }
    else { int r = t - 12 * EPS_N; k = 12 + r / ELR_N; u = lr_u[r]; }
    atomicAdd(&cnt[k * NG + u], 1);
}

__global__ void fill14_k(const int* __restrict__ ps_u, const int* __restrict__ ps_v,
                         const int* __restrict__ lr_u, const int* __restrict__ lr_v,
                         int* __restrict__ head, int* __restrict__ col)
{
    int t = blockIdx.x * 256 + threadIdx.x;
    const int total = 12 * EPS_N + 2 * ELR_N;
    if (t >= total) return;
    int k, u, v;
    if (t < 12 * EPS_N) { k = t / EPS_N; u = ps_u[t]; v = ps_v[t]; }
    else { int r = t - 12 * EPS_N; k = 12 + r / ELR_N; u = lr_u[r]; v = lr_v[r]; }
    int pos = atomicAdd(&head[k * NG + u], 1);
    col[pos] = v;
}

__global__ void histE_k(const int* __restrict__ wi, int n, int* __restrict__ cnt)
{
    int t = blockIdx.x * 256 + threadIdx.x;
    if (t >= n) return;
    atomicAdd(&cnt[wi[t]], 1);
}

__global__ void fillE_k(const int* __restrict__ wi, int n,
                        int* __restrict__ head, int* __restrict__ col)
{
    int t = blockIdx.x * 256 + threadIdx.x;
    if (t >= n) return;
    int pos = atomicAdd(&head[wi[t]], 1);
    col[pos] = t;
}

__global__ void scan1_k(const int* __restrict__ in, int n, int* __restrict__ bsum)
{
    __shared__ int sm[4];
    int base = blockIdx.x * SCAN_CHUNK;
    int s = 0;
    for (int i = threadIdx.x; i < SCAN_CHUNK; i += 256) {
        int idx = base + i;
        s += (idx < n) ? in[idx] : 0;
    }
    #pragma unroll
    for (int off = 1; off < 64; off <<= 1) s += __shfl_xor(s, off);
    if ((threadIdx.x & 63) == 0) sm[threadIdx.x >> 6] = s;
    __syncthreads();
    if (threadIdx.x == 0) bsum[blockIdx.x] = sm[0] + sm[1] + sm[2] + sm[3];
}

__global__ void scan2_k(int* __restrict__ bsum, int nb)
{
    if (threadIdx.x == 0) {
        int acc = 0;
        for (int i = 0; i < nb; ++i) { int t = bsum[i]; bsum[i] = acc; acc += t; }
    }
}

__global__ void scan3_k(const int* __restrict__ in, int n,
                        const int* __restrict__ bsum, int* __restrict__ outp)
{
    __shared__ int sm[256];
    int base = blockIdx.x * SCAN_CHUNK;
    int loc[16]; int s = 0;
    #pragma unroll
    for (int i = 0; i < 16; ++i) {
        int idx = base + threadIdx.x * 16 + i;
        loc[i] = (idx < n) ? in[idx] : 0; s += loc[i];
    }
    sm[threadIdx.x] = s; __syncthreads();
    for (int off = 1; off < 256; off <<= 1) {
        int v = (threadIdx.x >= off) ? sm[threadIdx.x - off] : 0;
        __syncthreads();
        sm[threadIdx.x] += v;
        __syncthreads();
    }
    int tp = (threadIdx.x ? sm[threadIdx.x - 1] : 0) + bsum[blockIdx.x];
    #pragma unroll
    for (int i = 0; i < 16; ++i) {
        int idx = base + threadIdx.x * 16 + i;
        if (idx < n) outp[idx] = tp;
        tp += loc[i];
        if (idx == n - 1) outp[n] = tp;
    }
}

// ================= shared device helpers (2-wave BM=32 layout) =============
// wave = waveN in {0,1}; rows: mi*16 + r16 (mi in {0,1}); cols waveN*64+ni*16+r16
__device__ __forceinline__ void mfma_tile(f32x4 (&acc)[2][4], const __bf16* atile,
                                          const __bf16* __restrict__ gw,
                                          int waveN, int r16, int kq, int lane)
{
    const __bf16* gwb = gw + ((size_t)waveN << 13) + lane * 8;
    #pragma unroll
    for (int ks = 0; ks < 4; ++ks) {
        bf16x8 a[2], b[4];
        #pragma unroll
        for (int mi = 0; mi < 2; ++mi) {
            const int lr = mi * 16 + r16;
            a[mi] = *reinterpret_cast<const bf16x8*>(atile + lr * AST + ((ks << 2) + kq) * 8);
        }
        #pragma unroll
        for (int ni = 0; ni < 4; ++ni)
            b[ni] = *reinterpret_cast<const bf16x8*>(gwb + ((ks << 2) + ni) * 512);
        #pragma unroll
        for (int mi = 0; mi < 2; ++mi)
            #pragma unroll
            for (int ni = 0; ni < 4; ++ni)
                acc[mi][ni] = __builtin_amdgcn_mfma_f32_16x16x32_bf16(
                    a[mi], b[ni], acc[mi][ni], 0, 0, 0);
    }
}

__device__ __forceinline__ void gn_stats(const f32x4 (&acc)[2][4],
                                         float (*smS)[32], float (*smQ)[32],
                                         int waveN, int r16, int kq)
{
    #pragma unroll
    for (int mi = 0; mi < 2; ++mi) {
        #pragma unroll
        for (int reg = 0; reg < 4; ++reg) {
            float s = acc[mi][0][reg] + acc[mi][1][reg] + acc[mi][2][reg] + acc[mi][3][reg];
            float q = acc[mi][0][reg]*acc[mi][0][reg] + acc[mi][1][reg]*acc[mi][1][reg]
                    + acc[mi][2][reg]*acc[mi][2][reg] + acc[mi][3][reg]*acc[mi][3][reg];
            #pragma unroll
            for (int off = 1; off < 16; off <<= 1) {
                s += __shfl_xor(s, off);
                q += __shfl_xor(q, off);
            }
            if (r16 == 0) {
                int lr = mi * 16 + kq * 4 + reg;
                smS[waveN][lr] = s; smQ[waveN][lr] = q;
            }
        }
    }
}

// ============ edgefull: h[e] = relu(gn(ctx[hi]@c1A + dist@c1B, sb)) =========
template<typename CT>
__launch_bounds__(128, 3)
__global__ void edgefull_k(const int* __restrict__ hi_idx, const int* __restrict__ wi_idx,
                           const CT* __restrict__ ctxfeat,
                           const float* __restrict__ cpose, const float* __restrict__ tpose,
                           const float* __restrict__ rpw, const float* __restrict__ rpb,
                           const __bf16* __restrict__ wc1A, const __bf16* __restrict__ wc1B,
                           const float* __restrict__ sb,
                           __bf16* __restrict__ hout, int M)
{
    __shared__ __bf16 atile[32 * AST];
    __shared__ float rw[640];
    __shared__ float smS[2][32], smQ[2][32];
    const int tid = threadIdx.x, lane = tid & 63, waveN = tid >> 6;
    const int r16 = lane & 15, kq = lane >> 4;
    const int ublk = blockIdx.x * 32;

    for (int i = tid; i < 640; i += 128)
        rw[i] = (i < 512) ? rpw[i] : rpb[i - 512];

    float dl[2][4];
    #pragma unroll
    for (int mi = 0; mi < 2; ++mi) {
        int r = ublk + mi * 16 + r16;
        int e = r < M ? r : M - 1;
        int hi = hi_idx[e], wi = wi_idx[e];
        float4 cp = *reinterpret_cast<const float4*>(cpose + (size_t)hi * 4);
        float4 tp = *reinterpret_cast<const float4*>(tpose + (size_t)wi * 4);
        dl[mi][0] = cp.x - tp.x; dl[mi][1] = cp.y - tp.y;
        dl[mi][2] = cp.z - tp.z; dl[mi][3] = cp.w - tp.w;
    }

    {   // gather ctx rows -> atile (32 rows x 4 threads)
        const int glr = tid >> 2, q = tid & 3;
        const int e = (ublk + glr) < M ? (ublk + glr) : M - 1;
        const int cr = hi_idx[e];
        const CT* sp = ctxfeat + (size_t)cr * 128 + q * 32;
        #pragma unroll
        for (int i = 0; i < 4; ++i) {
            bf16x8 h;
            if constexpr (sizeof(CT) == 4) h = cvt8((const float*)sp + i * 8);
            else h = *reinterpret_cast<const bf16x8*>((const __bf16*)sp + i * 8);
            *reinterpret_cast<bf16x8*>(atile + glr * AST + (q * 4 + i) * 8) = h;
        }
    }
    __syncthreads();

    f32x4 acc[2][4];
    #pragma unroll
    for (int mi = 0; mi < 2; ++mi)
        #pragma unroll
        for (int ni = 0; ni < 4; ++ni)
            acc[mi][ni] = (f32x4){0.f, 0.f, 0.f, 0.f};

    mfma_tile(acc, atile, wc1A, waveN, r16, kq, lane);

    {   // dist matmul (A in-register, B frag-major global)
        const __bf16* gwb = wc1B + ((size_t)waveN << 13) + lane * 8;
        #pragma unroll
        for (int ks = 0; ks < 4; ++ks) {
            bf16x8 a[2], b[4];
            #pragma unroll
            for (int mi = 0; mi < 2; ++mi) {
                #pragma unroll
                for (int i = 0; i < 8; ++i) {
                    const int k = ks * 32 + kq * 8 + i;
                    float4 w4 = *reinterpret_cast<const float4*>(&rw[k * 4]);
                    float d = fmaf(dl[mi][0], w4.x, fmaf(dl[mi][1], w4.y,
                              fmaf(dl[mi][2], w4.z, fmaf(dl[mi][3], w4.w, rw[512 + k]))));
                    a[mi][i] = (__bf16)fmaxf(d, 0.f);
                }
            }
            #pragma unroll
            for (int ni = 0; ni < 4; ++ni)
                b[ni] = *reinterpret_cast<const bf16x8*>(gwb + ((ks << 2) + ni) * 512);
            #pragma unroll
            for (int mi = 0; mi < 2; ++mi)
                #pragma unroll
                for (int ni = 0; ni < 4; ++ni)
                    acc[mi][ni] = __builtin_amdgcn_mfma_f32_16x16x32_bf16(
                        a[mi], b[ni], acc[mi][ni], 0, 0, 0);
        }
    }

    gn_stats(acc, smS, smQ, waveN, r16, kq);
    __syncthreads();

    #pragma unroll
    for (int mi = 0; mi < 2; ++mi) {
        #pragma unroll
        for (int reg = 0; reg < 4; ++reg) {
            const int lr = mi * 16 + kq * 4 + reg;
            const float S = smS[0][lr] + smS[1][lr];
            const float Q = smQ[0][lr] + smQ[1][lr];
            const float m = S * (1.f / 128.f);
            const float inv = rsqrtf(fmaxf(Q * (1.f / 128.f) - m * m, 0.f) + GN_EPS_F);
            const int crow = ublk + lr;
            if (crow < M) {
                __bf16* dp = hout + (size_t)crow * 128 + waveN * 64 + r16;
                #pragma unroll
                for (int ni = 0; ni < 4; ++ni) {
                    const int colc = waveN * 64 + ni * 16 + r16;
                    float y = (acc[mi][ni][reg] - m) * inv * sb[colc] + sb[128 + colc];
                    dp[ni * 16] = (__bf16)fmaxf(y, 0.f);
                }
            }
        }
    }
}

// ======= fusedlayer: one global_graph fusion layer, double-buffered atile ===
struct FW { const __bf16* w[16]; };   // 0..11 ps, 12 left, 13 right, 14 ctr, 15 ctr2

__launch_bounds__(128, 3)
__global__ void fusedlayer_k(const __bf16* __restrict__ feat,
                             const int* __restrict__ rp, const int* __restrict__ col,
                             FW fw, const float* __restrict__ gn1,
                             const float* __restrict__ gn2,
                             __bf16* __restrict__ outp, int M)
{
    __shared__ __bf16 atile[2][32 * AST];
    __shared__ float smS[2][32], smQ[2][32];
    const int tid = threadIdx.x, lane = tid & 63, waveN = tid >> 6;
    const int r16 = lane & 15, kq = lane >> 4;
    const int ublk = blockIdx.x * 32;
    const int glr = tid >> 2, q = tid & 3;
    const int grow = ublk + glr;
    const bool gv = grow < M;
    const int grc = gv ? grow : 0;

    // prefetch all CSR extents + FIRST col per scale (independent loads)
    int begs[14], degs[14], c0[14];
    #pragma unroll
    for (int j = 0; j < 14; ++j) {
        int b = 0, e = 0;
        if (gv) { b = rp[j * M + grow]; e = rp[j * M + grow + 1]; }
        begs[j] = b; degs[j] = e - b;
    }
    #pragma unroll
    for (int j = 0; j < 14; ++j)
        c0[j] = (degs[j] > 0) ? col[begs[j]] : 0;

    float ss[32];
    auto GATHER = [&](int jj) {
        #pragma unroll
        for (int i = 0; i < 32; ++i) ss[i] = 0.f;
        if (jj == 14) {
            const __bf16* sp = feat + (size_t)grc * 128 + q * 32;
            #pragma unroll
            for (int i = 0; i < 4; ++i) {
                bf16x8 h = *reinterpret_cast<const bf16x8*>(sp + i * 8);
                #pragma unroll
                for (int e = 0; e < 8; ++e) ss[i * 8 + e] = (float)h[e];
            }
        } else {
            const int d = degs[jj];
            if (d > 0) {
                const __bf16* sp = feat + (size_t)c0[jj] * 128 + q * 32;
                #pragma unroll
                for (int i = 0; i < 4; ++i) {
                    bf16x8 h = *reinterpret_cast<const bf16x8*>(sp + i * 8);
                    #pragma unroll
                    for (int e2 = 0; e2 < 8; ++e2) ss[i * 8 + e2] += (float)h[e2];
                }
            }
            for (int t2 = begs[jj] + 1; t2 < begs[jj] + d; ++t2) {   // rare tail
                const __bf16* sp = feat + (size_t)col[t2] * 128 + q * 32;
                #pragma unroll
                for (int i = 0; i < 4; ++i) {
                    bf16x8 h = *reinterpret_cast<const bf16x8*>(sp + i * 8);
                    #pragma unroll
                    for (int e2 = 0; e2 < 8; ++e2) ss[i * 8 + e2] += (float)h[e2];
                }
            }
        }
    };

    f32x4 acc[2][4];
    #pragma unroll
    for (int mi = 0; mi < 2; ++mi)
        #pragma unroll
        for (int ni = 0; ni < 4; ++ni)
            acc[mi][ni] = (f32x4){0.f, 0.f, 0.f, 0.f};

    GATHER(0);
    #pragma unroll
    for (int j = 0; j < 15; ++j) {
        __bf16* at = atile[j & 1];
        #pragma unroll
        for (int i = 0; i < 4; ++i) {
            bf16x8 o;
            #pragma unroll
            for (int e = 0; e < 8; ++e) o[e] = (__bf16)ss[i * 8 + e];
            *reinterpret_cast<bf16x8*>(at + glr * AST + (q * 4 + i) * 8) = o;
        }
        __syncthreads();
        if (j < 14) GATHER(j + 1);           // next gather overlaps this MFMA
        mfma_tile(acc, at, fw.w[j], waveN, r16, kq, lane);
    }

    // GN1 + relu -> atile[1]; mfma ctr2
    gn_stats(acc, smS, smQ, waveN, r16, kq);
    __syncthreads();
    {
        __bf16* at = atile[1];
        #pragma unroll
        for (int mi = 0; mi < 2; ++mi) {
            #pragma unroll
            for (int reg = 0; reg < 4; ++reg) {
                const int lr = mi * 16 + kq * 4 + reg;
                const float S = smS[0][lr] + smS[1][lr];
                const float Q = smQ[0][lr] + smQ[1][lr];
                const float m = S * (1.f / 128.f);
                const float inv = rsqrtf(fmaxf(Q * (1.f / 128.f) - m * m, 0.f) + GN_EPS_F);
                #pragma unroll
                for (int ni = 0; ni < 4; ++ni) {
                    const int colc = waveN * 64 + ni * 16 + r16;
                    float y = (acc[mi][ni][reg] - m) * inv * gn1[colc] + gn1[128 + colc];
                    at[lr * AST + colc] = (__bf16)fmaxf(y, 0.f);
                }
            }
        }
    }
    __syncthreads();

    f32x4 acc2[2][4];
    #pragma unroll
    for (int mi = 0; mi < 2; ++mi)
        #pragma unroll
        for (int ni = 0; ni < 4; ++ni)
            acc2[mi][ni] = (f32x4){0.f, 0.f, 0.f, 0.f};
    mfma_tile(acc2, atile[1], fw.w[15], waveN, r16, kq, lane);

    gn_stats(acc2, smS, smQ, waveN, r16, kq);
    __syncthreads();
    #pragma unroll
    for (int mi = 0; mi < 2; ++mi) {
        #pragma unroll
        for (int reg = 0; reg < 4; ++reg) {
            const int lr = mi * 16 + kq * 4 + reg;
            const float S = smS[0][lr] + smS[1][lr];
            const float Q = smQ[0][lr] + smQ[1][lr];
            const float m = S * (1.f / 128.f);
            const float inv = rsqrtf(fmaxf(Q * (1.f / 128.f) - m * m, 0.f) + GN_EPS_F);
            const int crow = ublk + lr;
            if (crow < M) {
                __bf16* dp = outp + (size_t)crow * 128 + waveN * 64 + r16;
                const __bf16* rs = feat + (size_t)crow * 128 + waveN * 64 + r16;
                #pragma unroll
                for (int ni = 0; ni < 4; ++ni) {
                    const int colc = waveN * 64 + ni * 16 + r16;
                    float y = (acc2[mi][ni][reg] - m) * inv * gn2[colc] + gn2[128 + colc];
                    y += (float)rs[ni * 16];
                    dp[ni * 16] = (__bf16)fmaxf(y, 0.f);
                }
            }
        }
    }
}

// ============= lptail: lane_pooling tail (chained GEMMs + GNs) ==============
template<bool LP2>
__launch_bounds__(128, 3)
__global__ void lptail_k(const __bf16* __restrict__ hsrc,
                         const int* __restrict__ rp, const int* __restrict__ col,
                         const float* __restrict__ roi,
                         const __bf16* __restrict__ wc2, const __bf16* __restrict__ winW,
                         const __bf16* __restrict__ wm1, const __bf16* __restrict__ wm2,
                         const float* __restrict__ ngn, const float* __restrict__ m1gn,
                         const float* __restrict__ m2gn,
                         void* __restrict__ outp, int M)
{
    __shared__ __bf16 atile[32 * AST];
    __shared__ float smS[2][32], smQ[2][32];
    const int tid = threadIdx.x, lane = tid & 63, waveN = tid >> 6;
    const int r16 = lane & 15, kq = lane >> 4;
    const int ublk = blockIdx.x * 32;
    const int glr = tid >> 2, q = tid & 3;
    const int grow = ublk + glr;
    const bool gv = grow < M;

    {   // gather Σh -> atile
        float ss[32];
        #pragma unroll
        for (int i = 0; i < 32; ++i) ss[i] = 0.f;
        if (gv) {
            const int b = rp[grow], e = rp[grow + 1];
            for (int jj = b; jj < e; ++jj) {
                const __bf16* sp = hsrc + (size_t)col[jj] * 128 + q * 32;
                #pragma unroll
                for (int i = 0; i < 4; ++i) {
                    bf16x8 h = *reinterpret_cast<const bf16x8*>(sp + i * 8);
                    #pragma unroll
                    for (int e2 = 0; e2 < 8; ++e2) ss[i * 8 + e2] += (float)h[e2];
                }
            }
        }
        #pragma unroll
        for (int i = 0; i < 4; ++i) {
            bf16x8 o;
            #pragma unroll
            for (int e2 = 0; e2 < 8; ++e2) o[e2] = (__bf16)ss[i * 8 + e2];
            *reinterpret_cast<bf16x8*>(atile + glr * AST + (q * 4 + i) * 8) = o;
        }
    }
    __syncthreads();

    f32x4 acc[2][4];
    #pragma unroll
    for (int mi = 0; mi < 2; ++mi)
        #pragma unroll
        for (int ni = 0; ni < 4; ++ni)
            acc[mi][ni] = (f32x4){0.f, 0.f, 0.f, 0.f};
    mfma_tile(acc, atile, wc2, waveN, r16, kq, lane);

    if (LP2) {   // + roi @ input_w
        __syncthreads();
        {
            const float* sp = roi + (size_t)(gv ? grow : 0) * 128 + q * 32;
            #pragma unroll
            for (int i = 0; i < 4; ++i)
                *reinterpret_cast<bf16x8*>(atile + glr * AST + (q * 4 + i) * 8) =
                    cvt8(sp + i * 8);
        }
        __syncthreads();
        mfma_tile(acc, atile, winW, waveN, r16, kq, lane);
    }

    auto CHAIN = [&](const float* SBP, const __bf16* WNEXT) {
        gn_stats(acc, smS, smQ, waveN, r16, kq);
        __syncthreads();
        #pragma unroll
        for (int mi = 0; mi < 2; ++mi) {
            #pragma unroll
            for (int reg = 0; reg < 4; ++reg) {
                const int lr = mi * 16 + kq * 4 + reg;
                const float S = smS[0][lr] + smS[1][lr];
                const float Q = smQ[0][lr] + smQ[1][lr];
                const float m = S * (1.f / 128.f);
                const float inv = rsqrtf(fmaxf(Q * (1.f / 128.f) - m * m, 0.f) + GN_EPS_F);
                #pragma unroll
                for (int ni = 0; ni < 4; ++ni) {
                    const int colc = waveN * 64 + ni * 16 + r16;
                    float y = (acc[mi][ni][reg] - m) * inv * SBP[colc] + SBP[128 + colc];
                    atile[lr * AST + colc] = (__bf16)fmaxf(y, 0.f);
                }
            }
        }
        __syncthreads();
        #pragma unroll
        for (int mi = 0; mi < 2; ++mi)
            #pragma unroll
            for (int ni = 0; ni < 4; ++ni)
                acc[mi][ni] = (f32x4){0.f, 0.f, 0.f, 0.f};
        mfma_tile(acc, atile, WNEXT, waveN, r16, kq, lane);
    };
    CHAIN(ngn, wm1);
    CHAIN(m1gn, wm2);

    gn_stats(acc, smS, smQ, waveN, r16, kq);
    __syncthreads();
    #pragma unroll
    for (int mi = 0; mi < 2; ++mi) {
        #pragma unroll
        for (int reg = 0; reg < 4; ++reg) {
            const int lr = mi * 16 + kq * 4 + reg;
            const float S = smS[0][lr] + smS[1][lr];
            const float Q = smQ[0][lr] + smQ[1][lr];
            const float m = S * (1.f / 128.f);
            const float inv = rsqrtf(fmaxf(Q * (1.f / 128.f) - m * m, 0.f) + GN_EPS_F);
            const int crow = ublk + lr;
            if (crow < M) {
                #pragma unroll
                for (int ni = 0; ni < 4; ++ni) {
                    const int colc = waveN * 64 + ni * 16 + r16;
                    float y = (acc[mi][ni][reg] - m) * inv * m2gn[colc] + m2gn[128 + colc];
                    if (LP2) {
                        y += roi[(size_t)crow * 128 + colc];
                        ((float*)outp)[(size_t)crow * 128 + colc] = fmaxf(y, 0.f);
                    } else {
                        ((__bf16*)outp)[(size_t)crow * 128 + colc] = (__bf16)fmaxf(y, 0.f);
                    }
                }
            }
        }
    }
}

// ===========================================================================
extern "C" void kernel_launch(void* const* d_in, const int* in_sizes, int n_in,
                              void* d_out, int out_size, void* d_ws, size_t ws_size,
                              hipStream_t stream)
{
    const float* roi_feat   = (const float*)d_in[0];
    const float* graph_pose = (const float*)d_in[1];
    const float* roi_pose   = (const float*)d_in[2];
    const float* lp_input_w = (const float*)d_in[3];
    const float* lp_rpw     = (const float*)d_in[4];
    const float* lp_rpb     = (const float*)d_in[5];
    const float* lp_c1w     = (const float*)d_in[6];
    const float* lp_c1gn    = (const float*)d_in[7];
    const float* lp_c2w     = (const float*)d_in[8];
    const float* lp_m1w     = (const float*)d_in[9];
    const float* lp_m1gn    = (const float*)d_in[10];
    const float* lp_m2w     = (const float*)d_in[11];
    const float* lp_m2gn    = (const float*)d_in[12];
    const float* lp_ngn     = (const float*)d_in[13];
    const float* f_ctrw     = (const float*)d_in[14];
    const float* f_psw      = (const float*)d_in[15];
    const float* f_lw       = (const float*)d_in[16];
    const float* f_rw       = (const float*)d_in[17];
    const float* f_ngn      = (const float*)d_in[18];
    const float* f_c2w      = (const float*)d_in[19];
    const float* f_c2gn     = (const float*)d_in[20];
    const int* e1_hi = (const int*)d_in[21];
    const int* e1_wi = (const int*)d_in[22];
    const int* e2_hi = (const int*)d_in[23];
    const int* e2_wi = (const int*)d_in[24];
    const int* ps_u  = (const int*)d_in[25];
    const int* ps_v  = (const int*)d_in[26];
    const int* lr_u  = (const int*)d_in[27];
    const int* lr_v  = (const int*)d_in[28];
    float* out = (float*)d_out;

    // ---- workspace (~77 MB) ----
    __bf16* gA   = (__bf16*)d_ws;                       // NG*128
    __bf16* gB   = gA + (size_t)NG * 128;               // NG*128
    __bf16* hbuf = gB + (size_t)NG * 128;               // E1_N*128
    __bf16* wbuf = hbuf + (size_t)E1_N * 128;           // 80*16384
    int* ip      = (int*)(wbuf + (size_t)80 * 16384);
    int* cnt14   = ip;             ip += 14 * NG;
    int* rp14    = ip;             ip += 14 * NG + 1;
    int* col14   = ip;             ip += 12 * EPS_N + 2 * ELR_N;
    int* cntE1   = ip;             ip += NG;
    int* rpE1    = ip;             ip += NG + 1;
    int* colE1   = ip;             ip += E1_N;
    int* cntE2   = ip;             ip += NR;
    int* rpE2    = ip;             ip += NR + 1;
    int* colE2   = ip;             ip += E2_N;
    int* bsum    = ip;             ip += 256;

    dim3 blk(256), blk128(128);
    const dim3 gNG32((NG + 31) / 32), gNR32((NR + 31) / 32), gE32((E1_N + 31) / 32);
    const int NE14 = 12 * EPS_N + 2 * ELR_N;
    const dim3 gH14((NE14 + 255) / 256);

    // ---------------- weight prep ----------------
    PrepTab tab; int nw = 0;
    auto addw = [&](const float* p, int s) { tab.src[nw] = p; tab.stride[nw] = s; ++nw; };
    addw(lp_c1w, 256);                 // 0 c1A_0
    addw(lp_c1w + 128, 256);           // 1 c1B_0
    addw(lp_c1w + 32768, 256);         // 2 c1A_1
    addw(lp_c1w + 32768 + 128, 256);   // 3 c1B_1
    addw(lp_input_w + 16384, 128);     // 4 input_w[1]
    addw(lp_c2w, 128); addw(lp_c2w + 16384, 128);   // 5,6
    addw(lp_m1w, 128); addw(lp_m1w + 16384, 128);   // 7,8
    addw(lp_m2w, 128); addw(lp_m2w + 16384, 128);   // 9,10
    for (int i = 0; i < 4; ++i) addw(f_ctrw + (size_t)i * 16384, 128);      // 11..14
    for (int i = 0; i < 4; ++i)
        for (int k = 0; k < 12; ++k) addw(f_psw + ((size_t)i * 12 + k) * 16384, 128);
    for (int i = 0; i < 4; ++i) addw(f_lw + (size_t)i * 16384, 128);        // 63..66
    for (int i = 0; i < 4; ++i) addw(f_rw + (size_t)i * 16384, 128);        // 67..70
    for (int i = 0; i < 4; ++i) addw(f_c2w + (size_t)i * 16384, 128);       // 71..74
    tab.n = nw;
    auto wb = [&](int idx) { return (const __bf16*)(wbuf + (size_t)idx * 16384); };
    prepw_k<<<dim3((nw * 2048 + 255) / 256), blk, 0, stream>>>(tab, wbuf);

    // ---------------- CSR builds ----------------
    hipMemsetAsync(cnt14, 0, (size_t)14 * NG * 4, stream);
    hist14_k<<<gH14, blk, 0, stream>>>(ps_u, lr_u, cnt14);
    {
        int n = 14 * NG, nb = (n + SCAN_CHUNK - 1) / SCAN_CHUNK;
        scan1_k<<<nb, blk, 0, stream>>>(cnt14, n, bsum);
        scan2_k<<<1, blk, 0, stream>>>(bsum, nb);
        scan3_k<<<nb, blk, 0, stream>>>(cnt14, n, bsum, rp14);
    }
    hipMemcpyAsync(cnt14, rp14, (size_t)14 * NG * 4, hipMemcpyDeviceToDevice, stream);
    fill14_k<<<gH14, blk, 0, stream>>>(ps_u, ps_v, lr_u, lr_v, cnt14, col14);

    hipMemsetAsync(cntE1, 0, (size_t)NG * 4, stream);
    histE_k<<<(E1_N + 255) / 256, blk, 0, stream>>>(e1_wi, E1_N, cntE1);
    {
        int n = NG, nb = (n + SCAN_CHUNK - 1) / SCAN_CHUNK;
        scan1_k<<<nb, blk, 0, stream>>>(cntE1, n, bsum);
        scan2_k<<<1, blk, 0, stream>>>(bsum, nb);
        scan3_k<<<nb, blk, 0, stream>>>(cntE1, n, bsum, rpE1);
    }
    hipMemcpyAsync(cntE1, rpE1, (size_t)NG * 4, hipMemcpyDeviceToDevice, stream);
    fillE_k<<<(E1_N + 255) / 256, blk, 0, stream>>>(e1_wi, E1_N, cntE1, colE1);

    hipMemsetAsync(cntE2, 0, (size_t)NR * 4, stream);
    histE_k<<<(E2_N + 255) / 256, blk, 0, stream>>>(e2_wi, E2_N, cntE2);
    {
        int n = NR, nb = (n + SCAN_CHUNK - 1) / SCAN_CHUNK;
        scan1_k<<<nb, blk, 0, stream>>>(cntE2, n, bsum);
        scan2_k<<<1, blk, 0, stream>>>(bsum, nb);
        scan3_k<<<nb, blk, 0, stream>>>(cntE2, n, bsum, rpE2);
    }
    hipMemcpyAsync(cntE2, rpE2, (size_t)NR * 4, hipMemcpyDeviceToDevice, stream);
    fillE_k<<<(E2_N + 255) / 256, blk, 0, stream>>>(e2_wi, E2_N, cntE2, colE2);

    // ---------------- lane_pooling #1 (roi -> graph) ----------------
    edgefull_k<float><<<gE32, blk128, 0, stream>>>(
        e1_hi, e1_wi, roi_feat, roi_pose, graph_pose, lp_rpw, lp_rpb,
        wb(0), wb(1), lp_c1gn, hbuf, E1_N);
    lptail_k<false><<<gNG32, blk128, 0, stream>>>(
        hbuf, rpE1, colE1, nullptr, wb(5), nullptr, wb(7), wb(9),
        lp_ngn, lp_m1gn, lp_m2gn, gA, NG);

    // ---------------- global_graph: 4 fused layers ----------------
    for (int i = 0; i < 4; ++i) {
        FW fw;
        for (int k = 0; k < 12; ++k) fw.w[k] = wb(15 + i * 12 + k);
        fw.w[12] = wb(63 + i); fw.w[13] = wb(67 + i);
        fw.w[14] = wb(11 + i); fw.w[15] = wb(71 + i);
        const __bf16* src = (i & 1) ? gB : gA;
        __bf16* dst = (i & 1) ? gA : gB;
        fusedlayer_k<<<gNG32, blk128, 0, stream>>>(
            src, rp14, col14, fw, f_ngn + (size_t)i * 256,
            f_c2gn + (size_t)i * 256, dst, NG);
    }
    // after i=3: result in gA

    // ---------------- lane_pooling #2 (graph -> roi) ----------------
    edgefull_k<__bf16><<<gE32, blk128, 0, stream>>>(
        e2_hi, e2_wi, gA, graph_pose, roi_pose, lp_rpw + 512, lp_rpb + 128,
        wb(2), wb(3), lp_c1gn + 256, hbuf, E2_N);
    lptail_k<true><<<gNR32, blk128, 0, stream>>>(
        hbuf, rpE2, colE2, roi_feat, wb(6), wb(4), wb(8), wb(10),
        lp_ngn + 256, lp_m1gn + 256, lp_m2gn + 256, out, NR);
}

// Round 9
// 697.286 us; speedup vs baseline: 3.4098x; 1.0972x over previous
//
#include <hip/hip_runtime.h>

#define NG 50000
#define NR 12000
#define EPS_N 50000
#define ELR_N 5000
#define E1_N 150000
#define E2_N 150000
#define GN_EPS_F 1e-5f
#define SCAN_CHUNK 4096
#define WST 136   // wave-LDS transpose tile row stride (bf16 elems)

typedef __attribute__((ext_vector_type(8))) __bf16 bf16x8;
typedef __attribute__((ext_vector_type(4))) float f32x4;

__device__ __forceinline__ bf16x8 cvt8(const float* __restrict__ p) {
    float4 x0 = *reinterpret_cast<const float4*>(p);
    float4 x1 = *reinterpret_cast<const float4*>(p + 4);
    bf16x8 a;
    a[0] = (__bf16)x0.x; a[1] = (__bf16)x0.y; a[2] = (__bf16)x0.z; a[3] = (__bf16)x0.w;
    a[4] = (__bf16)x1.x; a[5] = (__bf16)x1.y; a[6] = (__bf16)x1.z; a[7] = (__bf16)x1.w;
    return a;
}

// ====== weight prep: f32 -> fragment-major bf16 (global, coalesced reads) ===
// chunk = wn*16 + ks*4 + ni (wn 0..1); lane l owns W[wn*64+ni*16+(l&15)][(ks*4+(l>>4))*8..+8]
struct PrepTab { const float* src[80]; int stride[80]; int n; };

__global__ void prepw_k(PrepTab tab, __bf16* __restrict__ wbuf)
{
    int t = blockIdx.x * 256 + threadIdx.x;
    int w = t >> 11;
    if (w >= tab.n) return;
    int rr = t & 2047;
    int chunk = rr >> 6, l = rr & 63;
    int wn = chunk >> 4, ks = (chunk >> 2) & 3, ni = chunk & 3;
    int c = wn * 64 + ni * 16 + (l & 15);
    int kb = (ks * 4 + (l >> 4)) * 8;
    const float* s = tab.src[w] + (size_t)c * tab.stride[w] + kb;
    bf16x8 o;
    #pragma unroll
    for (int e = 0; e < 8; ++e) o[e] = (__bf16)s[e];
    *reinterpret_cast<bf16x8*>(wbuf + (size_t)w * 16384 + rr * 8) = o;
}

// ============================ CSR construction =============================
__global__ void hist14_k(const int* __restrict__ ps_u, const int* __restrict__ lr_u,
                         int* __restrict__ cnt)
{
    int t = blockIdx.x * 256 + threadIdx.x;
    const int total = 12 * EPS_N + 2 * ELR_N;
    if (t >= total) return;
    int k, u;
    if (t < 12 * EPS_N) { k = t / EPS_N; u = ps_u[t]; }
    else { int r = t - 12 * EPS_N; k = 12 + r / ELR_N; u = lr_u[r]; }
    atomicAdd(&cnt[k * NG + u], 1);
}

__global__ void fill14_k(const int* __restrict__ ps_u, const int* __restrict__ ps_v,
                         const int* __restrict__ lr_u, const int* __restrict__ lr_v,
                         int* __restrict__ head, int* __restrict__ col)
{
    int t = blockIdx.x * 256 + threadIdx.x;
    const int total = 12 * EPS_N + 2 * ELR_N;
    if (t >= total) return;
    int k, u, v;
    if (t < 12 * EPS_N) { k = t / EPS_N; u = ps_u[t]; v = ps_v[t]; }
    else { int r = t - 12 * EPS_N; k = 12 + r / ELR_N; u = lr_u[r]; v = lr_v[r]; }
    int pos = atomicAdd(&head[k * NG + u], 1);
    col[pos] = v;
}

__global__ void histE_k(const int* __restrict__ wi, int n, int* __restrict__ cnt)
{
    int t = blockIdx.x * 256 + threadIdx.x;
    if (t >= n) return;
    atomicAdd(&cnt[wi[t]], 1);
}

__global__ void fillE_k(const int* __restrict__ wi, int n,
                        int* __restrict__ head, int* __restrict__ col)
{
    int t = blockIdx.x * 256 + threadIdx.x;
    if (t >= n) return;
    int pos = atomicAdd(&head[wi[t]], 1);
    col[pos] = t;
}

__global__ void scan1_k(const int* __restrict__ in, int n, int* __restrict__ bsum)
{
    __shared__ int sm[4];
    int base = blockIdx.x * SCAN_CHUNK;
    int s = 0;
    for (int i = threadIdx.x; i < SCAN_CHUNK; i += 256) {
        int idx = base + i;
        s += (idx < n) ? in[idx] : 0;
    }
    #pragma unroll
    for (int off = 1; off < 64; off <<= 1) s += __shfl_xor(s, off);
    if ((threadIdx.x & 63) == 0) sm[threadIdx.x >> 6] = s;
    __syncthreads();
    if (threadIdx.x == 0) bsum[blockIdx.x] = sm[0] + sm[1] + sm[2] + sm[3];
}

__global__ void scan2_k(int* __restrict__ bsum, int nb)
{
    if (threadIdx.x == 0) {
        int acc = 0;
        for (int i = 0; i < nb; ++i) { int t = bsum[i]; bsum[i] = acc; acc += t; }
    }
}

__global__ void scan3_k(const int* __restrict__ in, int n,
                        const int* __restrict__ bsum, int* __restrict__ outp)
{
    __shared__ int sm[256];
    int base = blockIdx.x * SCAN_CHUNK;
    int loc[16]; int s = 0;
    #pragma unroll
    for (int i = 0; i < 16; ++i) {
        int idx = base + threadIdx.x * 16 + i;
        loc[i] = (idx < n) ? in[idx] : 0; s += loc[i];
    }
    sm[threadIdx.x] = s; __syncthreads();
    for (int off = 1; off < 256; off <<= 1) {
        int v = (threadIdx.x >= off) ? sm[threadIdx.x - off] : 0;
        __syncthreads();
        sm[threadIdx.x] += v;
        __syncthreads();
    }
    int tp = (threadIdx.x ? sm[threadIdx.x - 1] : 0) + bsum[blockIdx.x];
    #pragma unroll
    for (int i = 0; i < 16; ++i) {
        int idx = base + threadIdx.x * 16 + i;
        if (idx < n) outp[idx] = tp;
        tp += loc[i];
        if (idx == n - 1) outp[n] = tp;
    }
}

// ================ wave-autonomous GEMM helpers (BM=16 per wave) =============
// thread (r16 = lane&15, kq = lane>>4) owns row wbase+r16; A-frag k = ks*32+kq*8.
// acc[n2] covers cols n2*16+r16, output rows kq*4+reg.

__device__ __forceinline__ void mfma16(f32x4 (&acc)[8], const bf16x8 (&a)[4],
                                       const __bf16* __restrict__ gw, int lane)
{
    const __bf16* gwb = gw + lane * 8;
    #pragma unroll
    for (int ks = 0; ks < 4; ++ks) {
        #pragma unroll
        for (int n2 = 0; n2 < 8; ++n2) {
            const int chunk = (n2 >> 2) * 16 + ks * 4 + (n2 & 3);
            bf16x8 b = *reinterpret_cast<const bf16x8*>(gwb + chunk * 512);
            acc[n2] = __builtin_amdgcn_mfma_f32_16x16x32_bf16(a[ks], b, acc[n2], 0, 0, 0);
        }
    }
}

__device__ __forceinline__ void ss_to_frags(const float (&ss)[32], bf16x8 (&a)[4])
{
    #pragma unroll
    for (int ks = 0; ks < 4; ++ks)
        #pragma unroll
        for (int i = 0; i < 8; ++i)
            a[ks][i] = (__bf16)ss[ks * 8 + i];
}

// GN stats for the 4 rows (kq*4+reg) this lane participates in; wave-local.
__device__ __forceinline__ void gn_mi(const f32x4 (&acc)[8], float (&m)[4], float (&inv)[4])
{
    #pragma unroll
    for (int reg = 0; reg < 4; ++reg) {
        float s = 0.f, q = 0.f;
        #pragma unroll
        for (int n2 = 0; n2 < 8; ++n2) { float v = acc[n2][reg]; s += v; q = fmaf(v, v, q); }
        #pragma unroll
        for (int off = 1; off < 16; off <<= 1) {
            s += __shfl_xor(s, off);
            q += __shfl_xor(q, off);
        }
        m[reg] = s * (1.f / 128.f);
        inv[reg] = rsqrtf(fmaxf(q * (1.f / 128.f) - m[reg] * m[reg], 0.f) + GN_EPS_F);
    }
}

// GN+relu -> wave LDS tile (C-layout write) -> read back own row's A-frags.
// Intra-wave ds_write->ds_read; no barrier needed.
__device__ __forceinline__ void gn_relayout(const f32x4 (&acc)[8], const float* __restrict__ sb,
                                            __bf16* wl, bf16x8 (&a)[4], int r16, int kq)
{
    float m[4], inv[4];
    gn_mi(acc, m, inv);
    #pragma unroll
    for (int reg = 0; reg < 4; ++reg) {
        #pragma unroll
        for (int n2 = 0; n2 < 8; ++n2) {
            const int colc = n2 * 16 + r16;
            float y = (acc[n2][reg] - m[reg]) * inv[reg] * sb[colc] + sb[128 + colc];
            wl[(kq * 4 + reg) * WST + colc] = (__bf16)fmaxf(y, 0.f);
        }
    }
    #pragma unroll
    for (int ks = 0; ks < 4; ++ks)
        a[ks] = *reinterpret_cast<const bf16x8*>(wl + r16 * WST + ks * 32 + kq * 8);
}

// ============ edgefull: h[e] = relu(gn(ctx[hi]@c1A + dist@c1B, sb)) =========
template<typename CT>
__launch_bounds__(128, 3)
__global__ void edgefull_k(const int* __restrict__ hi_idx, const int* __restrict__ wi_idx,
                           const CT* __restrict__ ctxfeat,
                           const float* __restrict__ cpose, const float* __restrict__ tpose,
                           const float* __restrict__ rpw, const float* __restrict__ rpb,
                           const __bf16* __restrict__ wc1A, const __bf16* __restrict__ wc1B,
                           const float* __restrict__ sb,
                           __bf16* __restrict__ hout, int M)
{
    __shared__ float rw[640];
    const int tid = threadIdx.x, lane = tid & 63, wv = tid >> 6;
    const int r16 = lane & 15, kq = lane >> 4;
    const int wbase = blockIdx.x * 32 + wv * 16;
    const int erow = wbase + r16;
    const int ec = erow < M ? erow : M - 1;

    for (int i = tid; i < 640; i += 128)
        rw[i] = (i < 512) ? rpw[i] : rpb[i - 512];
    __syncthreads();

    const int hi = hi_idx[ec], wi = wi_idx[ec];
    float4 cp = *reinterpret_cast<const float4*>(cpose + (size_t)hi * 4);
    float4 tp = *reinterpret_cast<const float4*>(tpose + (size_t)wi * 4);
    const float d0 = cp.x - tp.x, d1 = cp.y - tp.y, d2 = cp.z - tp.z, d3 = cp.w - tp.w;

    f32x4 acc[8];
    #pragma unroll
    for (int n2 = 0; n2 < 8; ++n2) acc[n2] = (f32x4){0.f, 0.f, 0.f, 0.f};

    {   // ctx[hi] @ c1A
        bf16x8 a[4];
        const CT* sp = ctxfeat + (size_t)hi * 128 + kq * 8;
        #pragma unroll
        for (int ks = 0; ks < 4; ++ks) {
            if constexpr (sizeof(CT) == 4) a[ks] = cvt8((const float*)sp + ks * 32);
            else a[ks] = *reinterpret_cast<const bf16x8*>((const __bf16*)sp + ks * 32);
        }
        mfma16(acc, a, wc1A, lane);
    }
    {   // dist @ c1B (A built in-register)
        bf16x8 a[4];
        #pragma unroll
        for (int ks = 0; ks < 4; ++ks)
            #pragma unroll
            for (int i = 0; i < 8; ++i) {
                const int k = ks * 32 + kq * 8 + i;
                float4 w4 = *reinterpret_cast<const float4*>(&rw[k * 4]);
                float d = fmaf(d0, w4.x, fmaf(d1, w4.y, fmaf(d2, w4.z,
                          fmaf(d3, w4.w, rw[512 + k]))));
                a[ks][i] = (__bf16)fmaxf(d, 0.f);
            }
        mfma16(acc, a, wc1B, lane);
    }

    float m[4], inv[4];
    gn_mi(acc, m, inv);
    #pragma unroll
    for (int reg = 0; reg < 4; ++reg) {
        const int crow = wbase + kq * 4 + reg;
        if (crow < M) {
            __bf16* dp = hout + (size_t)crow * 128 + r16;
            #pragma unroll
            for (int n2 = 0; n2 < 8; ++n2) {
                const int colc = n2 * 16 + r16;
                float y = (acc[n2][reg] - m[reg]) * inv[reg] * sb[colc] + sb[128 + colc];
                dp[n2 * 16] = (__bf16)fmaxf(y, 0.f);
            }
        }
    }
}

// ======= fusedlayer: one global_graph fusion layer, barrier-free waves ======
struct FW { const __bf16* w[16]; };   // 0..11 ps, 12 left, 13 right, 14 ctr, 15 ctr2

__launch_bounds__(128, 3)
__global__ void fusedlayer_k(const __bf16* __restrict__ feat,
                             const int* __restrict__ rp, const int* __restrict__ col,
                             FW fw, const float* __restrict__ gn1,
                             const float* __restrict__ gn2,
                             __bf16* __restrict__ outp, int M)
{
    __shared__ __bf16 wl[2][16 * WST];
    const int tid = threadIdx.x, lane = tid & 63, wv = tid >> 6;
    const int r16 = lane & 15, kq = lane >> 4;
    const int wbase = blockIdx.x * 32 + wv * 16;
    const int wrow = (wbase + r16) < M ? (wbase + r16) : M - 1;

    f32x4 acc[8];
    #pragma unroll
    for (int n2 = 0; n2 < 8; ++n2) acc[n2] = (f32x4){0.f, 0.f, 0.f, 0.f};

    #pragma unroll
    for (int j = 0; j < 15; ++j) {
        float ss[32];
        #pragma unroll
        for (int i = 0; i < 32; ++i) ss[i] = 0.f;
        if (j == 14) {
            const __bf16* sp = feat + (size_t)wrow * 128 + kq * 8;
            #pragma unroll
            for (int ks = 0; ks < 4; ++ks) {
                bf16x8 h = *reinterpret_cast<const bf16x8*>(sp + ks * 32);
                #pragma unroll
                for (int i = 0; i < 8; ++i) ss[ks * 8 + i] = (float)h[i];
            }
        } else {
            const int b = rp[j * M + wrow], e = rp[j * M + wrow + 1];
            for (int t2 = b; t2 < e; ++t2) {
                const __bf16* sp = feat + (size_t)col[t2] * 128 + kq * 8;
                #pragma unroll
                for (int ks = 0; ks < 4; ++ks) {
                    bf16x8 h = *reinterpret_cast<const bf16x8*>(sp + ks * 32);
                    #pragma unroll
                    for (int i = 0; i < 8; ++i) ss[ks * 8 + i] += (float)h[i];
                }
            }
        }
        bf16x8 a[4];
        ss_to_frags(ss, a);
        mfma16(acc, a, fw.w[j], lane);
    }

    // GN1 + relu -> wave LDS -> A-frags; ctr2 GEMM
    bf16x8 a2[4];
    gn_relayout(acc, gn1, wl[wv], a2, r16, kq);
    f32x4 acc2[8];
    #pragma unroll
    for (int n2 = 0; n2 < 8; ++n2) acc2[n2] = (f32x4){0.f, 0.f, 0.f, 0.f};
    mfma16(acc2, a2, fw.w[15], lane);

    // GN2 + residual + relu -> out
    float m[4], inv[4];
    gn_mi(acc2, m, inv);
    #pragma unroll
    for (int reg = 0; reg < 4; ++reg) {
        const int crow = wbase + kq * 4 + reg;
        if (crow < M) {
            __bf16* dp = outp + (size_t)crow * 128 + r16;
            const __bf16* rs = feat + (size_t)crow * 128 + r16;
            #pragma unroll
            for (int n2 = 0; n2 < 8; ++n2) {
                const int colc = n2 * 16 + r16;
                float y = (acc2[n2][reg] - m[reg]) * inv[reg] * gn2[colc] + gn2[128 + colc];
                y += (float)rs[n2 * 16];
                dp[n2 * 16] = (__bf16)fmaxf(y, 0.f);
            }
        }
    }
}

// ============= lptail: lane_pooling tail (chained GEMMs + GNs) ==============
template<bool LP2>
__launch_bounds__(128, 3)
__global__ void lptail_k(const __bf16* __restrict__ hsrc,
                         const int* __restrict__ rp, const int* __restrict__ col,
                         const float* __restrict__ roi,
                         const __bf16* __restrict__ wc2, const __bf16* __restrict__ winW,
                         const __bf16* __restrict__ wm1, const __bf16* __restrict__ wm2,
                         const float* __restrict__ ngn, const float* __restrict__ m1gn,
                         const float* __restrict__ m2gn,
                         void* __restrict__ outp, int M)
{
    __shared__ __bf16 wl[2][16 * WST];
    const int tid = threadIdx.x, lane = tid & 63, wv = tid >> 6;
    const int r16 = lane & 15, kq = lane >> 4;
    const int wbase = blockIdx.x * 32 + wv * 16;
    const int wrow = (wbase + r16) < M ? (wbase + r16) : M - 1;

    f32x4 acc[8];
    #pragma unroll
    for (int n2 = 0; n2 < 8; ++n2) acc[n2] = (f32x4){0.f, 0.f, 0.f, 0.f};

    {   // (Σ h) @ c2
        float ss[32];
        #pragma unroll
        for (int i = 0; i < 32; ++i) ss[i] = 0.f;
        const int b = rp[wrow], e = rp[wrow + 1];
        for (int t2 = b; t2 < e; ++t2) {
            const __bf16* sp = hsrc + (size_t)col[t2] * 128 + kq * 8;
            #pragma unroll
            for (int ks = 0; ks < 4; ++ks) {
                bf16x8 h = *reinterpret_cast<const bf16x8*>(sp + ks * 32);
                #pragma unroll
                for (int i = 0; i < 8; ++i) ss[ks * 8 + i] += (float)h[i];
            }
        }
        bf16x8 a[4];
        ss_to_frags(ss, a);
        mfma16(acc, a, wc2, lane);
    }
    if (LP2) {   // + roi @ input_w
        bf16x8 a[4];
        const float* sp = roi + (size_t)wrow * 128 + kq * 8;
        #pragma unroll
        for (int ks = 0; ks < 4; ++ks) a[ks] = cvt8(sp + ks * 32);
        mfma16(acc, a, winW, lane);
    }

    {   // relu(gn(.,ngn)) @ m1
        bf16x8 a[4];
        gn_relayout(acc, ngn, wl[wv], a, r16, kq);
        #pragma unroll
        for (int n2 = 0; n2 < 8; ++n2) acc[n2] = (f32x4){0.f, 0.f, 0.f, 0.f};
        mfma16(acc, a, wm1, lane);
    }
    {   // relu(gn(.,m1gn)) @ m2
        bf16x8 a[4];
        gn_relayout(acc, m1gn, wl[wv], a, r16, kq);
        #pragma unroll
        for (int n2 = 0; n2 < 8; ++n2) acc[n2] = (f32x4){0.f, 0.f, 0.f, 0.f};
        mfma16(acc, a, wm2, lane);
    }

    float m[4], inv[4];
    gn_mi(acc, m, inv);
    #pragma unroll
    for (int reg = 0; reg < 4; ++reg) {
        const int crow = wbase + kq * 4 + reg;
        if (crow < M) {
            #pragma unroll
            for (int n2 = 0; n2 < 8; ++n2) {
                const int colc = n2 * 16 + r16;
                float y = (acc[n2][reg] - m[reg]) * inv[reg] * m2gn[colc] + m2gn[128 + colc];
                if (LP2) {
                    y += roi[(size_t)crow * 128 + colc];
                    ((float*)outp)[(size_t)crow * 128 + colc] = fmaxf(y, 0.f);
                } else {
                    ((__bf16*)outp)[(size_t)crow * 128 + colc] = (__bf16)fmaxf(y, 0.f);
                }
            }
        }
    }
}

// ===========================================================================
extern "C" void kernel_launch(void* const* d_in, const int* in_sizes, int n_in,
                              void* d_out, int out_size, void* d_ws, size_t ws_size,
                              hipStream_t stream)
{
    const float* roi_feat   = (const float*)d_in[0];
    const float* graph_pose = (const float*)d_in[1];
    const float* roi_pose   = (const float*)d_in[2];
    const float* lp_input_w = (const float*)d_in[3];
    const float* lp_rpw     = (const float*)d_in[4];
    const float* lp_rpb     = (const float*)d_in[5];
    const float* lp_c1w     = (const float*)d_in[6];
    const float* lp_c1gn    = (const float*)d_in[7];
    const float* lp_c2w     = (const float*)d_in[8];
    const float* lp_m1w     = (const float*)d_in[9];
    const float* lp_m1gn    = (const float*)d_in[10];
    const float* lp_m2w     = (const float*)d_in[11];
    const float* lp_m2gn    = (const float*)d_in[12];
    const float* lp_ngn     = (const float*)d_in[13];
    const float* f_ctrw     = (const float*)d_in[14];
    const float* f_psw      = (const float*)d_in[15];
    const float* f_lw       = (const float*)d_in[16];
    const float* f_rw       = (const float*)d_in[17];
    const float* f_ngn      = (const float*)d_in[18];
    const float* f_c2w      = (const float*)d_in[19];
    const float* f_c2gn     = (const float*)d_in[20];
    const int* e1_hi = (const int*)d_in[21];
    const int* e1_wi = (const int*)d_in[22];
    const int* e2_hi = (const int*)d_in[23];
    const int* e2_wi = (const int*)d_in[24];
    const int* ps_u  = (const int*)d_in[25];
    const int* ps_v  = (const int*)d_in[26];
    const int* lr_u  = (const int*)d_in[27];
    const int* lr_v  = (const int*)d_in[28];
    float* out = (float*)d_out;

    // ---- workspace (~77 MB) ----
    __bf16* gA   = (__bf16*)d_ws;                       // NG*128
    __bf16* gB   = gA + (size_t)NG * 128;               // NG*128
    __bf16* hbuf = gB + (size_t)NG * 128;               // E1_N*128
    __bf16* wbuf = hbuf + (size_t)E1_N * 128;           // 80*16384
    int* ip      = (int*)(wbuf + (size_t)80 * 16384);
    int* cnt14   = ip;             ip += 14 * NG;
    int* rp14    = ip;             ip += 14 * NG + 1;
    int* col14   = ip;             ip += 12 * EPS_N + 2 * ELR_N;
    int* cntE1   = ip;             ip += NG;
    int* rpE1    = ip;             ip += NG + 1;
    int* colE1   = ip;             ip += E1_N;
    int* cntE2   = ip;             ip += NR;
    int* rpE2    = ip;             ip += NR + 1;
    int* colE2   = ip;             ip += E2_N;
    int* bsum    = ip;             ip += 256;

    dim3 blk(256), blk128(128);
    const dim3 gNG32((NG + 31) / 32), gNR32((NR + 31) / 32), gE32((E1_N + 31) / 32);
    const int NE14 = 12 * EPS_N + 2 * ELR_N;
    const dim3 gH14((NE14 + 255) / 256);

    // ---------------- weight prep ----------------
    PrepTab tab; int nw = 0;
    auto addw = [&](const float* p, int s) { tab.src[nw] = p; tab.stride[nw] = s; ++nw; };
    addw(lp_c1w, 256);                 // 0 c1A_0
    addw(lp_c1w + 128, 256);           // 1 c1B_0
    addw(lp_c1w + 32768, 256);         // 2 c1A_1
    addw(lp_c1w + 32768 + 128, 256);   // 3 c1B_1
    addw(lp_input_w + 16384, 128);     // 4 input_w[1]
    addw(lp_c2w, 128); addw(lp_c2w + 16384, 128);   // 5,6
    addw(lp_m1w, 128); addw(lp_m1w + 16384, 128);   // 7,8
    addw(lp_m2w, 128); addw(lp_m2w + 16384, 128);   // 9,10
    for (int i = 0; i < 4; ++i) addw(f_ctrw + (size_t)i * 16384, 128);      // 11..14
    for (int i = 0; i < 4; ++i)
        for (int k = 0; k < 12; ++k) addw(f_psw + ((size_t)i * 12 + k) * 16384, 128);
    for (int i = 0; i < 4; ++i) addw(f_lw + (size_t)i * 16384, 128);        // 63..66
    for (int i = 0; i < 4; ++i) addw(f_rw + (size_t)i * 16384, 128);        // 67..70
    for (int i = 0; i < 4; ++i) addw(f_c2w + (size_t)i * 16384, 128);       // 71..74
    tab.n = nw;
    auto wb = [&](int idx) { return (const __bf16*)(wbuf + (size_t)idx * 16384); };
    prepw_k<<<dim3((nw * 2048 + 255) / 256), blk, 0, stream>>>(tab, wbuf);

    // ---------------- CSR builds ----------------
    hipMemsetAsync(cnt14, 0, (size_t)14 * NG * 4, stream);
    hist14_k<<<gH14, blk, 0, stream>>>(ps_u, lr_u, cnt14);
    {
        int n = 14 * NG, nb = (n + SCAN_CHUNK - 1) / SCAN_CHUNK;
        scan1_k<<<nb, blk, 0, stream>>>(cnt14, n, bsum);
        scan2_k<<<1, blk, 0, stream>>>(bsum, nb);
        scan3_k<<<nb, blk, 0, stream>>>(cnt14, n, bsum, rp14);
    }
    hipMemcpyAsync(cnt14, rp14, (size_t)14 * NG * 4, hipMemcpyDeviceToDevice, stream);
    fill14_k<<<gH14, blk, 0, stream>>>(ps_u, ps_v, lr_u, lr_v, cnt14, col14);

    hipMemsetAsync(cntE1, 0, (size_t)NG * 4, stream);
    histE_k<<<(E1_N + 255) / 256, blk, 0, stream>>>(e1_wi, E1_N, cntE1);
    {
        int n = NG, nb = (n + SCAN_CHUNK - 1) / SCAN_CHUNK;
        scan1_k<<<nb, blk, 0, stream>>>(cntE1, n, bsum);
        scan2_k<<<1, blk, 0, stream>>>(bsum, nb);
        scan3_k<<<nb, blk, 0, stream>>>(cntE1, n, bsum, rpE1);
    }
    hipMemcpyAsync(cntE1, rpE1, (size_t)NG * 4, hipMemcpyDeviceToDevice, stream);
    fillE_k<<<(E1_N + 255) / 256, blk, 0, stream>>>(e1_wi, E1_N, cntE1, colE1);

    hipMemsetAsync(cntE2, 0, (size_t)NR * 4, stream);
    histE_k<<<(E2_N + 255) / 256, blk, 0, stream>>>(e2_wi, E2_N, cntE2);
    {
        int n = NR, nb = (n + SCAN_CHUNK - 1) / SCAN_CHUNK;
        scan1_k<<<nb, blk, 0, stream>>>(cntE2, n, bsum);
        scan2_k<<<1, blk, 0, stream>>>(bsum, nb);
        scan3_k<<<nb, blk, 0, stream>>>(cntE2, n, bsum, rpE2);
    }
    hipMemcpyAsync(cntE2, rpE2, (size_t)NR * 4, hipMemcpyDeviceToDevice, stream);
    fillE_k<<<(E2_N + 255) / 256, blk, 0, stream>>>(e2_wi, E2_N, cntE2, colE2);

    // ---------------- lane_pooling #1 (roi -> graph) ----------------
    edgefull_k<float><<<gE32, blk128, 0, stream>>>(
        e1_hi, e1_wi, roi_feat, roi_pose, graph_pose, lp_rpw, lp_rpb,
        wb(0), wb(1), lp_c1gn, hbuf, E1_N);
    lptail_k<false><<<gNG32, blk128, 0, stream>>>(
        hbuf, rpE1, colE1, nullptr, wb(5), nullptr, wb(7), wb(9),
        lp_ngn, lp_m1gn, lp_m2gn, gA, NG);

    // ---------------- global_graph: 4 fused layers ----------------
    for (int i = 0; i < 4; ++i) {
        FW fw;
        for (int k = 0; k < 12; ++k) fw.w[k] = wb(15 + i * 12 + k);
        fw.w[12] = wb(63 + i); fw.w[13] = wb(67 + i);
        fw.w[14] = wb(11 + i); fw.w[15] = wb(71 + i);
        const __bf16* src = (i & 1) ? gB : gA;
        __bf16* dst = (i & 1) ? gA : gB;
        fusedlayer_k<<<gNG32, blk128, 0, stream>>>(
            src, rp14, col14, fw, f_ngn + (size_t)i * 256,
            f_c2gn + (size_t)i * 256, dst, NG);
    }
    // after i=3: result in gA

    // ---------------- lane_pooling #2 (graph -> roi) ----------------
    edgefull_k<__bf16><<<gE32, blk128, 0, stream>>>(
        e2_hi, e2_wi, gA, graph_pose, roi_pose, lp_rpw + 512, lp_rpb + 128,
        wb(2), wb(3), lp_c1gn + 256, hbuf, E2_N);
    lptail_k<true><<<gNR32, blk128, 0, stream>>>(
        hbuf, rpE2, colE2, roi_feat, wb(6), wb(4), wb(8), wb(10),
        lp_ngn + 256, lp_m1gn + 256, lp_m2gn + 256, out, NR);
}